// Round 12
// baseline (5243.372 us; speedup 1.0000x reference)
//
#include <hip/hip_runtime.h>
#include <hip/hip_bf16.h>

// SP_DecoderLight forward, MI355X. Round 12.
// R11: 5171us. Profile: seqmm head 3x436us @ VALU 17% (latency-bound strided
// loads); w2 GEMM done twice (stats+value, 16 dispatches ~1.9ms).
// Changes: (1) seqmm2: LDS-staged head, same c-ascending FMA order
// (bit-identical); (2) gram2: LDS-staged kNN gram (bit-identical);
// (3) single-pass w2 if ws>=413MB: gemm2 stores bf16 logits + f32-acc stats
// (sc2/sh2 bit-identical; only softmax input bf16-rounded). Fallback = R11.

using bf16 = __hip_bfloat16;
#define DEV static __device__ __forceinline__
DEV void stf(float* p, float v) { *p = v; }
DEV void stf(bf16* p, float v) { *p = __float2bfloat16(v); }

// ---------------- np-exact LDS-staged head GEMM (FMA chain, c-ascending) --
template<int ACT, int OG>
__global__ __launch_bounds__(256) void seqmm2_k(
    const float* __restrict__ W, const float* __restrict__ X,
    const float* __restrict__ bias, float* __restrict__ Out,
    int C, long sXb, long sOb)
{
  int t = threadIdx.x;
  int n = blockIdx.x * 256 + t;
  int o0 = blockIdx.y * OG;
  const float* Xb = X + (long)blockIdx.z * sXb;
  __shared__ float Xs[32][256];
  __shared__ float Ws[32][OG];
  float acc[OG];
#pragma unroll
  for (int g = 0; g < OG; ++g) acc[g] = 0.f;
  for (int c0 = 0; c0 < C; c0 += 32) {
#pragma unroll
    for (int cc = 0; cc < 32; ++cc) {
      int c = c0 + cc;
      Xs[cc][t] = (c < C) ? Xb[(long)c * 2048 + n] : 0.f;
    }
    for (int i = t; i < 32 * OG; i += 256) {
      int cc = i / OG, g = i % OG;
      int c = c0 + cc;
      Ws[cc][g] = (c < C) ? W[(long)(o0 + g) * C + c] : 0.f;
    }
    __syncthreads();
#pragma unroll
    for (int cc = 0; cc < 32; ++cc) {
      float xv = Xs[cc][t];
#pragma unroll
      for (int g = 0; g < OG; ++g)
        acc[g] = fmaf(Ws[cc][g], xv, acc[g]);   // c-ascending, pad-0 = no-op
    }
    __syncthreads();
  }
  float* Ob = Out + (long)blockIdx.z * sOb;
#pragma unroll
  for (int g = 0; g < OG; ++g) {
    float v = __fadd_rn(acc[g], bias[o0 + g]);
    if (ACT) v = v >= 0.f ? v : __fmul_rn(0.01f, v);
    Ob[(long)(o0 + g) * 2048 + n] = v;
  }
}

// numpy npyv(AVX512) pairwise sum of squares (exact golden realization)
__global__ void sqnp_k(const float* __restrict__ x1, float* __restrict__ sq) {
  int n = blockIdx.x * 256 + threadIdx.x;
  int b = blockIdx.y;
  const float* p = x1 + (long)b * 128 * 2048 + n;
  float r[4][16];
#pragma unroll
  for (int v = 0; v < 4; ++v)
#pragma unroll
    for (int l = 0; l < 16; ++l) {
      float x = p[(long)(16 * v + l) * 2048];
      r[v][l] = __fmul_rn(x, x);
    }
#pragma unroll
  for (int v = 0; v < 4; ++v)
#pragma unroll
    for (int l = 0; l < 16; ++l) {
      float x = p[(long)(64 + 16 * v + l) * 2048];
      r[v][l] = __fadd_rn(r[v][l], __fmul_rn(x, x));
    }
  float u[16];
#pragma unroll
  for (int l = 0; l < 16; ++l)
    u[l] = __fadd_rn(__fadd_rn(r[0][l], r[1][l]), __fadd_rn(r[2][l], r[3][l]));
  float b8[8];
#pragma unroll
  for (int l = 0; l < 8; ++l) b8[l] = __fadd_rn(u[l], u[l + 8]);
  float c4[4];
#pragma unroll
  for (int l = 0; l < 4; ++l) c4[l] = __fadd_rn(b8[l], b8[l + 4]);
  float d0 = __fadd_rn(c4[0], c4[2]);
  float d1 = __fadd_rn(c4[1], c4[3]);
  sq[b * 2048 + n] = __fadd_rn(d0, d1);
}

// np-exact LDS-staged gram (FMA chain, c-ascending; bit-identical to R11)
__global__ __launch_bounds__(256) void gram2_k(const float* __restrict__ A,
                                               const float* __restrict__ sqb,
                                               float* __restrict__ D) {
  int t = threadIdx.x;
  int m = blockIdx.x * 256 + t;
  int n0 = blockIdx.y * 16;
  __shared__ float Am[16][256];
  __shared__ float An[16][16];
  float g[16];
#pragma unroll
  for (int j = 0; j < 16; ++j) g[j] = 0.f;
  for (int c0 = 0; c0 < 128; c0 += 16) {
#pragma unroll
    for (int cc = 0; cc < 16; ++cc)
      Am[cc][t] = A[(long)(c0 + cc) * 2048 + m];
    { int cc = t >> 4, j = t & 15;
      An[cc][j] = A[(long)(c0 + cc) * 2048 + n0 + j]; }
    __syncthreads();
#pragma unroll
    for (int cc = 0; cc < 16; ++cc) {
      float xm = Am[cc][t];
#pragma unroll
      for (int j = 0; j < 16; ++j)
        g[j] = fmaf(An[cc][j], xm, g[j]);
    }
    __syncthreads();
  }
  float sm = sqb[m];
#pragma unroll
  for (int j = 0; j < 16; ++j) {
    float t1 = __fadd_rn(sqb[n0 + j], sm);
    D[(long)(n0 + j) * 2048 + m] = __fsub_rn(t1, __fmul_rn(2.0f, g[j]));
  }
}

// ---------------- f32 tiled GEMM 64x64 (small GEMMs) ----------------
template<int ACT>
__global__ __launch_bounds__(256) void gemm_k(
    const float* __restrict__ W, const float* __restrict__ X,
    const float* __restrict__ bias, float* __restrict__ Out,
    int O, int K, int N, long sXb, long sOb, float slope)
{
  const float* Xb = X + (long)blockIdx.z * sXb;
  int n0 = blockIdx.x * 64, o0 = blockIdx.y * 64;
  __shared__ float Ws[16][68];
  __shared__ float Xs[16][68];
  int t = threadIdx.x, tx = t & 15, ty = t >> 4;
  float acc[16] = {};
  for (int k0 = 0; k0 < K; k0 += 16) {
#pragma unroll
    for (int i = 0; i < 4; ++i) {
      int l = t + i * 256, oo = l >> 4, kk = l & 15;
      int o = o0 + oo, k = k0 + kk;
      float v = 0.f;
      if (o < O && k < K) v = W[(long)o * K + k];
      Ws[kk][oo] = v;
    }
#pragma unroll
    for (int i = 0; i < 4; ++i) {
      int kk = (t >> 6) + i * 4, nn = t & 63;
      int k = k0 + kk;
      float v = 0.f;
      if (k < K) v = Xb[(long)k * N + n0 + nn];
      Xs[kk][nn] = v;
    }
    __syncthreads();
#pragma unroll
    for (int kk = 0; kk < 16; ++kk) {
      float a0 = Ws[kk][ty * 4 + 0], a1 = Ws[kk][ty * 4 + 1];
      float a2 = Ws[kk][ty * 4 + 2], a3 = Ws[kk][ty * 4 + 3];
      float b0 = Xs[kk][tx * 4 + 0], b1 = Xs[kk][tx * 4 + 1];
      float b2 = Xs[kk][tx * 4 + 2], b3 = Xs[kk][tx * 4 + 3];
      acc[0] = fmaf(a0, b0, acc[0]);   acc[1] = fmaf(a0, b1, acc[1]);
      acc[2] = fmaf(a0, b2, acc[2]);   acc[3] = fmaf(a0, b3, acc[3]);
      acc[4] = fmaf(a1, b0, acc[4]);   acc[5] = fmaf(a1, b1, acc[5]);
      acc[6] = fmaf(a1, b2, acc[6]);   acc[7] = fmaf(a1, b3, acc[7]);
      acc[8] = fmaf(a2, b0, acc[8]);   acc[9] = fmaf(a2, b1, acc[9]);
      acc[10] = fmaf(a2, b2, acc[10]); acc[11] = fmaf(a2, b3, acc[11]);
      acc[12] = fmaf(a3, b0, acc[12]); acc[13] = fmaf(a3, b1, acc[13]);
      acc[14] = fmaf(a3, b2, acc[14]); acc[15] = fmaf(a3, b3, acc[15]);
    }
    __syncthreads();
  }
#pragma unroll
  for (int i = 0; i < 4; ++i) {
    int o = o0 + ty * 4 + i;
    if (o < O) {
      float bv = bias ? bias[o] : 0.f;
#pragma unroll
      for (int j = 0; j < 4; ++j) {
        float v = acc[i * 4 + j] + bv;
        if constexpr (ACT == 1) v = v >= 0.f ? v : slope * v;
        if constexpr (ACT == 2) v = tanhf(v);
        Out[(long)blockIdx.z * sOb + (long)o * N + n0 + tx * 4 + j] = v;
      }
    }
  }
}

// ---------------- f32 tiled GEMM 128x128, 8x8 microtile ----------------
// OMODE: 0 store, 1 stats-only, 2 store+stats. SPLITK: kOff = z*kLen.
template<int OMODE, int SPLITK, typename TO>
__global__ __launch_bounds__(256) void gemm2_k(
    const float* __restrict__ W, const float* __restrict__ X,
    const float* __restrict__ bias, TO* __restrict__ Out,
    int O, int K, int N, int kLen, long sXz, long sOz,
    double* __restrict__ gsum, double* __restrict__ gsq)
{
  int kOff = 0;
  if constexpr (SPLITK) { kOff = blockIdx.z * kLen; }
  else { X += (long)blockIdx.z * sXz; }
  int n0 = blockIdx.x * 128, o0 = blockIdx.y * 128;
  __shared__ float Ws[8][132];
  __shared__ float Xs[8][132];
  __shared__ float ssum[128], ssq[128];
  int t = threadIdx.x, tx = t & 15, ty = t >> 4;
  float acc[8][8] = {};
  for (int k0 = kOff; k0 < kOff + kLen; k0 += 8) {
    {
      int kk = t & 7, oo0 = t >> 3;
#pragma unroll
      for (int i = 0; i < 4; ++i) {
        int oo = oo0 + i * 32;
        Ws[kk][oo] = W[(long)(o0 + oo) * K + k0 + kk];
      }
    }
    {
      int nn = t & 127, kk0 = t >> 7;
#pragma unroll
      for (int i = 0; i < 4; ++i) {
        int kk = kk0 + i * 2;
        Xs[kk][nn] = X[(long)(k0 + kk) * N + n0 + nn];
      }
    }
    __syncthreads();
#pragma unroll
    for (int kk = 0; kk < 8; ++kk) {
      float a[8], bx[8];
#pragma unroll
      for (int i = 0; i < 8; ++i) a[i] = Ws[kk][ty * 8 + i];
#pragma unroll
      for (int j = 0; j < 8; ++j) bx[j] = Xs[kk][tx * 8 + j];
#pragma unroll
      for (int i = 0; i < 8; ++i)
#pragma unroll
        for (int j = 0; j < 8; ++j)
          acc[i][j] = fmaf(a[i], bx[j], acc[i][j]);
    }
    __syncthreads();
  }
  if constexpr (OMODE >= 1) {
    if (t < 128) { ssum[t] = 0.f; ssq[t] = 0.f; }
    __syncthreads();
#pragma unroll
    for (int i = 0; i < 8; ++i) {
      float s = 0.f, s2 = 0.f;
#pragma unroll
      for (int j = 0; j < 8; ++j) { float v = acc[i][j]; s += v; s2 = fmaf(v, v, s2); }
      atomicAdd(&ssum[ty * 8 + i], s);
      atomicAdd(&ssq[ty * 8 + i], s2);
    }
    __syncthreads();
    if (t < 128) {
      atomicAdd(&gsum[o0 + t], (double)ssum[t]);
      atomicAdd(&gsq[o0 + t], (double)ssq[t]);
    }
  }
  if constexpr (OMODE != 1) {
    TO* Ob = Out + (long)blockIdx.z * sOz;
#pragma unroll
    for (int i = 0; i < 8; ++i) {
      int o = o0 + ty * 8 + i;
      float bv = bias ? bias[o] : 0.f;
#pragma unroll
      for (int j = 0; j < 8; ++j)
        stf(&Ob[(long)o * N + n0 + tx * 8 + j], acc[i][j] + bv);
    }
  }
}

// ---------------- small kernels ----------------
__global__ void fill_k(float* __restrict__ out, float v, int n) {
  int id = blockIdx.x * 256 + threadIdx.x;
  if (id < n) out[id] = v;
}

__global__ void xz_k(const float* __restrict__ x, const float* __restrict__ z,
                     float* __restrict__ xz) {
  long id = (long)blockIdx.x * 256 + threadIdx.x;
  const long TOT = 8L * 131 * 2048;
  if (id >= TOT) return;
  int n = (int)(id % 2048);
  int c = (int)((id / 2048) % 131);
  int b = (int)(id / (131L * 2048));
  float v = (c < 3) ? x[((long)b * 3 + c) * 2048 + n]
                    : z[((long)b * 128 + (c - 3)) * 2048 + n];
  xz[id] = v;
}

__global__ void xwsplit_k(const float* __restrict__ xw, float* __restrict__ A,
                          float* __restrict__ Bm) {
  int id = blockIdx.x * 256 + threadIdx.x;
  if (id >= 512 * 128) return;
  int o = id / 128, c = id % 128;
  float a = xw[o * 256 + c];
  float b = xw[o * 256 + 128 + c];
  A[id] = a - b;
  Bm[id] = b;
}

__global__ __launch_bounds__(64) void topk_k(const float* __restrict__ dist,
                                             int* __restrict__ idx) {
  int n = blockIdx.x;
  const float* row = dist + (long)n * 2048;
  __shared__ float vals[2048];
  int lane = threadIdx.x;
  for (int i = lane; i < 2048; i += 64) vals[i] = row[i];
  __syncthreads();
  const float INF = __builtin_inff();
  for (int r = 0; r < 11; ++r) {
    float v = INF; int mi = 0x7fffffff;
    for (int i = lane; i < 2048; i += 64) {
      float xv = vals[i];
      if (xv < v) { v = xv; mi = i; }
    }
    for (int off = 32; off; off >>= 1) {
      float ov = __shfl_xor(v, off);
      int om = __shfl_xor(mi, off);
      if (ov < v || (ov == v && om < mi)) { v = ov; mi = om; }
    }
    if (mi < 0 || mi > 2047) mi = n;
    if (lane == 0) {
      if (r > 0) idx[n * 10 + (r - 1)] = mi;
      vals[mi] = INF;
    }
    __syncthreads();
  }
}

// G[c][m] = lrelu01(sc1[c]*(Q[c][idx[m]] - Q[c][m/10]) + sh1[c])  (per batch)
__global__ void g_k(const float* __restrict__ Q, const int* __restrict__ idx,
                    const float* __restrict__ sc, const float* __restrict__ sh,
                    float* __restrict__ G) {
  long id = (long)blockIdx.x * 256 + threadIdx.x;
  const long TOT = 256L * 20480;
  if (id >= TOT) return;
  int m = (int)(id % 20480);
  int c = (int)(id / 20480);
  int j = idx[m];
  int n = m / 10;
  const float* Qc = Q + (long)c * 2048;
  float v = fmaf(sc[c], Qc[j] - Qc[n], sh[c]);
  G[id] = v >= 0.f ? v : 0.01f * v;
}

// x2[o][n] = lrelu02( sum_{s<8} P[s][o][n] + bias[o] )
__global__ void redk_k(const float* __restrict__ P, const float* __restrict__ bias,
                       float* __restrict__ xo) {
  int id = blockIdx.x * 256 + threadIdx.x;
  if (id >= 512 * 2048) return;
  int o = id >> 11;
  float s = 0.f;
#pragma unroll
  for (int sp = 0; sp < 8; ++sp) s += P[(long)sp * 512 * 2048 + id];
  s += bias[o];
  xo[id] = s >= 0.f ? s : 0.2f * s;
}

__global__ __launch_bounds__(256) void stats_qd_k(const float* __restrict__ Q,
                                                  const int* __restrict__ idx,
                                                  double* __restrict__ sum,
                                                  double* __restrict__ sumsq) {
  int c = blockIdx.x, b = blockIdx.y;
  const float* Qp = Q + ((long)b * 256 + c) * 2048;
  const int* ip = idx + (long)b * 20480;
  float s = 0.f, s2 = 0.f;
  for (int m = threadIdx.x; m < 20480; m += 256) {
    float v = Qp[ip[m]] - Qp[m / 10];
    s += v; s2 = fmaf(v, v, s2);
  }
  __shared__ float ls[256], ls2[256];
  ls[threadIdx.x] = s; ls2[threadIdx.x] = s2;
  __syncthreads();
  for (int st = 128; st > 0; st >>= 1) {
    if (threadIdx.x < st) { ls[threadIdx.x] += ls[threadIdx.x + st]; ls2[threadIdx.x] += ls2[threadIdx.x + st]; }
    __syncthreads();
  }
  if (threadIdx.x == 0) { atomicAdd(&sum[c], (double)ls[0]); atomicAdd(&sumsq[c], (double)ls2[0]); }
}

__global__ __launch_bounds__(256) void stats_cx_k(const float* __restrict__ R,
                                                  const float* __restrict__ S,
                                                  const int* __restrict__ idx,
                                                  double* __restrict__ sum,
                                                  double* __restrict__ sumsq) {
  int c = blockIdx.x, b = blockIdx.y;
  const float* Rp = R + ((long)b * 512 + c) * 2048;
  const float* Sp = S + ((long)b * 512 + c) * 2048;
  const int* ip = idx + (long)b * 20480;
  float s = 0.f, s2 = 0.f;
  for (int m = threadIdx.x; m < 20480; m += 256) {
    float v = Rp[m / 10] + Sp[ip[m]];
    s += v; s2 = fmaf(v, v, s2);
  }
  __shared__ float ls[256], ls2[256];
  ls[threadIdx.x] = s; ls2[threadIdx.x] = s2;
  __syncthreads();
  for (int st = 128; st > 0; st >>= 1) {
    if (threadIdx.x < st) { ls[threadIdx.x] += ls[threadIdx.x + st]; ls2[threadIdx.x] += ls2[threadIdx.x + st]; }
    __syncthreads();
  }
  if (threadIdx.x == 0) { atomicAdd(&sum[c], (double)ls[0]); atomicAdd(&sumsq[c], (double)ls2[0]); }
}

__global__ void bnfin_k(const double* __restrict__ sum, const double* __restrict__ sumsq,
                        const float* __restrict__ g, const float* __restrict__ bb,
                        float* __restrict__ sc, float* __restrict__ sh, int C, double invcnt) {
  int c = blockIdx.x * 256 + threadIdx.x;
  if (c >= C) return;
  double mean = sum[c] * invcnt;
  double var = sumsq[c] * invcnt - mean * mean;
  float rstd = (float)(1.0 / sqrt(var + 1e-5));
  float scv = g[c] * rstd;
  sc[c] = scv;
  sh[c] = bb[c] - (float)mean * scv;
}

// path B: in-place f32 softmax
__global__ void softmax_c(float* __restrict__ w, const float* __restrict__ sc,
                          const float* __restrict__ sh) {
  int id = blockIdx.x * 256 + threadIdx.x;
  if (id >= 512 * 2048) return;
  int o = id >> 11, n = id & 2047;
  float* p = w + (long)o * 20480 + n * 10;
  float a = sc[o], bsh = sh[o];
  float v[10], m = -1e30f;
#pragma unroll
  for (int k = 0; k < 10; ++k) {
    float x = fmaf(a, p[k], bsh);
    x = x >= 0.f ? x : 0.01f * x;
    v[k] = x; m = fmaxf(m, x);
  }
  float s = 0.f;
#pragma unroll
  for (int k = 0; k < 10; ++k) { v[k] = __expf(v[k] - m); s += v[k]; }
  float inv = 1.f / s;
#pragma unroll
  for (int k = 0; k < 10; ++k) p[k] = v[k] * inv;
}

// path A: bf16 logits in, f32 weights out
__global__ void softmax_a(const bf16* __restrict__ wl, const float* __restrict__ sc,
                          const float* __restrict__ sh, float* __restrict__ wsm) {
  int id = blockIdx.x * 256 + threadIdx.x;
  if (id >= 512 * 2048) return;
  int o = id >> 11, n = id & 2047;
  const bf16* p = wl + (long)o * 20480 + n * 10;
  float* q = wsm + (long)o * 20480 + n * 10;
  float a = sc[o], bsh = sh[o];
  float v[10], m = -1e30f;
#pragma unroll
  for (int k = 0; k < 10; ++k) {
    float x = fmaf(a, __bfloat162float(p[k]), bsh);
    x = x >= 0.f ? x : 0.01f * x;
    v[k] = x; m = fmaxf(m, x);
  }
  float s = 0.f;
#pragma unroll
  for (int k = 0; k < 10; ++k) { v[k] = __expf(v[k] - m); s += v[k]; }
  float inv = 1.f / s;
#pragma unroll
  for (int k = 0; k < 10; ++k) q[k] = v[k] * inv;
}

// Xe[(c*10+k)][n] = lrelu01(sc3*(R+S[idx])+sh3) * wsm
__global__ void xe_c(const float* __restrict__ R, const float* __restrict__ S,
                     const int* __restrict__ idx, const float* __restrict__ wsm,
                     const float* __restrict__ sc, const float* __restrict__ sh,
                     float* __restrict__ Xe) {
  long id = (long)blockIdx.x * 256 + threadIdx.x;
  const long TOT = 5120L * 2048;
  if (id >= TOT) return;
  int n = (int)(id & 2047);
  int r = (int)(id >> 11);
  int c = r / 10, k = r % 10;
  int j = idx[n * 10 + k];
  float v = R[(long)c * 2048 + n] + S[(long)c * 2048 + j];
  v = fmaf(sc[c], v, sh[c]);
  v = v >= 0.f ? v : 0.01f * v;
  float wv = wsm[(long)c * 20480 + n * 10 + k];
  Xe[id] = v * wv;
}

__global__ void adain_k(float* __restrict__ x2, const float* __restrict__ ad2) {
  long id = (long)blockIdx.x * 256 + threadIdx.x;
  const long TOT = 8L * 512 * 2048;
  if (id >= TOT) return;
  int n = (int)(id & 2047);
  long t = id >> 11;
  int c = (int)(t & 511);
  int b = (int)(t >> 9);
  const float* A = ad2 + (long)b * 1024 * 2048;
  float ga = A[(long)c * 2048 + n];
  float be = A[(long)(512 + c) * 2048 + n];
  x2[id] = fmaf(ga, x2[id], be);
}

// ---------------- host ----------------
extern "C" void kernel_launch(void* const* d_in, const int* in_sizes, int n_in,
                              void* d_out, int out_size, void* d_ws, size_t ws_size,
                              hipStream_t stream) {
  (void)in_sizes; (void)n_in;
  const float* xin     = (const float*)d_in[0];
  const float* zin     = (const float*)d_in[1];
  const float* head_w1 = (const float*)d_in[2];
  const float* head_b1 = (const float*)d_in[3];
  const float* head_w2 = (const float*)d_in[4];
  const float* head_b2 = (const float*)d_in[5];
  const float* lat_w   = (const float*)d_in[22];
  const float* lat_b   = (const float*)d_in[23];
  const float* e2_w1   = (const float*)d_in[24];
  const float* e2_g1   = (const float*)d_in[26];
  const float* e2_bb1  = (const float*)d_in[27];
  const float* e2_w2   = (const float*)d_in[28];
  const float* e2_g2   = (const float*)d_in[30];
  const float* e2_bb2  = (const float*)d_in[31];
  const float* e2_xw   = (const float*)d_in[32];
  const float* e2_xg   = (const float*)d_in[34];
  const float* e2_xbb  = (const float*)d_in[35];
  const float* e2_ow   = (const float*)d_in[36];
  const float* e2_ob   = (const float*)d_in[37];
  const float* ad2_w   = (const float*)d_in[38];
  const float* ad2_b   = (const float*)d_in[39];
  const float* tail_w1 = (const float*)d_in[40];
  const float* tail_b1 = (const float*)d_in[41];
  const float* tail_w2 = (const float*)d_in[42];
  const float* tail_b2 = (const float*)d_in[43];
  const float* tail_w3 = (const float*)d_in[44];
  const float* tail_b3 = (const float*)d_in[45];
  float* out = (float*)d_out;

  // ---- arena ----
  char* ws = (char*)d_ws;
  size_t off = 0;
  auto A = [&](size_t bytes) { size_t r = off; off += (bytes + 255) & ~(size_t)255; return r; };
  size_t oStats = A(20480);
  size_t oSc1 = A(1024), oSh1 = A(1024);
  size_t oSc2 = A(2048), oSh2 = A(2048);
  size_t oSc3 = A(2048), oSh3 = A(2048);
  size_t oXwA = A(512 * 128 * 4), oXwB = A(512 * 128 * 4);
  size_t oSq  = A(8L * 2048 * 4);
  size_t oIdx = A(8L * 2048 * 10 * 4);
  size_t oX1  = A(8L * 128 * 2048 * 4);
  size_t oQ   = A(8L * 256 * 2048 * 4);
  size_t oR   = A(8L * 512 * 2048 * 4);
  size_t oS   = A(8L * 512 * 2048 * 4);
  size_t oStyle = A(8L * 512 * 2048 * 4);
  size_t oX2  = A(8L * 512 * 2048 * 4);
  size_t oSL  = A(83886080 + 512);
  size_t offBase = off;
  size_t oW2all = A(8L * 512 * 20480 * 2);   // 168MB bf16 logits (path A)
  size_t offFull = off;
  if (ws_size < offBase) {
    fill_k<<<(out_size + 255) / 256, 256, 0, stream>>>(out, (float)(ws_size >> 20), out_size);
    return;
  }
  bool pathA = ws_size >= offFull;

  double* sum1 = (double*)(ws + oStats);
  double* sumsq1 = sum1 + 256;
  double* sum2 = sumsq1 + 256;
  double* sumsq2 = sum2 + 512;
  double* sum3 = sumsq2 + 512;
  double* sumsq3 = sum3 + 512;
  float* sc1 = (float*)(ws + oSc1); float* sh1 = (float*)(ws + oSh1);
  float* sc2 = (float*)(ws + oSc2); float* sh2 = (float*)(ws + oSh2);
  float* sc3 = (float*)(ws + oSc3); float* sh3 = (float*)(ws + oSh3);
  float* xwA = (float*)(ws + oXwA); float* xwB = (float*)(ws + oXwB);
  float* sq = (float*)(ws + oSq);
  int* idx = (int*)(ws + oIdx);
  float* x1 = (float*)(ws + oX1);
  float* Q = (float*)(ws + oQ);
  float* R = (float*)(ws + oR);
  float* S = (float*)(ws + oS);
  float* style = (float*)(ws + oStyle);
  float* style1 = (float*)(ws + oX2);
  float* x2 = (float*)(ws + oX2);
  char* SL = ws + oSL;
  float* xz = (float*)(SL);
  float* dist = (float*)(SL);
  float* G = (float*)(SL);
  float* w2c = (float*)(SL + 41943040);   // path B w2 values / path A wsm
  float* Xec = (float*)(SL);
  float* P = (float*)(SL + 41943040);
  float* ad2out = (float*)(SL);
  float* t1 = (float*)(SL);
  float* t2 = (float*)(SL + 20971520);
  bf16* w2all = (bf16*)(ws + oW2all);

  hipMemsetAsync(ws + oStats, 0, 20480, stream);

  // ---- np-exact head (LDS-staged, FMA order preserved) ----
  xz_k<<<(8L * 131 * 2048 + 255) / 256, 256, 0, stream>>>(xin, zin, xz);
  seqmm2_k<1, 16><<<dim3(8, 32, 8), 256, 0, stream>>>(
      head_w1, xz, head_b1, style1, 131, 131L * 2048, 512L * 2048);
  seqmm2_k<1, 16><<<dim3(8, 32, 8), 256, 0, stream>>>(
      head_w2, style1, head_b2, style, 512, 512L * 2048, 512L * 2048);
  seqmm2_k<0, 16><<<dim3(8, 8, 8), 256, 0, stream>>>(
      lat_w, style, lat_b, x1, 512, 512L * 2048, 128L * 2048);

  // ---- np-exact kNN ----
  sqnp_k<<<dim3(8, 8), 256, 0, stream>>>(x1, sq);
  for (int b = 0; b < 8; ++b) {
    gram2_k<<<dim3(8, 128), 256, 0, stream>>>(
        x1 + (long)b * 128 * 2048, sq + b * 2048, dist);
    topk_k<<<2048, 64, 0, stream>>>(dist, idx + (long)b * 20480);
  }

  // ---- Q; BN1 stats ----
  gemm_k<0><<<dim3(32, 4, 8), 256, 0, stream>>>(
      e2_w1, x1, nullptr, Q, 256, 128, 2048, 128L * 2048, 256L * 2048, 0.f);
  stats_qd_k<<<dim3(256, 8), 256, 0, stream>>>(Q, idx, sum1, sumsq1);
  bnfin_k<<<1, 256, 0, stream>>>(sum1, sumsq1, e2_g1, e2_bb1, sc1, sh1, 256, 1.0 / 163840.0);

  // ---- conv_x: R, S; BN3 stats ----
  xwsplit_k<<<(512 * 128 + 255) / 256, 256, 0, stream>>>(e2_xw, xwA, xwB);
  gemm_k<0><<<dim3(32, 8, 8), 256, 0, stream>>>(
      xwA, x1, nullptr, R, 512, 128, 2048, 128L * 2048, 512L * 2048, 0.f);
  gemm_k<0><<<dim3(32, 8, 8), 256, 0, stream>>>(
      xwB, x1, nullptr, S, 512, 128, 2048, 128L * 2048, 512L * 2048, 0.f);
  stats_cx_k<<<dim3(512, 8), 256, 0, stream>>>(R, S, idx, sum3, sumsq3);
  bnfin_k<<<2, 256, 0, stream>>>(sum3, sumsq3, e2_xg, e2_xbb, sc3, sh3, 512, 1.0 / 163840.0);

  if (pathA) {
    // single w2 pass: store bf16 logits + stats from f32 acc
    for (int b = 0; b < 8; ++b) {
      g_k<<<20480, 256, 0, stream>>>(Q + (long)b * 256 * 2048, idx + (long)b * 20480,
                                     sc1, sh1, G);
      gemm2_k<2, 0, bf16><<<dim3(160, 4, 1), 256, 0, stream>>>(
          e2_w2, G, nullptr, w2all + (long)b * 512 * 20480, 512, 256, 20480, 256,
          0, 0, sum2, sumsq2);
    }
    bnfin_k<<<2, 256, 0, stream>>>(sum2, sumsq2, e2_g2, e2_bb2, sc2, sh2, 512, 1.0 / 163840.0);
    for (int b = 0; b < 8; ++b) {
      softmax_a<<<(512 * 2048 + 255) / 256, 256, 0, stream>>>(
          w2all + (long)b * 512 * 20480, sc2, sh2, w2c);
      xe_c<<<(5120L * 2048 + 255) / 256, 256, 0, stream>>>(
          R + (long)b * 512 * 2048, S + (long)b * 512 * 2048,
          idx + (long)b * 20480, w2c, sc3, sh3, Xec);
      gemm2_k<0, 1, float><<<dim3(16, 4, 8), 256, 0, stream>>>(
          e2_ow, Xec, nullptr, P, 512, 5120, 2048, 640, 0, 512L * 2048,
          nullptr, nullptr);
      redk_k<<<(512 * 2048 + 255) / 256, 256, 0, stream>>>(
          P, e2_ob, x2 + (long)b * 512 * 2048);
    }
  } else {
    // fallback: R11 two-pass
    for (int b = 0; b < 8; ++b) {
      g_k<<<20480, 256, 0, stream>>>(Q + (long)b * 256 * 2048, idx + (long)b * 20480,
                                     sc1, sh1, G);
      gemm2_k<1, 0, float><<<dim3(160, 4, 1), 256, 0, stream>>>(
          e2_w2, G, nullptr, nullptr, 512, 256, 20480, 256, 0, 0, sum2, sumsq2);
    }
    bnfin_k<<<2, 256, 0, stream>>>(sum2, sumsq2, e2_g2, e2_bb2, sc2, sh2, 512, 1.0 / 163840.0);
    for (int b = 0; b < 8; ++b) {
      g_k<<<20480, 256, 0, stream>>>(Q + (long)b * 256 * 2048, idx + (long)b * 20480,
                                     sc1, sh1, G);
      gemm2_k<0, 0, float><<<dim3(160, 4, 1), 256, 0, stream>>>(
          e2_w2, G, nullptr, w2c, 512, 256, 20480, 256, 0, 0, nullptr, nullptr);
      softmax_c<<<(512 * 2048 + 255) / 256, 256, 0, stream>>>(w2c, sc2, sh2);
      xe_c<<<(5120L * 2048 + 255) / 256, 256, 0, stream>>>(
          R + (long)b * 512 * 2048, S + (long)b * 512 * 2048,
          idx + (long)b * 20480, w2c, sc3, sh3, Xec);
      gemm2_k<0, 1, float><<<dim3(16, 4, 8), 256, 0, stream>>>(
          e2_ow, Xec, nullptr, P, 512, 5120, 2048, 640, 0, 512L * 2048,
          nullptr, nullptr);
      redk_k<<<(512 * 2048 + 255) / 256, 256, 0, stream>>>(
          P, e2_ob, x2 + (long)b * 512 * 2048);
    }
  }

  // ---- AdaIN2 ----
  gemm2_k<0, 0, float><<<dim3(16, 8, 8), 256, 0, stream>>>(
      ad2_w, style, ad2_b, ad2out, 1024, 512, 2048, 512, 512L * 2048, 1024L * 2048,
      nullptr, nullptr);
  adain_k<<<(8L * 512 * 2048 + 255) / 256, 256, 0, stream>>>(x2, ad2out);

  // ---- tail ----
  gemm_k<1><<<dim3(32, 4, 8), 256, 0, stream>>>(
      tail_w1, x2, tail_b1, t1, 256, 512, 2048, 512L * 2048, 256L * 2048, 0.01f);
  gemm_k<1><<<dim3(32, 1, 8), 256, 0, stream>>>(
      tail_w2, t1, tail_b2, t2, 64, 256, 2048, 256L * 2048, 64L * 2048, 0.01f);
  gemm_k<2><<<dim3(32, 1, 8), 256, 0, stream>>>(
      tail_w3, t2, tail_b3, out, 3, 64, 2048, 64L * 2048, 3L * 2048, 0.f);
}

// Round 13
// 4656.473 us; speedup vs baseline: 1.1260x; 1.1260x over previous
//
#include <hip/hip_runtime.h>
#include <hip/hip_bf16.h>

// SP_DecoderLight forward, MI355X. Round 13.
// R12: 5243us. seqmm2 head LDS-issue-bound (17 ds_read per 16 FMA, 492us x3);
// gemm2 X-reads 4-way bank-conflicted (1.05e7 conflicts/dispatch).
// Key insight: gemm2's per-element accumulation IS the np-exact ascending-k
// single-acc FMA chain -> head & gram move to the fast 128x128 kernel
// BIT-IDENTICALLY (head1 K zero-padded 131->136; np-exact epilogue).
// Conflict fix: thread columns = two stride-4 float4 groups (2-way = free).

using bf16 = __hip_bfloat16;
#define DEV static __device__ __forceinline__
DEV void stf(float* p, float v) { *p = v; }
DEV void stf(bf16* p, float v) { *p = __float2bfloat16(v); }

// ---------------- f32 tiled GEMM 128x128, 8x8 microtile ----------------
// Per-output-element: single-accumulator FMA chain over ascending k
// (np-exact; == einsum sum_of_products realization).
// OMODE: 0 store, 1 stats-only, 2 store+stats. SPLITK: kOff=z*kLen.
// ACT: 0 none, 1 np-exact lrelu(0.01) after +bias.
template<int OMODE, int SPLITK, int ACT, typename TO>
__global__ __launch_bounds__(256) void gemm2_k(
    const float* __restrict__ W, const float* __restrict__ X,
    const float* __restrict__ bias, TO* __restrict__ Out,
    int O, int K, int N, int kLen, long sXz, long sOz,
    double* __restrict__ gsum, double* __restrict__ gsq)
{
  int kOff = 0;
  if constexpr (SPLITK) { kOff = blockIdx.z * kLen; }
  else { X += (long)blockIdx.z * sXz; }
  int n0 = blockIdx.x * 128, o0 = blockIdx.y * 128;
  __shared__ float Ws[8][132];
  __shared__ float Xs[8][132];
  __shared__ float ssum[128], ssq[128];
  int t = threadIdx.x, tx = t & 15, ty = t >> 4;
  int cb = tx * 4;                       // two col groups: cb+j, 64+cb+j
  float acc[8][8] = {};
  for (int k0 = kOff; k0 < kOff + kLen; k0 += 8) {
    {
      int kk = t & 7, oo0 = t >> 3;
#pragma unroll
      for (int i = 0; i < 4; ++i) {
        int oo = oo0 + i * 32;
        Ws[kk][oo] = W[(long)(o0 + oo) * K + k0 + kk];
      }
    }
    {
      int nn = t & 127, kk0 = t >> 7;
#pragma unroll
      for (int i = 0; i < 4; ++i) {
        int kk = kk0 + i * 2;
        Xs[kk][nn] = X[(long)(k0 + kk) * N + n0 + nn];
      }
    }
    __syncthreads();
#pragma unroll
    for (int kk = 0; kk < 8; ++kk) {
      float a[8], bx[8];
#pragma unroll
      for (int i = 0; i < 8; ++i) a[i] = Ws[kk][ty * 8 + i];
#pragma unroll
      for (int j = 0; j < 4; ++j) { bx[j] = Xs[kk][cb + j]; bx[4 + j] = Xs[kk][64 + cb + j]; }
#pragma unroll
      for (int i = 0; i < 8; ++i)
#pragma unroll
        for (int j = 0; j < 8; ++j)
          acc[i][j] = fmaf(a[i], bx[j], acc[i][j]);
    }
    __syncthreads();
  }
  if constexpr (OMODE >= 1) {
    if (t < 128) { ssum[t] = 0.f; ssq[t] = 0.f; }
    __syncthreads();
#pragma unroll
    for (int i = 0; i < 8; ++i) {
      float s = 0.f, s2 = 0.f;
#pragma unroll
      for (int j = 0; j < 8; ++j) { float v = acc[i][j]; s += v; s2 = fmaf(v, v, s2); }
      atomicAdd(&ssum[ty * 8 + i], s);
      atomicAdd(&ssq[ty * 8 + i], s2);
    }
    __syncthreads();
    if (t < 128) {
      atomicAdd(&gsum[o0 + t], (double)ssum[t]);
      atomicAdd(&gsq[o0 + t], (double)ssq[t]);
    }
  }
  if constexpr (OMODE != 1) {
    TO* Ob = Out + (long)blockIdx.z * sOz;
#pragma unroll
    for (int i = 0; i < 8; ++i) {
      int o = o0 + ty * 8 + i;
      float bv = bias ? bias[o] : 0.f;
#pragma unroll
      for (int j = 0; j < 8; ++j) {
        int col = (j < 4) ? (n0 + cb + j) : (n0 + 64 + cb + (j - 4));
        float v = acc[i][j] + bv;                     // single rounded add
        if constexpr (ACT == 1) v = v >= 0.f ? v : 0.01f * v;  // single mul
        stf(&Ob[(long)o * N + col], v);
      }
    }
  }
}

// np-exact gram via same microtile (chain == gram2's): per batch,
// D[n][m] = fsub(fadd(sq[n],sq[m]), fmul(2, sum_c_asc fma(A[c][n],A[c][m])))
__global__ __launch_bounds__(256) void gramg_k(const float* __restrict__ A,
                                               const float* __restrict__ sqb,
                                               float* __restrict__ D) {
  int m0 = blockIdx.x * 128, n0 = blockIdx.y * 128;
  __shared__ float Am[8][132];
  __shared__ float An[8][132];
  int t = threadIdx.x, tx = t & 15, ty = t >> 4;
  int cb = tx * 4;
  float g[8][8] = {};
  for (int c0 = 0; c0 < 128; c0 += 8) {
    {
      int nn = t & 127, kk0 = t >> 7;
#pragma unroll
      for (int i = 0; i < 4; ++i) {
        int kk = kk0 + i * 2;
        Am[kk][nn] = A[(long)(c0 + kk) * 2048 + m0 + nn];
        An[kk][nn] = A[(long)(c0 + kk) * 2048 + n0 + nn];
      }
    }
    __syncthreads();
#pragma unroll
    for (int kk = 0; kk < 8; ++kk) {
      float a[8], bm[8];
#pragma unroll
      for (int i = 0; i < 8; ++i) a[i] = An[kk][ty * 8 + i];
#pragma unroll
      for (int j = 0; j < 4; ++j) { bm[j] = Am[kk][cb + j]; bm[4 + j] = Am[kk][64 + cb + j]; }
#pragma unroll
      for (int i = 0; i < 8; ++i)
#pragma unroll
        for (int j = 0; j < 8; ++j)
          g[i][j] = fmaf(a[i], bm[j], g[i][j]);
    }
    __syncthreads();
  }
#pragma unroll
  for (int i = 0; i < 8; ++i) {
    int n = n0 + ty * 8 + i;
    float sn = sqb[n];
#pragma unroll
    for (int j = 0; j < 8; ++j) {
      int m = (j < 4) ? (m0 + cb + j) : (m0 + 64 + cb + (j - 4));
      float t1 = __fadd_rn(sn, sqb[m]);
      D[(long)n * 2048 + m] = __fsub_rn(t1, __fmul_rn(2.0f, g[i][j]));
    }
  }
}

// numpy npyv(AVX512) pairwise sum of squares (exact golden realization)
__global__ void sqnp_k(const float* __restrict__ x1, float* __restrict__ sq) {
  int n = blockIdx.x * 256 + threadIdx.x;
  int b = blockIdx.y;
  const float* p = x1 + (long)b * 128 * 2048 + n;
  float r[4][16];
#pragma unroll
  for (int v = 0; v < 4; ++v)
#pragma unroll
    for (int l = 0; l < 16; ++l) {
      float x = p[(long)(16 * v + l) * 2048];
      r[v][l] = __fmul_rn(x, x);
    }
#pragma unroll
  for (int v = 0; v < 4; ++v)
#pragma unroll
    for (int l = 0; l < 16; ++l) {
      float x = p[(long)(64 + 16 * v + l) * 2048];
      r[v][l] = __fadd_rn(r[v][l], __fmul_rn(x, x));
    }
  float u[16];
#pragma unroll
  for (int l = 0; l < 16; ++l)
    u[l] = __fadd_rn(__fadd_rn(r[0][l], r[1][l]), __fadd_rn(r[2][l], r[3][l]));
  float b8[8];
#pragma unroll
  for (int l = 0; l < 8; ++l) b8[l] = __fadd_rn(u[l], u[l + 8]);
  float c4[4];
#pragma unroll
  for (int l = 0; l < 4; ++l) c4[l] = __fadd_rn(b8[l], b8[l + 4]);
  float d0 = __fadd_rn(c4[0], c4[2]);
  float d1 = __fadd_rn(c4[1], c4[3]);
  sq[b * 2048 + n] = __fadd_rn(d0, d1);
}

// ---------------- f32 tiled GEMM 64x64 (Q/R/S/tail) ----------------
template<int ACT>
__global__ __launch_bounds__(256) void gemm_k(
    const float* __restrict__ W, const float* __restrict__ X,
    const float* __restrict__ bias, float* __restrict__ Out,
    int O, int K, int N, long sXb, long sOb, float slope)
{
  const float* Xb = X + (long)blockIdx.z * sXb;
  int n0 = blockIdx.x * 64, o0 = blockIdx.y * 64;
  __shared__ float Ws[16][68];
  __shared__ float Xs[16][68];
  int t = threadIdx.x, tx = t & 15, ty = t >> 4;
  float acc[16] = {};
  for (int k0 = 0; k0 < K; k0 += 16) {
#pragma unroll
    for (int i = 0; i < 4; ++i) {
      int l = t + i * 256, oo = l >> 4, kk = l & 15;
      int o = o0 + oo, k = k0 + kk;
      float v = 0.f;
      if (o < O && k < K) v = W[(long)o * K + k];
      Ws[kk][oo] = v;
    }
#pragma unroll
    for (int i = 0; i < 4; ++i) {
      int kk = (t >> 6) + i * 4, nn = t & 63;
      int k = k0 + kk;
      float v = 0.f;
      if (k < K) v = Xb[(long)k * N + n0 + nn];
      Xs[kk][nn] = v;
    }
    __syncthreads();
#pragma unroll
    for (int kk = 0; kk < 16; ++kk) {
      float a0 = Ws[kk][ty * 4 + 0], a1 = Ws[kk][ty * 4 + 1];
      float a2 = Ws[kk][ty * 4 + 2], a3 = Ws[kk][ty * 4 + 3];
      float b0 = Xs[kk][tx * 4 + 0], b1 = Xs[kk][tx * 4 + 1];
      float b2 = Xs[kk][tx * 4 + 2], b3 = Xs[kk][tx * 4 + 3];
      acc[0] = fmaf(a0, b0, acc[0]);   acc[1] = fmaf(a0, b1, acc[1]);
      acc[2] = fmaf(a0, b2, acc[2]);   acc[3] = fmaf(a0, b3, acc[3]);
      acc[4] = fmaf(a1, b0, acc[4]);   acc[5] = fmaf(a1, b1, acc[5]);
      acc[6] = fmaf(a1, b2, acc[6]);   acc[7] = fmaf(a1, b3, acc[7]);
      acc[8] = fmaf(a2, b0, acc[8]);   acc[9] = fmaf(a2, b1, acc[9]);
      acc[10] = fmaf(a2, b2, acc[10]); acc[11] = fmaf(a2, b3, acc[11]);
      acc[12] = fmaf(a3, b0, acc[12]); acc[13] = fmaf(a3, b1, acc[13]);
      acc[14] = fmaf(a3, b2, acc[14]); acc[15] = fmaf(a3, b3, acc[15]);
    }
    __syncthreads();
  }
#pragma unroll
  for (int i = 0; i < 4; ++i) {
    int o = o0 + ty * 4 + i;
    if (o < O) {
      float bv = bias ? bias[o] : 0.f;
#pragma unroll
      for (int j = 0; j < 4; ++j) {
        float v = acc[i * 4 + j] + bv;
        if constexpr (ACT == 1) v = v >= 0.f ? v : slope * v;
        if constexpr (ACT == 2) v = tanhf(v);
        Out[(long)blockIdx.z * sOb + (long)o * N + n0 + tx * 4 + j] = v;
      }
    }
  }
}

// ---------------- small kernels ----------------
__global__ void fill_k(float* __restrict__ out, float v, int n) {
  int id = blockIdx.x * 256 + threadIdx.x;
  if (id < n) out[id] = v;
}

__global__ void wpad_k(const float* __restrict__ w, float* __restrict__ wp) {
  int id = blockIdx.x * 256 + threadIdx.x;   // 512*136
  if (id >= 512 * 136) return;
  int o = id / 136, k = id % 136;
  wp[id] = (k < 131) ? w[o * 131 + k] : 0.f;
}

// xzp[b][c][n], c<136: [x; z; zeros] (pad rows exactly zero every call)
__global__ void xz_k(const float* __restrict__ x, const float* __restrict__ z,
                     float* __restrict__ xz) {
  long id = (long)blockIdx.x * 256 + threadIdx.x;
  const long TOT = 8L * 136 * 2048;
  if (id >= TOT) return;
  int n = (int)(id % 2048);
  int c = (int)((id / 2048) % 136);
  int b = (int)(id / (136L * 2048));
  float v = 0.f;
  if (c < 3) v = x[((long)b * 3 + c) * 2048 + n];
  else if (c < 131) v = z[((long)b * 128 + (c - 3)) * 2048 + n];
  xz[id] = v;
}

__global__ void xwsplit_k(const float* __restrict__ xw, float* __restrict__ A,
                          float* __restrict__ Bm) {
  int id = blockIdx.x * 256 + threadIdx.x;
  if (id >= 512 * 128) return;
  int o = id / 128, c = id % 128;
  float a = xw[o * 256 + c];
  float b = xw[o * 256 + 128 + c];
  A[id] = a - b;
  Bm[id] = b;
}

__global__ __launch_bounds__(64) void topk_k(const float* __restrict__ dist,
                                             int* __restrict__ idx) {
  int n = blockIdx.x;
  const float* row = dist + (long)n * 2048;
  __shared__ float vals[2048];
  int lane = threadIdx.x;
  for (int i = lane; i < 2048; i += 64) vals[i] = row[i];
  __syncthreads();
  const float INF = __builtin_inff();
  for (int r = 0; r < 11; ++r) {
    float v = INF; int mi = 0x7fffffff;
    for (int i = lane; i < 2048; i += 64) {
      float xv = vals[i];
      if (xv < v) { v = xv; mi = i; }
    }
    for (int off = 32; off; off >>= 1) {
      float ov = __shfl_xor(v, off);
      int om = __shfl_xor(mi, off);
      if (ov < v || (ov == v && om < mi)) { v = ov; mi = om; }
    }
    if (mi < 0 || mi > 2047) mi = n;
    if (lane == 0) {
      if (r > 0) idx[n * 10 + (r - 1)] = mi;
      vals[mi] = INF;
    }
    __syncthreads();
  }
}

// G[c][m] = lrelu01(sc1[c]*(Q[c][idx[m]] - Q[c][m/10]) + sh1[c])  (per batch)
__global__ void g_k(const float* __restrict__ Q, const int* __restrict__ idx,
                    const float* __restrict__ sc, const float* __restrict__ sh,
                    float* __restrict__ G) {
  long id = (long)blockIdx.x * 256 + threadIdx.x;
  const long TOT = 256L * 20480;
  if (id >= TOT) return;
  int m = (int)(id % 20480);
  int c = (int)(id / 20480);
  int j = idx[m];
  int n = m / 10;
  const float* Qc = Q + (long)c * 2048;
  float v = fmaf(sc[c], Qc[j] - Qc[n], sh[c]);
  G[id] = v >= 0.f ? v : 0.01f * v;
}

// x2[o][n] = lrelu02( sum_{s<8} P[s][o][n] + bias[o] )
__global__ void redk_k(const float* __restrict__ P, const float* __restrict__ bias,
                       float* __restrict__ xo) {
  int id = blockIdx.x * 256 + threadIdx.x;
  if (id >= 512 * 2048) return;
  int o = id >> 11;
  float s = 0.f;
#pragma unroll
  for (int sp = 0; sp < 8; ++sp) s += P[(long)sp * 512 * 2048 + id];
  s += bias[o];
  xo[id] = s >= 0.f ? s : 0.2f * s;
}

__global__ __launch_bounds__(256) void stats_qd_k(const float* __restrict__ Q,
                                                  const int* __restrict__ idx,
                                                  double* __restrict__ sum,
                                                  double* __restrict__ sumsq) {
  int c = blockIdx.x, b = blockIdx.y;
  const float* Qp = Q + ((long)b * 256 + c) * 2048;
  const int* ip = idx + (long)b * 20480;
  float s = 0.f, s2 = 0.f;
  for (int m = threadIdx.x; m < 20480; m += 256) {
    float v = Qp[ip[m]] - Qp[m / 10];
    s += v; s2 = fmaf(v, v, s2);
  }
  __shared__ float ls[256], ls2[256];
  ls[threadIdx.x] = s; ls2[threadIdx.x] = s2;
  __syncthreads();
  for (int st = 128; st > 0; st >>= 1) {
    if (threadIdx.x < st) { ls[threadIdx.x] += ls[threadIdx.x + st]; ls2[threadIdx.x] += ls2[threadIdx.x + st]; }
    __syncthreads();
  }
  if (threadIdx.x == 0) { atomicAdd(&sum[c], (double)ls[0]); atomicAdd(&sumsq[c], (double)ls2[0]); }
}

__global__ __launch_bounds__(256) void stats_cx_k(const float* __restrict__ R,
                                                  const float* __restrict__ S,
                                                  const int* __restrict__ idx,
                                                  double* __restrict__ sum,
                                                  double* __restrict__ sumsq) {
  int c = blockIdx.x, b = blockIdx.y;
  const float* Rp = R + ((long)b * 512 + c) * 2048;
  const float* Sp = S + ((long)b * 512 + c) * 2048;
  const int* ip = idx + (long)b * 20480;
  float s = 0.f, s2 = 0.f;
  for (int m = threadIdx.x; m < 20480; m += 256) {
    float v = Rp[m / 10] + Sp[ip[m]];
    s += v; s2 = fmaf(v, v, s2);
  }
  __shared__ float ls[256], ls2[256];
  ls[threadIdx.x] = s; ls2[threadIdx.x] = s2;
  __syncthreads();
  for (int st = 128; st > 0; st >>= 1) {
    if (threadIdx.x < st) { ls[threadIdx.x] += ls[threadIdx.x + st]; ls2[threadIdx.x] += ls2[threadIdx.x + st]; }
    __syncthreads();
  }
  if (threadIdx.x == 0) { atomicAdd(&sum[c], (double)ls[0]); atomicAdd(&sumsq[c], (double)ls2[0]); }
}

__global__ void bnfin_k(const double* __restrict__ sum, const double* __restrict__ sumsq,
                        const float* __restrict__ g, const float* __restrict__ bb,
                        float* __restrict__ sc, float* __restrict__ sh, int C, double invcnt) {
  int c = blockIdx.x * 256 + threadIdx.x;
  if (c >= C) return;
  double mean = sum[c] * invcnt;
  double var = sumsq[c] * invcnt - mean * mean;
  float rstd = (float)(1.0 / sqrt(var + 1e-5));
  float scv = g[c] * rstd;
  sc[c] = scv;
  sh[c] = bb[c] - (float)mean * scv;
}

__global__ void softmax_c(float* __restrict__ w, const float* __restrict__ sc,
                          const float* __restrict__ sh) {
  int id = blockIdx.x * 256 + threadIdx.x;
  if (id >= 512 * 2048) return;
  int o = id >> 11, n = id & 2047;
  float* p = w + (long)o * 20480 + n * 10;
  float a = sc[o], bsh = sh[o];
  float v[10], m = -1e30f;
#pragma unroll
  for (int k = 0; k < 10; ++k) {
    float x = fmaf(a, p[k], bsh);
    x = x >= 0.f ? x : 0.01f * x;
    v[k] = x; m = fmaxf(m, x);
  }
  float s = 0.f;
#pragma unroll
  for (int k = 0; k < 10; ++k) { v[k] = __expf(v[k] - m); s += v[k]; }
  float inv = 1.f / s;
#pragma unroll
  for (int k = 0; k < 10; ++k) p[k] = v[k] * inv;
}

__global__ void softmax_a(const bf16* __restrict__ wl, const float* __restrict__ sc,
                          const float* __restrict__ sh, float* __restrict__ wsm) {
  int id = blockIdx.x * 256 + threadIdx.x;
  if (id >= 512 * 2048) return;
  int o = id >> 11, n = id & 2047;
  const bf16* p = wl + (long)o * 20480 + n * 10;
  float* q = wsm + (long)o * 20480 + n * 10;
  float a = sc[o], bsh = sh[o];
  float v[10], m = -1e30f;
#pragma unroll
  for (int k = 0; k < 10; ++k) {
    float x = fmaf(a, __bfloat162float(p[k]), bsh);
    x = x >= 0.f ? x : 0.01f * x;
    v[k] = x; m = fmaxf(m, x);
  }
  float s = 0.f;
#pragma unroll
  for (int k = 0; k < 10; ++k) { v[k] = __expf(v[k] - m); s += v[k]; }
  float inv = 1.f / s;
#pragma unroll
  for (int k = 0; k < 10; ++k) q[k] = v[k] * inv;
}

__global__ void xe_c(const float* __restrict__ R, const float* __restrict__ S,
                     const int* __restrict__ idx, const float* __restrict__ wsm,
                     const float* __restrict__ sc, const float* __restrict__ sh,
                     float* __restrict__ Xe) {
  long id = (long)blockIdx.x * 256 + threadIdx.x;
  const long TOT = 5120L * 2048;
  if (id >= TOT) return;
  int n = (int)(id & 2047);
  int r = (int)(id >> 11);
  int c = r / 10, k = r % 10;
  int j = idx[n * 10 + k];
  float v = R[(long)c * 2048 + n] + S[(long)c * 2048 + j];
  v = fmaf(sc[c], v, sh[c]);
  v = v >= 0.f ? v : 0.01f * v;
  float wv = wsm[(long)c * 20480 + n * 10 + k];
  Xe[id] = v * wv;
}

__global__ void adain_k(float* __restrict__ x2, const float* __restrict__ ad2) {
  long id = (long)blockIdx.x * 256 + threadIdx.x;
  const long TOT = 8L * 512 * 2048;
  if (id >= TOT) return;
  int n = (int)(id & 2047);
  long t = id >> 11;
  int c = (int)(t & 511);
  int b = (int)(t >> 9);
  const float* A = ad2 + (long)b * 1024 * 2048;
  float ga = A[(long)c * 2048 + n];
  float be = A[(long)(512 + c) * 2048 + n];
  x2[id] = fmaf(ga, x2[id], be);
}

// ---------------- host ----------------
extern "C" void kernel_launch(void* const* d_in, const int* in_sizes, int n_in,
                              void* d_out, int out_size, void* d_ws, size_t ws_size,
                              hipStream_t stream) {
  (void)in_sizes; (void)n_in;
  const float* xin     = (const float*)d_in[0];
  const float* zin     = (const float*)d_in[1];
  const float* head_w1 = (const float*)d_in[2];
  const float* head_b1 = (const float*)d_in[3];
  const float* head_w2 = (const float*)d_in[4];
  const float* head_b2 = (const float*)d_in[5];
  const float* lat_w   = (const float*)d_in[22];
  const float* lat_b   = (const float*)d_in[23];
  const float* e2_w1   = (const float*)d_in[24];
  const float* e2_g1   = (const float*)d_in[26];
  const float* e2_bb1  = (const float*)d_in[27];
  const float* e2_w2   = (const float*)d_in[28];
  const float* e2_g2   = (const float*)d_in[30];
  const float* e2_bb2  = (const float*)d_in[31];
  const float* e2_xw   = (const float*)d_in[32];
  const float* e2_xg   = (const float*)d_in[34];
  const float* e2_xbb  = (const float*)d_in[35];
  const float* e2_ow   = (const float*)d_in[36];
  const float* e2_ob   = (const float*)d_in[37];
  const float* ad2_w   = (const float*)d_in[38];
  const float* ad2_b   = (const float*)d_in[39];
  const float* tail_w1 = (const float*)d_in[40];
  const float* tail_b1 = (const float*)d_in[41];
  const float* tail_w2 = (const float*)d_in[42];
  const float* tail_b2 = (const float*)d_in[43];
  const float* tail_w3 = (const float*)d_in[44];
  const float* tail_b3 = (const float*)d_in[45];
  float* out = (float*)d_out;

  // ---- arena ----
  char* ws = (char*)d_ws;
  size_t off = 0;
  auto A = [&](size_t bytes) { size_t r = off; off += (bytes + 255) & ~(size_t)255; return r; };
  size_t oStats = A(20480);
  size_t oSc1 = A(1024), oSh1 = A(1024);
  size_t oSc2 = A(2048), oSh2 = A(2048);
  size_t oSc3 = A(2048), oSh3 = A(2048);
  size_t oXwA = A(512 * 128 * 4), oXwB = A(512 * 128 * 4);
  size_t oWp  = A(512 * 136 * 4);
  size_t oSq  = A(8L * 2048 * 4);
  size_t oIdx = A(8L * 2048 * 10 * 4);
  size_t oX1  = A(8L * 128 * 2048 * 4);
  size_t oQ   = A(8L * 256 * 2048 * 4);
  size_t oR   = A(8L * 512 * 2048 * 4);
  size_t oS   = A(8L * 512 * 2048 * 4);
  size_t oStyle = A(8L * 512 * 2048 * 4);
  size_t oX2  = A(8L * 512 * 2048 * 4);
  size_t oSL  = A(83886080 + 512);
  size_t offBase = off;
  size_t oW2all = A(8L * 512 * 20480 * 2);   // 168MB bf16 logits (path A)
  size_t offFull = off;
  if (ws_size < offBase) {
    fill_k<<<(out_size + 255) / 256, 256, 0, stream>>>(out, (float)(ws_size >> 20), out_size);
    return;
  }
  bool pathA = ws_size >= offFull;

  double* sum1 = (double*)(ws + oStats);
  double* sumsq1 = sum1 + 256;
  double* sum2 = sumsq1 + 256;
  double* sumsq2 = sum2 + 512;
  double* sum3 = sumsq2 + 512;
  double* sumsq3 = sum3 + 512;
  float* sc1 = (float*)(ws + oSc1); float* sh1 = (float*)(ws + oSh1);
  float* sc2 = (float*)(ws + oSc2); float* sh2 = (float*)(ws + oSh2);
  float* sc3 = (float*)(ws + oSc3); float* sh3 = (float*)(ws + oSh3);
  float* xwA = (float*)(ws + oXwA); float* xwB = (float*)(ws + oXwB);
  float* Wp = (float*)(ws + oWp);
  float* sq = (float*)(ws + oSq);
  int* idx = (int*)(ws + oIdx);
  float* x1 = (float*)(ws + oX1);
  float* Q = (float*)(ws + oQ);
  float* R = (float*)(ws + oR);
  float* S = (float*)(ws + oS);
  float* style = (float*)(ws + oStyle);
  float* style1 = (float*)(ws + oX2);
  float* x2 = (float*)(ws + oX2);
  char* SL = ws + oSL;
  float* xzp = (float*)(SL);            // 8*136*2048*4 = 8.9MB
  float* dist = (float*)(SL);
  float* G = (float*)(SL);
  float* w2c = (float*)(SL + 41943040);
  float* Xec = (float*)(SL);
  float* P = (float*)(SL + 41943040);
  float* ad2out = (float*)(SL);
  float* t1 = (float*)(SL);
  float* t2 = (float*)(SL + 20971520);
  bf16* w2all = (bf16*)(ws + oW2all);

  hipMemsetAsync(ws + oStats, 0, 20480, stream);

  // ---- np-exact head via gemm2 (bit-identical chain) ----
  wpad_k<<<(512 * 136 + 255) / 256, 256, 0, stream>>>(head_w1, Wp);
  xz_k<<<(8L * 136 * 2048 + 255) / 256, 256, 0, stream>>>(xin, zin, xzp);
  gemm2_k<0, 0, 1, float><<<dim3(16, 4, 8), 256, 0, stream>>>(
      Wp, xzp, head_b1, style1, 512, 136, 2048, 136, 136L * 2048, 512L * 2048,
      nullptr, nullptr);
  gemm2_k<0, 0, 1, float><<<dim3(16, 4, 8), 256, 0, stream>>>(
      head_w2, style1, head_b2, style, 512, 512, 2048, 512, 512L * 2048, 512L * 2048,
      nullptr, nullptr);
  gemm2_k<0, 0, 0, float><<<dim3(16, 1, 8), 256, 0, stream>>>(
      lat_w, style, lat_b, x1, 128, 512, 2048, 512, 512L * 2048, 128L * 2048,
      nullptr, nullptr);

  // ---- np-exact kNN ----
  sqnp_k<<<dim3(8, 8), 256, 0, stream>>>(x1, sq);
  for (int b = 0; b < 8; ++b) {
    gramg_k<<<dim3(16, 16), 256, 0, stream>>>(
        x1 + (long)b * 128 * 2048, sq + b * 2048, dist);
    topk_k<<<2048, 64, 0, stream>>>(dist, idx + (long)b * 20480);
  }

  // ---- Q; BN1 stats ----
  gemm_k<0><<<dim3(32, 4, 8), 256, 0, stream>>>(
      e2_w1, x1, nullptr, Q, 256, 128, 2048, 128L * 2048, 256L * 2048, 0.f);
  stats_qd_k<<<dim3(256, 8), 256, 0, stream>>>(Q, idx, sum1, sumsq1);
  bnfin_k<<<1, 256, 0, stream>>>(sum1, sumsq1, e2_g1, e2_bb1, sc1, sh1, 256, 1.0 / 163840.0);

  // ---- conv_x: R, S; BN3 stats ----
  xwsplit_k<<<(512 * 128 + 255) / 256, 256, 0, stream>>>(e2_xw, xwA, xwB);
  gemm_k<0><<<dim3(32, 8, 8), 256, 0, stream>>>(
      xwA, x1, nullptr, R, 512, 128, 2048, 128L * 2048, 512L * 2048, 0.f);
  gemm_k<0><<<dim3(32, 8, 8), 256, 0, stream>>>(
      xwB, x1, nullptr, S, 512, 128, 2048, 128L * 2048, 512L * 2048, 0.f);
  stats_cx_k<<<dim3(512, 8), 256, 0, stream>>>(R, S, idx, sum3, sumsq3);
  bnfin_k<<<2, 256, 0, stream>>>(sum3, sumsq3, e2_xg, e2_xbb, sc3, sh3, 512, 1.0 / 163840.0);

  if (pathA) {
    for (int b = 0; b < 8; ++b) {
      g_k<<<20480, 256, 0, stream>>>(Q + (long)b * 256 * 2048, idx + (long)b * 20480,
                                     sc1, sh1, G);
      gemm2_k<2, 0, 0, bf16><<<dim3(160, 4, 1), 256, 0, stream>>>(
          e2_w2, G, nullptr, w2all + (long)b * 512 * 20480, 512, 256, 20480, 256,
          0, 0, sum2, sumsq2);
    }
    bnfin_k<<<2, 256, 0, stream>>>(sum2, sumsq2, e2_g2, e2_bb2, sc2, sh2, 512, 1.0 / 163840.0);
    for (int b = 0; b < 8; ++b) {
      softmax_a<<<(512 * 2048 + 255) / 256, 256, 0, stream>>>(
          w2all + (long)b * 512 * 20480, sc2, sh2, w2c);
      xe_c<<<(5120L * 2048 + 255) / 256, 256, 0, stream>>>(
          R + (long)b * 512 * 2048, S + (long)b * 512 * 2048,
          idx + (long)b * 20480, w2c, sc3, sh3, Xec);
      gemm2_k<0, 1, 0, float><<<dim3(16, 4, 8), 256, 0, stream>>>(
          e2_ow, Xec, nullptr, P, 512, 5120, 2048, 640, 0, 512L * 2048,
          nullptr, nullptr);
      redk_k<<<(512 * 2048 + 255) / 256, 256, 0, stream>>>(
          P, e2_ob, x2 + (long)b * 512 * 2048);
    }
  } else {
    for (int b = 0; b < 8; ++b) {
      g_k<<<20480, 256, 0, stream>>>(Q + (long)b * 256 * 2048, idx + (long)b * 20480,
                                     sc1, sh1, G);
      gemm2_k<1, 0, 0, float><<<dim3(160, 4, 1), 256, 0, stream>>>(
          e2_w2, G, nullptr, nullptr, 512, 256, 20480, 256, 0, 0, sum2, sumsq2);
    }
    bnfin_k<<<2, 256, 0, stream>>>(sum2, sumsq2, e2_g2, e2_bb2, sc2, sh2, 512, 1.0 / 163840.0);
    for (int b = 0; b < 8; ++b) {
      g_k<<<20480, 256, 0, stream>>>(Q + (long)b * 256 * 2048, idx + (long)b * 20480,
                                     sc1, sh1, G);
      gemm2_k<0, 0, 0, float><<<dim3(160, 4, 1), 256, 0, stream>>>(
          e2_w2, G, nullptr, w2c, 512, 256, 20480, 256, 0, 0, nullptr, nullptr);
      softmax_c<<<(512 * 2048 + 255) / 256, 256, 0, stream>>>(w2c, sc2, sh2);
      xe_c<<<(5120L * 2048 + 255) / 256, 256, 0, stream>>>(
          R + (long)b * 512 * 2048, S + (long)b * 512 * 2048,
          idx + (long)b * 20480, w2c, sc3, sh3, Xec);
      gemm2_k<0, 1, 0, float><<<dim3(16, 4, 8), 256, 0, stream>>>(
          e2_ow, Xec, nullptr, P, 512, 5120, 2048, 640, 0, 512L * 2048,
          nullptr, nullptr);
      redk_k<<<(512 * 2048 + 255) / 256, 256, 0, stream>>>(
          P, e2_ob, x2 + (long)b * 512 * 2048);
    }
  }

  // ---- AdaIN2 ----
  gemm2_k<0, 0, 0, float><<<dim3(16, 8, 8), 256, 0, stream>>>(
      ad2_w, style, ad2_b, ad2out, 1024, 512, 2048, 512, 512L * 2048, 1024L * 2048,
      nullptr, nullptr);
  adain_k<<<(8L * 512 * 2048 + 255) / 256, 256, 0, stream>>>(x2, ad2out);

  // ---- tail ----
  gemm_k<1><<<dim3(32, 4, 8), 256, 0, stream>>>(
      tail_w1, x2, tail_b1, t1, 256, 512, 2048, 512L * 2048, 256L * 2048, 0.01f);
  gemm_k<1><<<dim3(32, 1, 8), 256, 0, stream>>>(
      tail_w2, t1, tail_b2, t2, 64, 256, 2048, 256L * 2048, 64L * 2048, 0.01f);
  gemm_k<2><<<dim3(32, 1, 8), 256, 0, stream>>>(
      tail_w3, t2, tail_b3, out, 3, 64, 2048, 64L * 2048, 3L * 2048, 0.f);
}

// Round 14
// 2619.360 us; speedup vs baseline: 2.0018x; 1.7777x over previous
//
#include <hip/hip_runtime.h>
#include <hip/hip_bf16.h>

// SP_DecoderLight forward, MI355X. Round 14: bf16 MFMA for smooth GEMMs.
// R13: 4656us, f32 gemm2 at structural limit (79 TF, VALU 66%), MfmaUtil 0.
// Smooth path (w2, conv_out, AdaIN ~2ms) -> mfma_f32_16x16x32_bf16, f32 acc.
// Exact kNN path (head/gram/topk, Q/R/S, BN stats) unchanged bit-for-bit.

using bf16 = __hip_bfloat16;
typedef short bf8_t __attribute__((ext_vector_type(8)));
typedef float f4_t __attribute__((ext_vector_type(4)));

#define DEV static __device__ __forceinline__
DEV void stf(float* p, float v) { *p = v; }
DEV void stf(bf16* p, float v) { *p = __float2bfloat16(v); }
DEV unsigned short f2b(float f) { bf16 h = __float2bfloat16(f); return *reinterpret_cast<unsigned short*>(&h); }
DEV unsigned short ldb(const float* p) { return f2b(*p); }
DEV unsigned short ldb(const unsigned short* p) { return *p; }

// ---------------- MFMA bf16 GEMM 128x128 ----------------
// W bf16 [O][K]; X [K][N] (float -> converted, or ushort bf16 bits).
// OMODE: 0 store, 1 stats-only, 2 store+stats. SPLITK: kOff=z*kLen else X+=z*sXz.
template<int OMODE, int SPLITK, typename TB, typename TO>
__global__ __launch_bounds__(256) void mfma_k(
    const unsigned short* __restrict__ Wb, const TB* __restrict__ X,
    const float* __restrict__ bias, TO* __restrict__ Out,
    int O, int K, int N, int kLen, long sXz, long sOz,
    double* __restrict__ gsum, double* __restrict__ gsq)
{
  int kOff = 0;
  if constexpr (SPLITK) { kOff = blockIdx.z * kLen; }
  else { X += (long)blockIdx.z * sXz; }
  int n0 = blockIdx.x * 128, o0 = blockIdx.y * 128;
  __shared__ unsigned short As[128][40];   // [o][k], 80B rows (16B-aligned)
  __shared__ unsigned short Bs[128][40];   // [n][k]
  __shared__ float ssum[128], ssq[128];
  int t = threadIdx.x;
  int w = t >> 6, l = t & 63;
  int lr = l & 15, lk = l >> 4;
  f4_t acc[2][8];
#pragma unroll
  for (int mi = 0; mi < 2; ++mi)
#pragma unroll
    for (int nj = 0; nj < 8; ++nj) acc[mi][nj] = (f4_t){0.f, 0.f, 0.f, 0.f};

  for (int k0 = kOff; k0 < kOff + kLen; k0 += 32) {
    {  // stage A (W): 4 bf16 per 8B load/store
      int ro = t >> 3, kq = (t & 7) * 4;
#pragma unroll
      for (int i = 0; i < 4; ++i) {
        int o = ro + i * 32;
        unsigned long long v = *reinterpret_cast<const unsigned long long*>(
            &Wb[(long)(o0 + o) * K + k0 + kq]);
        *reinterpret_cast<unsigned long long*>(&As[o][kq]) = v;
      }
    }
    {  // stage B (X): pairs along k, b32 LDS writes
      int nn = t & 127, kb = (t >> 7) * 2;
#pragma unroll
      for (int i = 0; i < 8; ++i) {
        int kk = kb + i * 4;
        unsigned short b0 = ldb(&X[(long)(k0 + kk) * N + n0 + nn]);
        unsigned short b1 = ldb(&X[(long)(k0 + kk + 1) * N + n0 + nn]);
        *reinterpret_cast<unsigned int*>(&Bs[nn][kk]) =
            (unsigned)b0 | ((unsigned)b1 << 16);
      }
    }
    __syncthreads();
    bf8_t a[2], b[8];
#pragma unroll
    for (int mi = 0; mi < 2; ++mi)
      a[mi] = *reinterpret_cast<const bf8_t*>(&As[w * 32 + mi * 16 + lr][lk * 8]);
#pragma unroll
    for (int nj = 0; nj < 8; ++nj)
      b[nj] = *reinterpret_cast<const bf8_t*>(&Bs[nj * 16 + lr][lk * 8]);
#pragma unroll
    for (int mi = 0; mi < 2; ++mi)
#pragma unroll
      for (int nj = 0; nj < 8; ++nj)
        acc[mi][nj] = __builtin_amdgcn_mfma_f32_16x16x32_bf16(
            a[mi], b[nj], acc[mi][nj], 0, 0, 0);
    __syncthreads();
  }
  if constexpr (OMODE >= 1) {
    if (t < 128) { ssum[t] = 0.f; ssq[t] = 0.f; }
    __syncthreads();
#pragma unroll
    for (int mi = 0; mi < 2; ++mi)
#pragma unroll
      for (int jj = 0; jj < 4; ++jj) {
        float s = 0.f, s2 = 0.f;
#pragma unroll
        for (int nj = 0; nj < 8; ++nj) {
          float v = acc[mi][nj][jj];
          s += v; s2 = fmaf(v, v, s2);
        }
        // reduce across the 16 col-lanes (same o)
#pragma unroll
        for (int off = 1; off < 16; off <<= 1) {
          s += __shfl_xor(s, off);
          s2 += __shfl_xor(s2, off);
        }
        if (lr == 0) {
          int oi = w * 32 + mi * 16 + lk * 4 + jj;
          atomicAdd(&ssum[oi], s);
          atomicAdd(&ssq[oi], s2);
        }
      }
    __syncthreads();
    if (t < 128) {
      atomicAdd(&gsum[o0 + t], (double)ssum[t]);
      atomicAdd(&gsq[o0 + t], (double)ssq[t]);
    }
  }
  if constexpr (OMODE != 1) {
    TO* Ob = Out + (long)blockIdx.z * sOz;
#pragma unroll
    for (int mi = 0; mi < 2; ++mi)
#pragma unroll
      for (int nj = 0; nj < 8; ++nj)
#pragma unroll
        for (int jj = 0; jj < 4; ++jj) {
          int o = o0 + w * 32 + mi * 16 + lk * 4 + jj;
          int n = n0 + nj * 16 + lr;
          float v = acc[mi][nj][jj] + (bias ? bias[o] : 0.f);
          stf(&Ob[(long)o * N + n], v);
        }
  }
}

// ---------------- f32 tiled GEMM 128x128 (np-exact chain; head) -----------
template<int OMODE, int SPLITK, int ACT, typename TO>
__global__ __launch_bounds__(256) void gemm2_k(
    const float* __restrict__ W, const float* __restrict__ X,
    const float* __restrict__ bias, TO* __restrict__ Out,
    int O, int K, int N, int kLen, long sXz, long sOz,
    double* __restrict__ gsum, double* __restrict__ gsq)
{
  int kOff = 0;
  if constexpr (SPLITK) { kOff = blockIdx.z * kLen; }
  else { X += (long)blockIdx.z * sXz; }
  int n0 = blockIdx.x * 128, o0 = blockIdx.y * 128;
  __shared__ float Ws[8][132];
  __shared__ float Xs[8][132];
  int t = threadIdx.x, tx = t & 15, ty = t >> 4;
  int cb = tx * 4;
  float acc[8][8] = {};
  for (int k0 = kOff; k0 < kOff + kLen; k0 += 8) {
    {
      int kk = t & 7, oo0 = t >> 3;
#pragma unroll
      for (int i = 0; i < 4; ++i) {
        int oo = oo0 + i * 32;
        Ws[kk][oo] = W[(long)(o0 + oo) * K + k0 + kk];
      }
    }
    {
      int nn = t & 127, kk0 = t >> 7;
#pragma unroll
      for (int i = 0; i < 4; ++i) {
        int kk = kk0 + i * 2;
        Xs[kk][nn] = X[(long)(k0 + kk) * N + n0 + nn];
      }
    }
    __syncthreads();
#pragma unroll
    for (int kk = 0; kk < 8; ++kk) {
      float a[8], bx[8];
#pragma unroll
      for (int i = 0; i < 8; ++i) a[i] = Ws[kk][ty * 8 + i];
#pragma unroll
      for (int j = 0; j < 4; ++j) { bx[j] = Xs[kk][cb + j]; bx[4 + j] = Xs[kk][64 + cb + j]; }
#pragma unroll
      for (int i = 0; i < 8; ++i)
#pragma unroll
        for (int j = 0; j < 8; ++j)
          acc[i][j] = fmaf(a[i], bx[j], acc[i][j]);
    }
    __syncthreads();
  }
  TO* Ob = Out + (long)blockIdx.z * sOz;
#pragma unroll
  for (int i = 0; i < 8; ++i) {
    int o = o0 + ty * 8 + i;
    float bv = bias ? bias[o] : 0.f;
#pragma unroll
    for (int j = 0; j < 8; ++j) {
      int col = (j < 4) ? (n0 + cb + j) : (n0 + 64 + cb + (j - 4));
      float v = acc[i][j] + bv;
      if constexpr (ACT == 1) v = v >= 0.f ? v : 0.01f * v;
      stf(&Ob[(long)o * N + col], v);
    }
  }
}

// np-exact gram (ascending-c FMA chain, np-exact epilogue)
__global__ __launch_bounds__(256) void gramg_k(const float* __restrict__ A,
                                               const float* __restrict__ sqb,
                                               float* __restrict__ D) {
  int m0 = blockIdx.x * 128, n0 = blockIdx.y * 128;
  __shared__ float Am[8][132];
  __shared__ float An[8][132];
  int t = threadIdx.x, tx = t & 15, ty = t >> 4;
  int cb = tx * 4;
  float g[8][8] = {};
  for (int c0 = 0; c0 < 128; c0 += 8) {
    {
      int nn = t & 127, kk0 = t >> 7;
#pragma unroll
      for (int i = 0; i < 4; ++i) {
        int kk = kk0 + i * 2;
        Am[kk][nn] = A[(long)(c0 + kk) * 2048 + m0 + nn];
        An[kk][nn] = A[(long)(c0 + kk) * 2048 + n0 + nn];
      }
    }
    __syncthreads();
#pragma unroll
    for (int kk = 0; kk < 8; ++kk) {
      float a[8], bm[8];
#pragma unroll
      for (int i = 0; i < 8; ++i) a[i] = An[kk][ty * 8 + i];
#pragma unroll
      for (int j = 0; j < 4; ++j) { bm[j] = Am[kk][cb + j]; bm[4 + j] = Am[kk][64 + cb + j]; }
#pragma unroll
      for (int i = 0; i < 8; ++i)
#pragma unroll
        for (int j = 0; j < 8; ++j)
          g[i][j] = fmaf(a[i], bm[j], g[i][j]);
    }
    __syncthreads();
  }
#pragma unroll
  for (int i = 0; i < 8; ++i) {
    int n = n0 + ty * 8 + i;
    float sn = sqb[n];
#pragma unroll
    for (int j = 0; j < 8; ++j) {
      int m = (j < 4) ? (m0 + cb + j) : (m0 + 64 + cb + (j - 4));
      float t1 = __fadd_rn(sn, sqb[m]);
      D[(long)n * 2048 + m] = __fsub_rn(t1, __fmul_rn(2.0f, g[i][j]));
    }
  }
}

// numpy npyv(AVX512) pairwise sum of squares (exact golden realization)
__global__ void sqnp_k(const float* __restrict__ x1, float* __restrict__ sq) {
  int n = blockIdx.x * 256 + threadIdx.x;
  int b = blockIdx.y;
  const float* p = x1 + (long)b * 128 * 2048 + n;
  float r[4][16];
#pragma unroll
  for (int v = 0; v < 4; ++v)
#pragma unroll
    for (int l = 0; l < 16; ++l) {
      float x = p[(long)(16 * v + l) * 2048];
      r[v][l] = __fmul_rn(x, x);
    }
#pragma unroll
  for (int v = 0; v < 4; ++v)
#pragma unroll
    for (int l = 0; l < 16; ++l) {
      float x = p[(long)(64 + 16 * v + l) * 2048];
      r[v][l] = __fadd_rn(r[v][l], __fmul_rn(x, x));
    }
  float u[16];
#pragma unroll
  for (int l = 0; l < 16; ++l)
    u[l] = __fadd_rn(__fadd_rn(r[0][l], r[1][l]), __fadd_rn(r[2][l], r[3][l]));
  float b8[8];
#pragma unroll
  for (int l = 0; l < 8; ++l) b8[l] = __fadd_rn(u[l], u[l + 8]);
  float c4[4];
#pragma unroll
  for (int l = 0; l < 4; ++l) c4[l] = __fadd_rn(b8[l], b8[l + 4]);
  float d0 = __fadd_rn(c4[0], c4[2]);
  float d1 = __fadd_rn(c4[1], c4[3]);
  sq[b * 2048 + n] = __fadd_rn(d0, d1);
}

// ---------------- f32 tiled GEMM 64x64 (Q/R/S/tail) ----------------
template<int ACT>
__global__ __launch_bounds__(256) void gemm_k(
    const float* __restrict__ W, const float* __restrict__ X,
    const float* __restrict__ bias, float* __restrict__ Out,
    int O, int K, int N, long sXb, long sOb, float slope)
{
  const float* Xb = X + (long)blockIdx.z * sXb;
  int n0 = blockIdx.x * 64, o0 = blockIdx.y * 64;
  __shared__ float Ws[16][68];
  __shared__ float Xs[16][68];
  int t = threadIdx.x, tx = t & 15, ty = t >> 4;
  float acc[16] = {};
  for (int k0 = 0; k0 < K; k0 += 16) {
#pragma unroll
    for (int i = 0; i < 4; ++i) {
      int l = t + i * 256, oo = l >> 4, kk = l & 15;
      int o = o0 + oo, k = k0 + kk;
      float v = 0.f;
      if (o < O && k < K) v = W[(long)o * K + k];
      Ws[kk][oo] = v;
    }
#pragma unroll
    for (int i = 0; i < 4; ++i) {
      int kk = (t >> 6) + i * 4, nn = t & 63;
      int k = k0 + kk;
      float v = 0.f;
      if (k < K) v = Xb[(long)k * N + n0 + nn];
      Xs[kk][nn] = v;
    }
    __syncthreads();
#pragma unroll
    for (int kk = 0; kk < 16; ++kk) {
      float a0 = Ws[kk][ty * 4 + 0], a1 = Ws[kk][ty * 4 + 1];
      float a2 = Ws[kk][ty * 4 + 2], a3 = Ws[kk][ty * 4 + 3];
      float b0 = Xs[kk][tx * 4 + 0], b1 = Xs[kk][tx * 4 + 1];
      float b2 = Xs[kk][tx * 4 + 2], b3 = Xs[kk][tx * 4 + 3];
      acc[0] = fmaf(a0, b0, acc[0]);   acc[1] = fmaf(a0, b1, acc[1]);
      acc[2] = fmaf(a0, b2, acc[2]);   acc[3] = fmaf(a0, b3, acc[3]);
      acc[4] = fmaf(a1, b0, acc[4]);   acc[5] = fmaf(a1, b1, acc[5]);
      acc[6] = fmaf(a1, b2, acc[6]);   acc[7] = fmaf(a1, b3, acc[7]);
      acc[8] = fmaf(a2, b0, acc[8]);   acc[9] = fmaf(a2, b1, acc[9]);
      acc[10] = fmaf(a2, b2, acc[10]); acc[11] = fmaf(a2, b3, acc[11]);
      acc[12] = fmaf(a3, b0, acc[12]); acc[13] = fmaf(a3, b1, acc[13]);
      acc[14] = fmaf(a3, b2, acc[14]); acc[15] = fmaf(a3, b3, acc[15]);
    }
    __syncthreads();
  }
#pragma unroll
  for (int i = 0; i < 4; ++i) {
    int o = o0 + ty * 4 + i;
    if (o < O) {
      float bv = bias ? bias[o] : 0.f;
#pragma unroll
      for (int j = 0; j < 4; ++j) {
        float v = acc[i * 4 + j] + bv;
        if constexpr (ACT == 1) v = v >= 0.f ? v : slope * v;
        if constexpr (ACT == 2) v = tanhf(v);
        Out[(long)blockIdx.z * sOb + (long)o * N + n0 + tx * 4 + j] = v;
      }
    }
  }
}

// ---------------- small kernels ----------------
__global__ void fill_k(float* __restrict__ out, float v, int n) {
  int id = blockIdx.x * 256 + threadIdx.x;
  if (id < n) out[id] = v;
}

__global__ void wcvt_k(const float* __restrict__ in, unsigned short* __restrict__ o, long n) {
  long id = (long)blockIdx.x * 256 + threadIdx.x;
  if (id < n) o[id] = f2b(in[id]);
}

__global__ void wpad_k(const float* __restrict__ w, float* __restrict__ wp) {
  int id = blockIdx.x * 256 + threadIdx.x;
  if (id >= 512 * 136) return;
  int o = id / 136, k = id % 136;
  wp[id] = (k < 131) ? w[o * 131 + k] : 0.f;
}

__global__ void xz_k(const float* __restrict__ x, const float* __restrict__ z,
                     float* __restrict__ xz) {
  long id = (long)blockIdx.x * 256 + threadIdx.x;
  const long TOT = 8L * 136 * 2048;
  if (id >= TOT) return;
  int n = (int)(id % 2048);
  int c = (int)((id / 2048) % 136);
  int b = (int)(id / (136L * 2048));
  float v = 0.f;
  if (c < 3) v = x[((long)b * 3 + c) * 2048 + n];
  else if (c < 131) v = z[((long)b * 128 + (c - 3)) * 2048 + n];
  xz[id] = v;
}

__global__ void xwsplit_k(const float* __restrict__ xw, float* __restrict__ A,
                          float* __restrict__ Bm) {
  int id = blockIdx.x * 256 + threadIdx.x;
  if (id >= 512 * 128) return;
  int o = id / 128, c = id % 128;
  float a = xw[o * 256 + c];
  float b = xw[o * 256 + 128 + c];
  A[id] = a - b;
  Bm[id] = b;
}

__global__ __launch_bounds__(64) void topk_k(const float* __restrict__ dist,
                                             int* __restrict__ idx) {
  int n = blockIdx.x;
  const float* row = dist + (long)n * 2048;
  __shared__ float vals[2048];
  int lane = threadIdx.x;
  for (int i = lane; i < 2048; i += 64) vals[i] = row[i];
  __syncthreads();
  const float INF = __builtin_inff();
  for (int r = 0; r < 11; ++r) {
    float v = INF; int mi = 0x7fffffff;
    for (int i = lane; i < 2048; i += 64) {
      float xv = vals[i];
      if (xv < v) { v = xv; mi = i; }
    }
    for (int off = 32; off; off >>= 1) {
      float ov = __shfl_xor(v, off);
      int om = __shfl_xor(mi, off);
      if (ov < v || (ov == v && om < mi)) { v = ov; mi = om; }
    }
    if (mi < 0 || mi > 2047) mi = n;
    if (lane == 0) {
      if (r > 0) idx[n * 10 + (r - 1)] = mi;
      vals[mi] = INF;
    }
    __syncthreads();
  }
}

// G bf16: lrelu01(sc1*(Q[idx]-Q[n])+sh1)
__global__ void g_k(const float* __restrict__ Q, const int* __restrict__ idx,
                    const float* __restrict__ sc, const float* __restrict__ sh,
                    unsigned short* __restrict__ G) {
  long id = (long)blockIdx.x * 256 + threadIdx.x;
  const long TOT = 256L * 20480;
  if (id >= TOT) return;
  int m = (int)(id % 20480);
  int c = (int)(id / 20480);
  int j = idx[m];
  int n = m / 10;
  const float* Qc = Q + (long)c * 2048;
  float v = fmaf(sc[c], Qc[j] - Qc[n], sh[c]);
  v = v >= 0.f ? v : 0.01f * v;
  G[id] = f2b(v);
}

__global__ void redk_k(const float* __restrict__ P, const float* __restrict__ bias,
                       float* __restrict__ xo) {
  int id = blockIdx.x * 256 + threadIdx.x;
  if (id >= 512 * 2048) return;
  int o = id >> 11;
  float s = 0.f;
#pragma unroll
  for (int sp = 0; sp < 8; ++sp) s += P[(long)sp * 512 * 2048 + id];
  s += bias[o];
  xo[id] = s >= 0.f ? s : 0.2f * s;
}

__global__ __launch_bounds__(256) void stats_qd_k(const float* __restrict__ Q,
                                                  const int* __restrict__ idx,
                                                  double* __restrict__ sum,
                                                  double* __restrict__ sumsq) {
  int c = blockIdx.x, b = blockIdx.y;
  const float* Qp = Q + ((long)b * 256 + c) * 2048;
  const int* ip = idx + (long)b * 20480;
  float s = 0.f, s2 = 0.f;
  for (int m = threadIdx.x; m < 20480; m += 256) {
    float v = Qp[ip[m]] - Qp[m / 10];
    s += v; s2 = fmaf(v, v, s2);
  }
  __shared__ float ls[256], ls2[256];
  ls[threadIdx.x] = s; ls2[threadIdx.x] = s2;
  __syncthreads();
  for (int st = 128; st > 0; st >>= 1) {
    if (threadIdx.x < st) { ls[threadIdx.x] += ls[threadIdx.x + st]; ls2[threadIdx.x] += ls2[threadIdx.x + st]; }
    __syncthreads();
  }
  if (threadIdx.x == 0) { atomicAdd(&sum[c], (double)ls[0]); atomicAdd(&sumsq[c], (double)ls2[0]); }
}

__global__ __launch_bounds__(256) void stats_cx_k(const float* __restrict__ R,
                                                  const float* __restrict__ S,
                                                  const int* __restrict__ idx,
                                                  double* __restrict__ sum,
                                                  double* __restrict__ sumsq) {
  int c = blockIdx.x, b = blockIdx.y;
  const float* Rp = R + ((long)b * 512 + c) * 2048;
  const float* Sp = S + ((long)b * 512 + c) * 2048;
  const int* ip = idx + (long)b * 20480;
  float s = 0.f, s2 = 0.f;
  for (int m = threadIdx.x; m < 20480; m += 256) {
    float v = Rp[m / 10] + Sp[ip[m]];
    s += v; s2 = fmaf(v, v, s2);
  }
  __shared__ float ls[256], ls2[256];
  ls[threadIdx.x] = s; ls2[threadIdx.x] = s2;
  __syncthreads();
  for (int st = 128; st > 0; st >>= 1) {
    if (threadIdx.x < st) { ls[threadIdx.x] += ls[threadIdx.x + st]; ls2[threadIdx.x] += ls2[threadIdx.x + st]; }
    __syncthreads();
  }
  if (threadIdx.x == 0) { atomicAdd(&sum[c], (double)ls[0]); atomicAdd(&sumsq[c], (double)ls2[0]); }
}

__global__ void bnfin_k(const double* __restrict__ sum, const double* __restrict__ sumsq,
                        const float* __restrict__ g, const float* __restrict__ bb,
                        float* __restrict__ sc, float* __restrict__ sh, int C, double invcnt) {
  int c = blockIdx.x * 256 + threadIdx.x;
  if (c >= C) return;
  double mean = sum[c] * invcnt;
  double var = sumsq[c] * invcnt - mean * mean;
  float rstd = (float)(1.0 / sqrt(var + 1e-5));
  float scv = g[c] * rstd;
  sc[c] = scv;
  sh[c] = bb[c] - (float)mean * scv;
}

// f32 logits in place (path B)
__global__ void softmax_c(float* __restrict__ w, const float* __restrict__ sc,
                          const float* __restrict__ sh) {
  int id = blockIdx.x * 256 + threadIdx.x;
  if (id >= 512 * 2048) return;
  int o = id >> 11, n = id & 2047;
  float* p = w + (long)o * 20480 + n * 10;
  float a = sc[o], bsh = sh[o];
  float v[10], m = -1e30f;
#pragma unroll
  for (int k = 0; k < 10; ++k) {
    float x = fmaf(a, p[k], bsh);
    x = x >= 0.f ? x : 0.01f * x;
    v[k] = x; m = fmaxf(m, x);
  }
  float s = 0.f;
#pragma unroll
  for (int k = 0; k < 10; ++k) { v[k] = __expf(v[k] - m); s += v[k]; }
  float inv = 1.f / s;
#pragma unroll
  for (int k = 0; k < 10; ++k) p[k] = v[k] * inv;
}

// bf16 logits in, f32 weights out (path A)
__global__ void softmax_a(const bf16* __restrict__ wl, const float* __restrict__ sc,
                          const float* __restrict__ sh, float* __restrict__ wsm) {
  int id = blockIdx.x * 256 + threadIdx.x;
  if (id >= 512 * 2048) return;
  int o = id >> 11, n = id & 2047;
  const bf16* p = wl + (long)o * 20480 + n * 10;
  float* q = wsm + (long)o * 20480 + n * 10;
  float a = sc[o], bsh = sh[o];
  float v[10], m = -1e30f;
#pragma unroll
  for (int k = 0; k < 10; ++k) {
    float x = fmaf(a, __bfloat162float(p[k]), bsh);
    x = x >= 0.f ? x : 0.01f * x;
    v[k] = x; m = fmaxf(m, x);
  }
  float s = 0.f;
#pragma unroll
  for (int k = 0; k < 10; ++k) { v[k] = __expf(v[k] - m); s += v[k]; }
  float inv = 1.f / s;
#pragma unroll
  for (int k = 0; k < 10; ++k) q[k] = v[k] * inv;
}

// Xe bf16
__global__ void xe_c(const float* __restrict__ R, const float* __restrict__ S,
                     const int* __restrict__ idx, const float* __restrict__ wsm,
                     const float* __restrict__ sc, const float* __restrict__ sh,
                     unsigned short* __restrict__ Xe) {
  long id = (long)blockIdx.x * 256 + threadIdx.x;
  const long TOT = 5120L * 2048;
  if (id >= TOT) return;
  int n = (int)(id & 2047);
  int r = (int)(id >> 11);
  int c = r / 10, k = r % 10;
  int j = idx[n * 10 + k];
  float v = R[(long)c * 2048 + n] + S[(long)c * 2048 + j];
  v = fmaf(sc[c], v, sh[c]);
  v = v >= 0.f ? v : 0.01f * v;
  float wv = wsm[(long)c * 20480 + n * 10 + k];
  Xe[id] = f2b(v * wv);
}

__global__ void adain_k(float* __restrict__ x2, const float* __restrict__ ad2) {
  long id = (long)blockIdx.x * 256 + threadIdx.x;
  const long TOT = 8L * 512 * 2048;
  if (id >= TOT) return;
  int n = (int)(id & 2047);
  long t = id >> 11;
  int c = (int)(t & 511);
  int b = (int)(t >> 9);
  const float* A = ad2 + (long)b * 1024 * 2048;
  float ga = A[(long)c * 2048 + n];
  float be = A[(long)(512 + c) * 2048 + n];
  x2[id] = fmaf(ga, x2[id], be);
}

// ---------------- host ----------------
extern "C" void kernel_launch(void* const* d_in, const int* in_sizes, int n_in,
                              void* d_out, int out_size, void* d_ws, size_t ws_size,
                              hipStream_t stream) {
  (void)in_sizes; (void)n_in;
  const float* xin     = (const float*)d_in[0];
  const float* zin     = (const float*)d_in[1];
  const float* head_w1 = (const float*)d_in[2];
  const float* head_b1 = (const float*)d_in[3];
  const float* head_w2 = (const float*)d_in[4];
  const float* head_b2 = (const float*)d_in[5];
  const float* lat_w   = (const float*)d_in[22];
  const float* lat_b   = (const float*)d_in[23];
  const float* e2_w1   = (const float*)d_in[24];
  const float* e2_g1   = (const float*)d_in[26];
  const float* e2_bb1  = (const float*)d_in[27];
  const float* e2_w2   = (const float*)d_in[28];
  const float* e2_g2   = (const float*)d_in[30];
  const float* e2_bb2  = (const float*)d_in[31];
  const float* e2_xw   = (const float*)d_in[32];
  const float* e2_xg   = (const float*)d_in[34];
  const float* e2_xbb  = (const float*)d_in[35];
  const float* e2_ow   = (const float*)d_in[36];
  const float* e2_ob   = (const float*)d_in[37];
  const float* ad2_w   = (const float*)d_in[38];
  const float* ad2_b   = (const float*)d_in[39];
  const float* tail_w1 = (const float*)d_in[40];
  const float* tail_b1 = (const float*)d_in[41];
  const float* tail_w2 = (const float*)d_in[42];
  const float* tail_b2 = (const float*)d_in[43];
  const float* tail_w3 = (const float*)d_in[44];
  const float* tail_b3 = (const float*)d_in[45];
  float* out = (float*)d_out;

  // ---- arena ----
  char* ws = (char*)d_ws;
  size_t off = 0;
  auto A = [&](size_t bytes) { size_t r = off; off += (bytes + 255) & ~(size_t)255; return r; };
  size_t oStats = A(20480);
  size_t oSc1 = A(1024), oSh1 = A(1024);
  size_t oSc2 = A(2048), oSh2 = A(2048);
  size_t oSc3 = A(2048), oSh3 = A(2048);
  size_t oXwA = A(512 * 128 * 4), oXwB = A(512 * 128 * 4);
  size_t oWp  = A(512 * 136 * 4);
  size_t oW2b = A(512 * 256 * 2);
  size_t oOwb = A(512L * 5120 * 2);
  size_t oAdb = A(1024 * 512 * 2);
  size_t oSq  = A(8L * 2048 * 4);
  size_t oIdx = A(8L * 2048 * 10 * 4);
  size_t oX1  = A(8L * 128 * 2048 * 4);
  size_t oQ   = A(8L * 256 * 2048 * 4);
  size_t oR   = A(8L * 512 * 2048 * 4);
  size_t oS   = A(8L * 512 * 2048 * 4);
  size_t oStyle = A(8L * 512 * 2048 * 4);
  size_t oX2  = A(8L * 512 * 2048 * 4);
  size_t oSL  = A(83886080 + 512);
  size_t offBase = off;
  size_t oW2all = A(8L * 512 * 20480 * 2);
  size_t offFull = off;
  if (ws_size < offBase) {
    fill_k<<<(out_size + 255) / 256, 256, 0, stream>>>(out, (float)(ws_size >> 20), out_size);
    return;
  }
  bool pathA = ws_size >= offFull;

  double* sum1 = (double*)(ws + oStats);
  double* sumsq1 = sum1 + 256;
  double* sum2 = sumsq1 + 256;
  double* sumsq2 = sum2 + 512;
  double* sum3 = sumsq2 + 512;
  double* sumsq3 = sum3 + 512;
  float* sc1 = (float*)(ws + oSc1); float* sh1 = (float*)(ws + oSh1);
  float* sc2 = (float*)(ws + oSc2); float* sh2 = (float*)(ws + oSh2);
  float* sc3 = (float*)(ws + oSc3); float* sh3 = (float*)(ws + oSh3);
  float* xwA = (float*)(ws + oXwA); float* xwB = (float*)(ws + oXwB);
  float* Wp = (float*)(ws + oWp);
  unsigned short* w2b = (unsigned short*)(ws + oW2b);
  unsigned short* owb = (unsigned short*)(ws + oOwb);
  unsigned short* adb = (unsigned short*)(ws + oAdb);
  float* sq = (float*)(ws + oSq);
  int* idx = (int*)(ws + oIdx);
  float* x1 = (float*)(ws + oX1);
  float* Q = (float*)(ws + oQ);
  float* R = (float*)(ws + oR);
  float* S = (float*)(ws + oS);
  float* style = (float*)(ws + oStyle);
  float* style1 = (float*)(ws + oX2);
  float* x2 = (float*)(ws + oX2);
  char* SL = ws + oSL;
  float* xzp = (float*)(SL);
  float* dist = (float*)(SL);
  unsigned short* G = (unsigned short*)(SL);       // 10.5MB
  unsigned short* Xeb = (unsigned short*)(SL);     // 21MB (after G dead)
  float* w2c = (float*)(SL + 41943040);            // 42MB (wsm / pathB logits)
  float* P = (float*)(SL + 41943040);              // 33.5MB (after w2c dead)
  float* ad2out = (float*)(SL);
  float* t1 = (float*)(SL);
  float* t2 = (float*)(SL + 20971520);
  bf16* w2all = (bf16*)(ws + oW2all);

  hipMemsetAsync(ws + oStats, 0, 20480, stream);

  // weight conversions (bf16 copies for MFMA)
  wcvt_k<<<(512 * 256 + 255) / 256, 256, 0, stream>>>(e2_w2, w2b, 512 * 256);
  wcvt_k<<<(int)((512L * 5120 + 255) / 256), 256, 0, stream>>>(e2_ow, owb, 512L * 5120);
  wcvt_k<<<(1024 * 512 + 255) / 256, 256, 0, stream>>>(ad2_w, adb, 1024 * 512);

  // ---- np-exact head via gemm2 (bit-identical chain) ----
  wpad_k<<<(512 * 136 + 255) / 256, 256, 0, stream>>>(head_w1, Wp);
  xz_k<<<(8L * 136 * 2048 + 255) / 256, 256, 0, stream>>>(xin, zin, xzp);
  gemm2_k<0, 0, 1, float><<<dim3(16, 4, 8), 256, 0, stream>>>(
      Wp, xzp, head_b1, style1, 512, 136, 2048, 136, 136L * 2048, 512L * 2048,
      nullptr, nullptr);
  gemm2_k<0, 0, 1, float><<<dim3(16, 4, 8), 256, 0, stream>>>(
      head_w2, style1, head_b2, style, 512, 512, 2048, 512, 512L * 2048, 512L * 2048,
      nullptr, nullptr);
  gemm2_k<0, 0, 0, float><<<dim3(16, 1, 8), 256, 0, stream>>>(
      lat_w, style, lat_b, x1, 128, 512, 2048, 512, 512L * 2048, 128L * 2048,
      nullptr, nullptr);

  // ---- np-exact kNN ----
  sqnp_k<<<dim3(8, 8), 256, 0, stream>>>(x1, sq);
  for (int b = 0; b < 8; ++b) {
    gramg_k<<<dim3(16, 16), 256, 0, stream>>>(
        x1 + (long)b * 128 * 2048, sq + b * 2048, dist);
    topk_k<<<2048, 64, 0, stream>>>(dist, idx + (long)b * 20480);
  }

  // ---- Q; BN1 stats ----
  gemm_k<0><<<dim3(32, 4, 8), 256, 0, stream>>>(
      e2_w1, x1, nullptr, Q, 256, 128, 2048, 128L * 2048, 256L * 2048, 0.f);
  stats_qd_k<<<dim3(256, 8), 256, 0, stream>>>(Q, idx, sum1, sumsq1);
  bnfin_k<<<1, 256, 0, stream>>>(sum1, sumsq1, e2_g1, e2_bb1, sc1, sh1, 256, 1.0 / 163840.0);

  // ---- conv_x: R, S; BN3 stats ----
  xwsplit_k<<<(512 * 128 + 255) / 256, 256, 0, stream>>>(e2_xw, xwA, xwB);
  gemm_k<0><<<dim3(32, 8, 8), 256, 0, stream>>>(
      xwA, x1, nullptr, R, 512, 128, 2048, 128L * 2048, 512L * 2048, 0.f);
  gemm_k<0><<<dim3(32, 8, 8), 256, 0, stream>>>(
      xwB, x1, nullptr, S, 512, 128, 2048, 128L * 2048, 512L * 2048, 0.f);
  stats_cx_k<<<dim3(512, 8), 256, 0, stream>>>(R, S, idx, sum3, sumsq3);
  bnfin_k<<<2, 256, 0, stream>>>(sum3, sumsq3, e2_xg, e2_xbb, sc3, sh3, 512, 1.0 / 163840.0);

  if (pathA) {
    for (int b = 0; b < 8; ++b) {
      g_k<<<20480, 256, 0, stream>>>(Q + (long)b * 256 * 2048, idx + (long)b * 20480,
                                     sc1, sh1, G);
      mfma_k<2, 0, unsigned short, bf16><<<dim3(160, 4, 1), 256, 0, stream>>>(
          w2b, G, nullptr, w2all + (long)b * 512 * 20480, 512, 256, 20480, 256,
          0, 0, sum2, sumsq2);
    }
    bnfin_k<<<2, 256, 0, stream>>>(sum2, sumsq2, e2_g2, e2_bb2, sc2, sh2, 512, 1.0 / 163840.0);
    for (int b = 0; b < 8; ++b) {
      softmax_a<<<(512 * 2048 + 255) / 256, 256, 0, stream>>>(
          w2all + (long)b * 512 * 20480, sc2, sh2, w2c);
      xe_c<<<(5120L * 2048 + 255) / 256, 256, 0, stream>>>(
          R + (long)b * 512 * 2048, S + (long)b * 512 * 2048,
          idx + (long)b * 20480, w2c, sc3, sh3, Xeb);
      mfma_k<0, 1, unsigned short, float><<<dim3(16, 4, 8), 256, 0, stream>>>(
          owb, Xeb, nullptr, P, 512, 5120, 2048, 640, 0, 512L * 2048,
          nullptr, nullptr);
      redk_k<<<(512 * 2048 + 255) / 256, 256, 0, stream>>>(
          P, e2_ob, x2 + (long)b * 512 * 2048);
    }
  } else {
    for (int b = 0; b < 8; ++b) {
      g_k<<<20480, 256, 0, stream>>>(Q + (long)b * 256 * 2048, idx + (long)b * 20480,
                                     sc1, sh1, G);
      mfma_k<1, 0, unsigned short, float><<<dim3(160, 4, 1), 256, 0, stream>>>(
          w2b, G, nullptr, nullptr, 512, 256, 20480, 256, 0, 0, sum2, sumsq2);
    }
    bnfin_k<<<2, 256, 0, stream>>>(sum2, sumsq2, e2_g2, e2_bb2, sc2, sh2, 512, 1.0 / 163840.0);
    for (int b = 0; b < 8; ++b) {
      g_k<<<20480, 256, 0, stream>>>(Q + (long)b * 256 * 2048, idx + (long)b * 20480,
                                     sc1, sh1, G);
      mfma_k<0, 0, unsigned short, float><<<dim3(160, 4, 1), 256, 0, stream>>>(
          w2b, G, nullptr, w2c, 512, 256, 20480, 256, 0, 0, nullptr, nullptr);
      softmax_c<<<(512 * 2048 + 255) / 256, 256, 0, stream>>>(w2c, sc2, sh2);
      xe_c<<<(5120L * 2048 + 255) / 256, 256, 0, stream>>>(
          R + (long)b * 512 * 2048, S + (long)b * 512 * 2048,
          idx + (long)b * 20480, w2c, sc3, sh3, Xeb);
      mfma_k<0, 1, unsigned short, float><<<dim3(16, 4, 8), 256, 0, stream>>>(
          owb, Xeb, nullptr, P, 512, 5120, 2048, 640, 0, 512L * 2048,
          nullptr, nullptr);
      redk_k<<<(512 * 2048 + 255) / 256, 256, 0, stream>>>(
          P, e2_ob, x2 + (long)b * 512 * 2048);
    }
  }

  // ---- AdaIN2 via MFMA ----
  mfma_k<0, 0, float, float><<<dim3(16, 8, 8), 256, 0, stream>>>(
      adb, style, ad2_b, ad2out, 1024, 512, 2048, 512, 512L * 2048, 1024L * 2048,
      nullptr, nullptr);
  adain_k<<<(8L * 512 * 2048 + 255) / 256, 256, 0, stream>>>(x2, ad2out);

  // ---- tail (f32) ----
  gemm_k<1><<<dim3(32, 4, 8), 256, 0, stream>>>(
      tail_w1, x2, tail_b1, t1, 256, 512, 2048, 512L * 2048, 256L * 2048, 0.01f);
  gemm_k<1><<<dim3(32, 1, 8), 256, 0, stream>>>(
      tail_w2, t1, tail_b2, t2, 64, 256, 2048, 256L * 2048, 64L * 2048, 0.01f);
  gemm_k<2><<<dim3(32, 1, 8), 256, 0, stream>>>(
      tail_w3, t2, tail_b3, out, 3, 64, 2048, 64L * 2048, 3L * 2048, 0.f);
}

// Round 15
// 1896.339 us; speedup vs baseline: 2.7650x; 1.3813x over previous
//
#include <hip/hip_runtime.h>
#include <hip/hip_bf16.h>

// SP_DecoderLight forward, MI355X. Round 15.
// R14: 2619us. Top: stats_cx 170us @ VALU 15% (latency-bound gathers);
// pathB two-pass w2 confirmed (R12 bit-identical => ws<413MB).
// Changes: (1) LDS-staged stats gathers (bit-identical); (2) register topk;
// (3) fused softmax+Xe (saves 672MB traffic); (4) bf16 w2 logits;
// (5) R/S + tail1 via MFMA (smooth-path bf16). Exact kNN path untouched.

using bf16 = __hip_bfloat16;
typedef short bf8_t __attribute__((ext_vector_type(8)));
typedef float f4_t __attribute__((ext_vector_type(4)));

#define DEV static __device__ __forceinline__
DEV void stf(float* p, float v) { *p = v; }
DEV void stf(bf16* p, float v) { *p = __float2bfloat16(v); }
DEV unsigned short f2b(float f) { bf16 h = __float2bfloat16(f); return *reinterpret_cast<unsigned short*>(&h); }
DEV float b2f(unsigned short u) { bf16 h; *reinterpret_cast<unsigned short*>(&h) = u; return __bfloat162float(h); }
DEV unsigned short ldb(const float* p) { return f2b(*p); }
DEV unsigned short ldb(const unsigned short* p) { return *p; }

// ---------------- MFMA bf16 GEMM 128x128 ----------------
// OMODE: 0 store, 1 stats-only, 2 store+stats. SPLITK: kOff=z*kLen else X+=z*sXz.
// ACT: 0 none, 1 lrelu(0.01) after +bias.
template<int OMODE, int SPLITK, int ACT, typename TB, typename TO>
__global__ __launch_bounds__(256) void mfma_k(
    const unsigned short* __restrict__ Wb, const TB* __restrict__ X,
    const float* __restrict__ bias, TO* __restrict__ Out,
    int O, int K, int N, int kLen, long sXz, long sOz,
    double* __restrict__ gsum, double* __restrict__ gsq)
{
  int kOff = 0;
  if constexpr (SPLITK) { kOff = blockIdx.z * kLen; }
  else { X += (long)blockIdx.z * sXz; }
  int n0 = blockIdx.x * 128, o0 = blockIdx.y * 128;
  __shared__ unsigned short As[128][40];
  __shared__ unsigned short Bs[128][40];
  __shared__ float ssum[128], ssq[128];
  int t = threadIdx.x;
  int w = t >> 6, l = t & 63;
  int lr = l & 15, lk = l >> 4;
  f4_t acc[2][8];
#pragma unroll
  for (int mi = 0; mi < 2; ++mi)
#pragma unroll
    for (int nj = 0; nj < 8; ++nj) acc[mi][nj] = (f4_t){0.f, 0.f, 0.f, 0.f};

  for (int k0 = kOff; k0 < kOff + kLen; k0 += 32) {
    {
      int ro = t >> 3, kq = (t & 7) * 4;
#pragma unroll
      for (int i = 0; i < 4; ++i) {
        int o = ro + i * 32;
        unsigned long long v = *reinterpret_cast<const unsigned long long*>(
            &Wb[(long)(o0 + o) * K + k0 + kq]);
        *reinterpret_cast<unsigned long long*>(&As[o][kq]) = v;
      }
    }
    {
      int nn = t & 127, kb = (t >> 7) * 2;
#pragma unroll
      for (int i = 0; i < 8; ++i) {
        int kk = kb + i * 4;
        unsigned short b0 = ldb(&X[(long)(k0 + kk) * N + n0 + nn]);
        unsigned short b1 = ldb(&X[(long)(k0 + kk + 1) * N + n0 + nn]);
        *reinterpret_cast<unsigned int*>(&Bs[nn][kk]) =
            (unsigned)b0 | ((unsigned)b1 << 16);
      }
    }
    __syncthreads();
    bf8_t a[2], b[8];
#pragma unroll
    for (int mi = 0; mi < 2; ++mi)
      a[mi] = *reinterpret_cast<const bf8_t*>(&As[w * 32 + mi * 16 + lr][lk * 8]);
#pragma unroll
    for (int nj = 0; nj < 8; ++nj)
      b[nj] = *reinterpret_cast<const bf8_t*>(&Bs[nj * 16 + lr][lk * 8]);
#pragma unroll
    for (int mi = 0; mi < 2; ++mi)
#pragma unroll
      for (int nj = 0; nj < 8; ++nj)
        acc[mi][nj] = __builtin_amdgcn_mfma_f32_16x16x32_bf16(
            a[mi], b[nj], acc[mi][nj], 0, 0, 0);
    __syncthreads();
  }
  if constexpr (OMODE >= 1) {
    if (t < 128) { ssum[t] = 0.f; ssq[t] = 0.f; }
    __syncthreads();
#pragma unroll
    for (int mi = 0; mi < 2; ++mi)
#pragma unroll
      for (int jj = 0; jj < 4; ++jj) {
        float s = 0.f, s2 = 0.f;
#pragma unroll
        for (int nj = 0; nj < 8; ++nj) {
          float v = acc[mi][nj][jj];
          s += v; s2 = fmaf(v, v, s2);
        }
#pragma unroll
        for (int off = 1; off < 16; off <<= 1) {
          s += __shfl_xor(s, off);
          s2 += __shfl_xor(s2, off);
        }
        if (lr == 0) {
          int oi = w * 32 + mi * 16 + lk * 4 + jj;
          atomicAdd(&ssum[oi], s);
          atomicAdd(&ssq[oi], s2);
        }
      }
    __syncthreads();
    if (t < 128) {
      atomicAdd(&gsum[o0 + t], (double)ssum[t]);
      atomicAdd(&gsq[o0 + t], (double)ssq[t]);
    }
  }
  if constexpr (OMODE != 1) {
    TO* Ob = Out + (long)blockIdx.z * sOz;
#pragma unroll
    for (int mi = 0; mi < 2; ++mi)
#pragma unroll
      for (int nj = 0; nj < 8; ++nj)
#pragma unroll
        for (int jj = 0; jj < 4; ++jj) {
          int o = o0 + w * 32 + mi * 16 + lk * 4 + jj;
          int n = n0 + nj * 16 + lr;
          float v = acc[mi][nj][jj] + (bias ? bias[o] : 0.f);
          if constexpr (ACT == 1) v = v >= 0.f ? v : 0.01f * v;
          stf(&Ob[(long)o * N + n], v);
        }
  }
}

// ---------------- f32 tiled GEMM 128x128 (np-exact chain; head) -----------
template<int ACT>
__global__ __launch_bounds__(256) void gemm2_k(
    const float* __restrict__ W, const float* __restrict__ X,
    const float* __restrict__ bias, float* __restrict__ Out,
    int O, int K, int N, int kLen, long sXz, long sOz)
{
  X += (long)blockIdx.z * sXz;
  int n0 = blockIdx.x * 128, o0 = blockIdx.y * 128;
  __shared__ float Ws[8][132];
  __shared__ float Xs[8][132];
  int t = threadIdx.x, tx = t & 15, ty = t >> 4;
  int cb = tx * 4;
  float acc[8][8] = {};
  for (int k0 = 0; k0 < kLen; k0 += 8) {
    {
      int kk = t & 7, oo0 = t >> 3;
#pragma unroll
      for (int i = 0; i < 4; ++i) {
        int oo = oo0 + i * 32;
        Ws[kk][oo] = W[(long)(o0 + oo) * K + k0 + kk];
      }
    }
    {
      int nn = t & 127, kk0 = t >> 7;
#pragma unroll
      for (int i = 0; i < 4; ++i) {
        int kk = kk0 + i * 2;
        Xs[kk][nn] = X[(long)(k0 + kk) * N + n0 + nn];
      }
    }
    __syncthreads();
#pragma unroll
    for (int kk = 0; kk < 8; ++kk) {
      float a[8], bx[8];
#pragma unroll
      for (int i = 0; i < 8; ++i) a[i] = Ws[kk][ty * 8 + i];
#pragma unroll
      for (int j = 0; j < 4; ++j) { bx[j] = Xs[kk][cb + j]; bx[4 + j] = Xs[kk][64 + cb + j]; }
#pragma unroll
      for (int i = 0; i < 8; ++i)
#pragma unroll
        for (int j = 0; j < 8; ++j)
          acc[i][j] = fmaf(a[i], bx[j], acc[i][j]);
    }
    __syncthreads();
  }
  float* Ob = Out + (long)blockIdx.z * sOz;
#pragma unroll
  for (int i = 0; i < 8; ++i) {
    int o = o0 + ty * 8 + i;
    float bv = bias ? bias[o] : 0.f;
#pragma unroll
    for (int j = 0; j < 8; ++j) {
      int col = (j < 4) ? (n0 + cb + j) : (n0 + 64 + cb + (j - 4));
      float v = acc[i][j] + bv;
      if constexpr (ACT == 1) v = v >= 0.f ? v : 0.01f * v;
      Ob[(long)o * N + col] = v;
    }
  }
}

// np-exact gram
__global__ __launch_bounds__(256) void gramg_k(const float* __restrict__ A,
                                               const float* __restrict__ sqb,
                                               float* __restrict__ D) {
  int m0 = blockIdx.x * 128, n0 = blockIdx.y * 128;
  __shared__ float Am[8][132];
  __shared__ float An[8][132];
  int t = threadIdx.x, tx = t & 15, ty = t >> 4;
  int cb = tx * 4;
  float g[8][8] = {};
  for (int c0 = 0; c0 < 128; c0 += 8) {
    {
      int nn = t & 127, kk0 = t >> 7;
#pragma unroll
      for (int i = 0; i < 4; ++i) {
        int kk = kk0 + i * 2;
        Am[kk][nn] = A[(long)(c0 + kk) * 2048 + m0 + nn];
        An[kk][nn] = A[(long)(c0 + kk) * 2048 + n0 + nn];
      }
    }
    __syncthreads();
#pragma unroll
    for (int kk = 0; kk < 8; ++kk) {
      float a[8], bm[8];
#pragma unroll
      for (int i = 0; i < 8; ++i) a[i] = An[kk][ty * 8 + i];
#pragma unroll
      for (int j = 0; j < 4; ++j) { bm[j] = Am[kk][cb + j]; bm[4 + j] = Am[kk][64 + cb + j]; }
#pragma unroll
      for (int i = 0; i < 8; ++i)
#pragma unroll
        for (int j = 0; j < 8; ++j)
          g[i][j] = fmaf(a[i], bm[j], g[i][j]);
    }
    __syncthreads();
  }
#pragma unroll
  for (int i = 0; i < 8; ++i) {
    int n = n0 + ty * 8 + i;
    float sn = sqb[n];
#pragma unroll
    for (int j = 0; j < 8; ++j) {
      int m = (j < 4) ? (m0 + cb + j) : (m0 + 64 + cb + (j - 4));
      float t1 = __fadd_rn(sn, sqb[m]);
      D[(long)n * 2048 + m] = __fsub_rn(t1, __fmul_rn(2.0f, g[i][j]));
    }
  }
}

// numpy npyv(AVX512) pairwise sum of squares
__global__ void sqnp_k(const float* __restrict__ x1, float* __restrict__ sq) {
  int n = blockIdx.x * 256 + threadIdx.x;
  int b = blockIdx.y;
  const float* p = x1 + (long)b * 128 * 2048 + n;
  float r[4][16];
#pragma unroll
  for (int v = 0; v < 4; ++v)
#pragma unroll
    for (int l = 0; l < 16; ++l) {
      float x = p[(long)(16 * v + l) * 2048];
      r[v][l] = __fmul_rn(x, x);
    }
#pragma unroll
  for (int v = 0; v < 4; ++v)
#pragma unroll
    for (int l = 0; l < 16; ++l) {
      float x = p[(long)(64 + 16 * v + l) * 2048];
      r[v][l] = __fadd_rn(r[v][l], __fmul_rn(x, x));
    }
  float u[16];
#pragma unroll
  for (int l = 0; l < 16; ++l)
    u[l] = __fadd_rn(__fadd_rn(r[0][l], r[1][l]), __fadd_rn(r[2][l], r[3][l]));
  float b8[8];
#pragma unroll
  for (int l = 0; l < 8; ++l) b8[l] = __fadd_rn(u[l], u[l + 8]);
  float c4[4];
#pragma unroll
  for (int l = 0; l < 4; ++l) c4[l] = __fadd_rn(b8[l], b8[l + 4]);
  float d0 = __fadd_rn(c4[0], c4[2]);
  float d1 = __fadd_rn(c4[1], c4[3]);
  sq[b * 2048 + n] = __fadd_rn(d0, d1);
}

// ---------------- f32 tiled GEMM 64x64 (Q / tail2 / tail3) ----------------
template<int ACT>
__global__ __launch_bounds__(256) void gemm_k(
    const float* __restrict__ W, const float* __restrict__ X,
    const float* __restrict__ bias, float* __restrict__ Out,
    int O, int K, int N, long sXb, long sOb, float slope)
{
  const float* Xb = X + (long)blockIdx.z * sXb;
  int n0 = blockIdx.x * 64, o0 = blockIdx.y * 64;
  __shared__ float Ws[16][68];
  __shared__ float Xs[16][68];
  int t = threadIdx.x, tx = t & 15, ty = t >> 4;
  float acc[16] = {};
  for (int k0 = 0; k0 < K; k0 += 16) {
#pragma unroll
    for (int i = 0; i < 4; ++i) {
      int l = t + i * 256, oo = l >> 4, kk = l & 15;
      int o = o0 + oo, k = k0 + kk;
      float v = 0.f;
      if (o < O && k < K) v = W[(long)o * K + k];
      Ws[kk][oo] = v;
    }
#pragma unroll
    for (int i = 0; i < 4; ++i) {
      int kk = (t >> 6) + i * 4, nn = t & 63;
      int k = k0 + kk;
      float v = 0.f;
      if (k < K) v = Xb[(long)k * N + n0 + nn];
      Xs[kk][nn] = v;
    }
    __syncthreads();
#pragma unroll
    for (int kk = 0; kk < 16; ++kk) {
      float a0 = Ws[kk][ty * 4 + 0], a1 = Ws[kk][ty * 4 + 1];
      float a2 = Ws[kk][ty * 4 + 2], a3 = Ws[kk][ty * 4 + 3];
      float b0 = Xs[kk][tx * 4 + 0], b1 = Xs[kk][tx * 4 + 1];
      float b2 = Xs[kk][tx * 4 + 2], b3 = Xs[kk][tx * 4 + 3];
      acc[0] = fmaf(a0, b0, acc[0]);   acc[1] = fmaf(a0, b1, acc[1]);
      acc[2] = fmaf(a0, b2, acc[2]);   acc[3] = fmaf(a0, b3, acc[3]);
      acc[4] = fmaf(a1, b0, acc[4]);   acc[5] = fmaf(a1, b1, acc[5]);
      acc[6] = fmaf(a1, b2, acc[6]);   acc[7] = fmaf(a1, b3, acc[7]);
      acc[8] = fmaf(a2, b0, acc[8]);   acc[9] = fmaf(a2, b1, acc[9]);
      acc[10] = fmaf(a2, b2, acc[10]); acc[11] = fmaf(a2, b3, acc[11]);
      acc[12] = fmaf(a3, b0, acc[12]); acc[13] = fmaf(a3, b1, acc[13]);
      acc[14] = fmaf(a3, b2, acc[14]); acc[15] = fmaf(a3, b3, acc[15]);
    }
    __syncthreads();
  }
#pragma unroll
  for (int i = 0; i < 4; ++i) {
    int o = o0 + ty * 4 + i;
    if (o < O) {
      float bv = bias ? bias[o] : 0.f;
#pragma unroll
      for (int j = 0; j < 4; ++j) {
        float v = acc[i * 4 + j] + bv;
        if constexpr (ACT == 1) v = v >= 0.f ? v : slope * v;
        if constexpr (ACT == 2) v = tanhf(v);
        Out[(long)blockIdx.z * sOb + (long)o * N + n0 + tx * 4 + j] = v;
      }
    }
  }
}

// ---------------- small kernels ----------------
__global__ void fill_k(float* __restrict__ out, float v, int n) {
  int id = blockIdx.x * 256 + threadIdx.x;
  if (id < n) out[id] = v;
}

__global__ void wcvt_k(const float* __restrict__ in, unsigned short* __restrict__ o, long n) {
  long id = (long)blockIdx.x * 256 + threadIdx.x;
  if (id < n) o[id] = f2b(in[id]);
}

__global__ void wpad_k(const float* __restrict__ w, float* __restrict__ wp) {
  int id = blockIdx.x * 256 + threadIdx.x;
  if (id >= 512 * 136) return;
  int o = id / 136, k = id % 136;
  wp[id] = (k < 131) ? w[o * 131 + k] : 0.f;
}

__global__ void xz_k(const float* __restrict__ x, const float* __restrict__ z,
                     float* __restrict__ xz) {
  long id = (long)blockIdx.x * 256 + threadIdx.x;
  const long TOT = 8L * 136 * 2048;
  if (id >= TOT) return;
  int n = (int)(id % 2048);
  int c = (int)((id / 2048) % 136);
  int b = (int)(id / (136L * 2048));
  float v = 0.f;
  if (c < 3) v = x[((long)b * 3 + c) * 2048 + n];
  else if (c < 131) v = z[((long)b * 128 + (c - 3)) * 2048 + n];
  xz[id] = v;
}

// split + bf16 convert: A = xw[:, :128]-xw[:, 128:], B = xw[:, 128:]
__global__ void xwsplit_k(const float* __restrict__ xw,
                          unsigned short* __restrict__ Ab,
                          unsigned short* __restrict__ Bb) {
  int id = blockIdx.x * 256 + threadIdx.x;
  if (id >= 512 * 128) return;
  int o = id / 128, c = id % 128;
  float a = xw[o * 256 + c];
  float b = xw[o * 256 + 128 + c];
  Ab[id] = f2b(a - b);
  Bb[id] = f2b(b);
}

// register-resident topk: 4 rows per block (one per wave); 11 smallest asc.
__global__ __launch_bounds__(256) void topk_k(const float* __restrict__ dist,
                                              int* __restrict__ idx) {
  int row = blockIdx.x * 4 + (threadIdx.x >> 6);
  int lane = threadIdx.x & 63;
  const float* rp = dist + (long)row * 2048;
  float v[32];
#pragma unroll
  for (int i = 0; i < 32; ++i) v[i] = rp[i * 64 + lane];
  unsigned taken = 0;
  const float INF = __builtin_inff();
  for (int r = 0; r < 11; ++r) {
    float best = INF; int bi = 0x7fffffff;
#pragma unroll
    for (int i = 0; i < 32; ++i) {
      bool free = !((taken >> i) & 1u);
      if (free && v[i] < best) { best = v[i]; bi = i; }
    }
    int gi = (bi == 0x7fffffff) ? 0x7ffffffe : bi * 64 + lane;
#pragma unroll
    for (int off = 32; off; off >>= 1) {
      float ov = __shfl_xor(best, off);
      int og = __shfl_xor(gi, off);
      if (ov < best || (ov == best && og < gi)) { best = ov; gi = og; }
    }
    if (gi >= 0 && gi < 2048) {
      if (lane == 0 && r > 0) idx[row * 10 + (r - 1)] = gi;
      if ((gi & 63) == lane) taken |= 1u << (gi >> 6);
    } else if (lane == 0 && r > 0) {
      idx[row * 10 + (r - 1)] = row;   // defensive
    }
  }
}

// G bf16: lrelu01(sc1*(Q[idx]-Q[n])+sh1)  (per batch)
__global__ void g_k(const float* __restrict__ Q, const int* __restrict__ idx,
                    const float* __restrict__ sc, const float* __restrict__ sh,
                    unsigned short* __restrict__ G) {
  long id = (long)blockIdx.x * 256 + threadIdx.x;
  const long TOT = 256L * 20480;
  if (id >= TOT) return;
  int m = (int)(id % 20480);
  int c = (int)(id / 20480);
  int j = idx[m];
  int n = m / 10;
  const float* Qc = Q + (long)c * 2048;
  float v = fmaf(sc[c], Qc[j] - Qc[n], sh[c]);
  v = v >= 0.f ? v : 0.01f * v;
  G[id] = f2b(v);
}

__global__ void redk_k(const float* __restrict__ P, const float* __restrict__ bias,
                       float* __restrict__ xo) {
  int id = blockIdx.x * 256 + threadIdx.x;
  if (id >= 512 * 2048) return;
  int o = id >> 11;
  float s = 0.f;
#pragma unroll
  for (int sp = 0; sp < 8; ++sp) s += P[(long)sp * 512 * 2048 + id];
  s += bias[o];
  xo[id] = s >= 0.f ? s : 0.2f * s;
}

// BN1 stats, Q row LDS-staged (bit-identical accumulation)
__global__ __launch_bounds__(256) void stats_qd_k(const float* __restrict__ Q,
                                                  const int* __restrict__ idx,
                                                  double* __restrict__ sum,
                                                  double* __restrict__ sumsq) {
  int c = blockIdx.x, b = blockIdx.y;
  const float* Qp = Q + ((long)b * 256 + c) * 2048;
  const int* ip = idx + (long)b * 20480;
  __shared__ float Qs[2048];
  for (int i = threadIdx.x; i < 2048; i += 256) Qs[i] = Qp[i];
  __syncthreads();
  float s = 0.f, s2 = 0.f;
  for (int m = threadIdx.x; m < 20480; m += 256) {
    float v = Qs[ip[m]] - Qs[m / 10];
    s += v; s2 = fmaf(v, v, s2);
  }
  __shared__ float ls[256], ls2[256];
  ls[threadIdx.x] = s; ls2[threadIdx.x] = s2;
  __syncthreads();
  for (int st = 128; st > 0; st >>= 1) {
    if (threadIdx.x < st) { ls[threadIdx.x] += ls[threadIdx.x + st]; ls2[threadIdx.x] += ls2[threadIdx.x + st]; }
    __syncthreads();
  }
  if (threadIdx.x == 0) { atomicAdd(&sum[c], (double)ls[0]); atomicAdd(&sumsq[c], (double)ls2[0]); }
}

// BN3 stats, R+S rows LDS-staged
__global__ __launch_bounds__(256) void stats_cx_k(const float* __restrict__ R,
                                                  const float* __restrict__ S,
                                                  const int* __restrict__ idx,
                                                  double* __restrict__ sum,
                                                  double* __restrict__ sumsq) {
  int c = blockIdx.x, b = blockIdx.y;
  const float* Rp = R + ((long)b * 512 + c) * 2048;
  const float* Sp = S + ((long)b * 512 + c) * 2048;
  const int* ip = idx + (long)b * 20480;
  __shared__ float Rs[2048], Ss[2048];
  for (int i = threadIdx.x; i < 2048; i += 256) { Rs[i] = Rp[i]; Ss[i] = Sp[i]; }
  __syncthreads();
  float s = 0.f, s2 = 0.f;
  for (int m = threadIdx.x; m < 20480; m += 256) {
    float v = Rs[m / 10] + Ss[ip[m]];
    s += v; s2 = fmaf(v, v, s2);
  }
  __shared__ float ls[256], ls2[256];
  ls[threadIdx.x] = s; ls2[threadIdx.x] = s2;
  __syncthreads();
  for (int st = 128; st > 0; st >>= 1) {
    if (threadIdx.x < st) { ls[threadIdx.x] += ls[threadIdx.x + st]; ls2[threadIdx.x] += ls2[threadIdx.x + st]; }
    __syncthreads();
  }
  if (threadIdx.x == 0) { atomicAdd(&sum[c], (double)ls[0]); atomicAdd(&sumsq[c], (double)ls2[0]); }
}

__global__ void bnfin_k(const double* __restrict__ sum, const double* __restrict__ sumsq,
                        const float* __restrict__ g, const float* __restrict__ bb,
                        float* __restrict__ sc, float* __restrict__ sh, int C, double invcnt) {
  int c = blockIdx.x * 256 + threadIdx.x;
  if (c >= C) return;
  double mean = sum[c] * invcnt;
  double var = sumsq[c] * invcnt - mean * mean;
  float rstd = (float)(1.0 / sqrt(var + 1e-5));
  float scv = g[c] * rstd;
  sc[c] = scv;
  sh[c] = bb[c] - (float)mean * scv;
}

// fused softmax + Xe (per batch): block = channel c; S row LDS-staged.
__global__ __launch_bounds__(256) void smxe_k(
    const bf16* __restrict__ wl, const float* __restrict__ sc2,
    const float* __restrict__ sh2, const float* __restrict__ R,
    const float* __restrict__ S, const int* __restrict__ ip,
    const float* __restrict__ sc3, const float* __restrict__ sh3,
    unsigned short* __restrict__ Xe) {
  int c = blockIdx.x;
  __shared__ float Ss[2048];
  const float* Sp = S + (long)c * 2048;
  const float* Rp = R + (long)c * 2048;
  for (int i = threadIdx.x; i < 2048; i += 256) Ss[i] = Sp[i];
  __syncthreads();
  float a = sc2[c], bs = sh2[c], a3 = sc3[c], b3 = sh3[c];
  const bf16* wc = wl + (long)c * 20480;
  for (int n = threadIdx.x; n < 2048; n += 256) {
    float v[10], m = -1e30f;
#pragma unroll
    for (int k = 0; k < 10; ++k) {
      float x = fmaf(a, __bfloat162float(wc[n * 10 + k]), bs);
      x = x >= 0.f ? x : 0.01f * x;
      v[k] = x; m = fmaxf(m, x);
    }
    float s = 0.f;
#pragma unroll
    for (int k = 0; k < 10; ++k) { v[k] = __expf(v[k] - m); s += v[k]; }
    float inv = 1.f / s;
    float rn = Rp[n];
#pragma unroll
    for (int k = 0; k < 10; ++k) {
      int j = ip[n * 10 + k];
      float h = fmaf(a3, rn + Ss[j], b3);
      h = h >= 0.f ? h : 0.01f * h;
      Xe[(long)(c * 10 + k) * 2048 + n] = f2b(h * (v[k] * inv));
    }
  }
}

// AdaIN in place + bf16 copy for tail1 MFMA
__global__ void adain_k(float* __restrict__ x2, const float* __restrict__ ad2,
                        unsigned short* __restrict__ x2b) {
  long id = (long)blockIdx.x * 256 + threadIdx.x;
  const long TOT = 8L * 512 * 2048;
  if (id >= TOT) return;
  int n = (int)(id & 2047);
  long t = id >> 11;
  int c = (int)(t & 511);
  int b = (int)(t >> 9);
  const float* A = ad2 + (long)b * 1024 * 2048;
  float ga = A[(long)c * 2048 + n];
  float be = A[(long)(512 + c) * 2048 + n];
  float v = fmaf(ga, x2[id], be);
  x2[id] = v;
  x2b[id] = f2b(v);
}

// ---------------- host ----------------
extern "C" void kernel_launch(void* const* d_in, const int* in_sizes, int n_in,
                              void* d_out, int out_size, void* d_ws, size_t ws_size,
                              hipStream_t stream) {
  (void)in_sizes; (void)n_in;
  const float* xin     = (const float*)d_in[0];
  const float* zin     = (const float*)d_in[1];
  const float* head_w1 = (const float*)d_in[2];
  const float* head_b1 = (const float*)d_in[3];
  const float* head_w2 = (const float*)d_in[4];
  const float* head_b2 = (const float*)d_in[5];
  const float* lat_w   = (const float*)d_in[22];
  const float* lat_b   = (const float*)d_in[23];
  const float* e2_w1   = (const float*)d_in[24];
  const float* e2_g1   = (const float*)d_in[26];
  const float* e2_bb1  = (const float*)d_in[27];
  const float* e2_w2   = (const float*)d_in[28];
  const float* e2_g2   = (const float*)d_in[30];
  const float* e2_bb2  = (const float*)d_in[31];
  const float* e2_xw   = (const float*)d_in[32];
  const float* e2_xg   = (const float*)d_in[34];
  const float* e2_xbb  = (const float*)d_in[35];
  const float* e2_ow   = (const float*)d_in[36];
  const float* e2_ob   = (const float*)d_in[37];
  const float* ad2_w   = (const float*)d_in[38];
  const float* ad2_b   = (const float*)d_in[39];
  const float* tail_w1 = (const float*)d_in[40];
  const float* tail_b1 = (const float*)d_in[41];
  const float* tail_w2 = (const float*)d_in[42];
  const float* tail_b2 = (const float*)d_in[43];
  const float* tail_w3 = (const float*)d_in[44];
  const float* tail_b3 = (const float*)d_in[45];
  float* out = (float*)d_out;

  // ---- arena ----
  char* ws = (char*)d_ws;
  size_t off = 0;
  auto A = [&](size_t bytes) { size_t r = off; off += (bytes + 255) & ~(size_t)255; return r; };
  size_t oStats = A(20480);
  size_t oSc1 = A(1024), oSh1 = A(1024);
  size_t oSc2 = A(2048), oSh2 = A(2048);
  size_t oSc3 = A(2048), oSh3 = A(2048);
  size_t oXwAb = A(512 * 128 * 2), oXwBb = A(512 * 128 * 2);
  size_t oWp  = A(512 * 136 * 4);
  size_t oW2b = A(512 * 256 * 2);
  size_t oOwb = A(512L * 5120 * 2);
  size_t oAdb = A(1024 * 512 * 2);
  size_t oTw1b = A(256 * 512 * 2);
  size_t oSq  = A(8L * 2048 * 4);
  size_t oIdx = A(8L * 2048 * 10 * 4);
  size_t oX1  = A(8L * 128 * 2048 * 4);
  size_t oQ   = A(8L * 256 * 2048 * 4);
  size_t oR   = A(8L * 512 * 2048 * 4);
  size_t oS   = A(8L * 512 * 2048 * 4);
  size_t oStyle = A(8L * 512 * 2048 * 4);
  size_t oX2  = A(8L * 512 * 2048 * 4);
  size_t oSL  = A(83886080 + 512);
  size_t offBase = off;
  size_t oW2all = A(8L * 512 * 20480 * 2);
  size_t offFull = off;
  if (ws_size < offBase) {
    fill_k<<<(out_size + 255) / 256, 256, 0, stream>>>(out, (float)(ws_size >> 20), out_size);
    return;
  }
  bool pathA = ws_size >= offFull;

  double* sum1 = (double*)(ws + oStats);
  double* sumsq1 = sum1 + 256;
  double* sum2 = sumsq1 + 256;
  double* sumsq2 = sum2 + 512;
  double* sum3 = sumsq2 + 512;
  double* sumsq3 = sum3 + 512;
  float* sc1 = (float*)(ws + oSc1); float* sh1 = (float*)(ws + oSh1);
  float* sc2 = (float*)(ws + oSc2); float* sh2 = (float*)(ws + oSh2);
  float* sc3 = (float*)(ws + oSc3); float* sh3 = (float*)(ws + oSh3);
  unsigned short* xwAb = (unsigned short*)(ws + oXwAb);
  unsigned short* xwBb = (unsigned short*)(ws + oXwBb);
  float* Wp = (float*)(ws + oWp);
  unsigned short* w2b = (unsigned short*)(ws + oW2b);
  unsigned short* owb = (unsigned short*)(ws + oOwb);
  unsigned short* adb = (unsigned short*)(ws + oAdb);
  unsigned short* tw1b = (unsigned short*)(ws + oTw1b);
  float* sq = (float*)(ws + oSq);
  int* idx = (int*)(ws + oIdx);
  float* x1 = (float*)(ws + oX1);
  float* Q = (float*)(ws + oQ);
  float* R = (float*)(ws + oR);
  float* S = (float*)(ws + oS);
  float* style = (float*)(ws + oStyle);
  float* style1 = (float*)(ws + oX2);
  float* x2 = (float*)(ws + oX2);
  char* SL = ws + oSL;
  // SL (84MB) schedule:
  //  xzp [0,8.9) -> dist [0,16.8) + x1b [17,21.3) -> per-batch:
  //  G [0,10.5) -> w2lb [44,65) -> Xe [0,21) -> P [44,77.5) -> redk
  //  -> ad2out [0,67) + x2b [67,83.8) -> t1 [0,16.8) + t2 [21,25.2)
  float* xzp = (float*)(SL);
  float* dist = (float*)(SL);
  unsigned short* x1b = (unsigned short*)(SL + 17825792);
  unsigned short* G = (unsigned short*)(SL);
  bf16* w2lb = (bf16*)(SL + 46137344);
  unsigned short* Xeb = (unsigned short*)(SL);
  float* P = (float*)(SL + 46137344);
  float* ad2out = (float*)(SL);
  unsigned short* x2b = (unsigned short*)(SL + 70254592);
  float* t1 = (float*)(SL);
  float* t2 = (float*)(SL + 20971520);
  bf16* w2all = (bf16*)(ws + oW2all);

  hipMemsetAsync(ws + oStats, 0, 20480, stream);

  // weight conversions
  wcvt_k<<<(512 * 256 + 255) / 256, 256, 0, stream>>>(e2_w2, w2b, 512 * 256);
  wcvt_k<<<(int)((512L * 5120 + 255) / 256), 256, 0, stream>>>(e2_ow, owb, 512L * 5120);
  wcvt_k<<<(1024 * 512 + 255) / 256, 256, 0, stream>>>(ad2_w, adb, 1024 * 512);
  wcvt_k<<<(256 * 512 + 255) / 256, 256, 0, stream>>>(tail_w1, tw1b, 256 * 512);

  // ---- np-exact head (f32 gemm2, bit-identical chain) ----
  wpad_k<<<(512 * 136 + 255) / 256, 256, 0, stream>>>(head_w1, Wp);
  xz_k<<<(8L * 136 * 2048 + 255) / 256, 256, 0, stream>>>(xin, zin, xzp);
  gemm2_k<1><<<dim3(16, 4, 8), 256, 0, stream>>>(
      Wp, xzp, head_b1, style1, 512, 136, 2048, 136, 136L * 2048, 512L * 2048);
  gemm2_k<1><<<dim3(16, 4, 8), 256, 0, stream>>>(
      head_w2, style1, head_b2, style, 512, 512, 2048, 512, 512L * 2048, 512L * 2048);
  gemm2_k<0><<<dim3(16, 1, 8), 256, 0, stream>>>(
      lat_w, style, lat_b, x1, 128, 512, 2048, 512, 512L * 2048, 128L * 2048);

  // bf16 copy of x1 for R/S MFMA
  wcvt_k<<<(int)((8L * 128 * 2048 + 255) / 256), 256, 0, stream>>>(x1, x1b, 8L * 128 * 2048);

  // ---- np-exact kNN ----
  sqnp_k<<<dim3(8, 8), 256, 0, stream>>>(x1, sq);
  for (int b = 0; b < 8; ++b) {
    gramg_k<<<dim3(16, 16), 256, 0, stream>>>(
        x1 + (long)b * 128 * 2048, sq + b * 2048, dist);
    topk_k<<<512, 256, 0, stream>>>(dist, idx + (long)b * 20480);
  }

  // ---- Q (f32); BN1 stats ----
  gemm_k<0><<<dim3(32, 4, 8), 256, 0, stream>>>(
      e2_w1, x1, nullptr, Q, 256, 128, 2048, 128L * 2048, 256L * 2048, 0.f);
  stats_qd_k<<<dim3(256, 8), 256, 0, stream>>>(Q, idx, sum1, sumsq1);
  bnfin_k<<<1, 256, 0, stream>>>(sum1, sumsq1, e2_g1, e2_bb1, sc1, sh1, 256, 1.0 / 163840.0);

  // ---- conv_x via MFMA: R, S; BN3 stats ----
  xwsplit_k<<<(512 * 128 + 255) / 256, 256, 0, stream>>>(e2_xw, xwAb, xwBb);
  mfma_k<0, 0, 0, unsigned short, float><<<dim3(16, 4, 8), 256, 0, stream>>>(
      xwAb, x1b, nullptr, R, 512, 128, 2048, 128, 128L * 2048, 512L * 2048,
      nullptr, nullptr);
  mfma_k<0, 0, 0, unsigned short, float><<<dim3(16, 4, 8), 256, 0, stream>>>(
      xwBb, x1b, nullptr, S, 512, 128, 2048, 128, 128L * 2048, 512L * 2048,
      nullptr, nullptr);
  stats_cx_k<<<dim3(512, 8), 256, 0, stream>>>(R, S, idx, sum3, sumsq3);
  bnfin_k<<<2, 256, 0, stream>>>(sum3, sumsq3, e2_xg, e2_xbb, sc3, sh3, 512, 1.0 / 163840.0);

  if (pathA) {
    // single w2 pass: bf16 logits all-batch + stats
    for (int b = 0; b < 8; ++b) {
      g_k<<<20480, 256, 0, stream>>>(Q + (long)b * 256 * 2048, idx + (long)b * 20480,
                                     sc1, sh1, G);
      mfma_k<2, 0, 0, unsigned short, bf16><<<dim3(160, 4, 1), 256, 0, stream>>>(
          w2b, G, nullptr, w2all + (long)b * 512 * 20480, 512, 256, 20480, 256,
          0, 0, sum2, sumsq2);
    }
    bnfin_k<<<2, 256, 0, stream>>>(sum2, sumsq2, e2_g2, e2_bb2, sc2, sh2, 512, 1.0 / 163840.0);
    for (int b = 0; b < 8; ++b) {
      smxe_k<<<512, 256, 0, stream>>>(
          w2all + (long)b * 512 * 20480, sc2, sh2,
          R + (long)b * 512 * 2048, S + (long)b * 512 * 2048,
          idx + (long)b * 20480, sc3, sh3, Xeb);
      mfma_k<0, 1, 0, unsigned short, float><<<dim3(16, 4, 8), 256, 0, stream>>>(
          owb, Xeb, nullptr, P, 512, 5120, 2048, 640, 0, 512L * 2048,
          nullptr, nullptr);
      redk_k<<<(512 * 2048 + 255) / 256, 256, 0, stream>>>(
          P, e2_ob, x2 + (long)b * 512 * 2048);
    }
  } else {
    // two-pass w2 (stats, then value+bf16 logits per batch)
    for (int b = 0; b < 8; ++b) {
      g_k<<<20480, 256, 0, stream>>>(Q + (long)b * 256 * 2048, idx + (long)b * 20480,
                                     sc1, sh1, G);
      mfma_k<1, 0, 0, unsigned short, float><<<dim3(160, 4, 1), 256, 0, stream>>>(
          w2b, G, nullptr, nullptr, 512, 256, 20480, 256, 0, 0, sum2, sumsq2);
    }
    bnfin_k<<<2, 256, 0, stream>>>(sum2, sumsq2, e2_g2, e2_bb2, sc2, sh2, 512, 1.0 / 163840.0);
    for (int b = 0; b < 8; ++b) {
      g_k<<<20480, 256, 0, stream>>>(Q + (long)b * 256 * 2048, idx + (long)b * 20480,
                                     sc1, sh1, G);
      mfma_k<0, 0, 0, unsigned short, bf16><<<dim3(160, 4, 1), 256, 0, stream>>>(
          w2b, G, nullptr, w2lb, 512, 256, 20480, 256, 0, 0, nullptr, nullptr);
      smxe_k<<<512, 256, 0, stream>>>(
          w2lb, sc2, sh2,
          R + (long)b * 512 * 2048, S + (long)b * 512 * 2048,
          idx + (long)b * 20480, sc3, sh3, Xeb);
      mfma_k<0, 1, 0, unsigned short, float><<<dim3(16, 4, 8), 256, 0, stream>>>(
          owb, Xeb, nullptr, P, 512, 5120, 2048, 640, 0, 512L * 2048,
          nullptr, nullptr);
      redk_k<<<(512 * 2048 + 255) / 256, 256, 0, stream>>>(
          P, e2_ob, x2 + (long)b * 512 * 2048);
    }
  }

  // ---- AdaIN2 (MFMA) + in-place apply + bf16 copy ----
  mfma_k<0, 0, 0, float, float><<<dim3(16, 8, 8), 256, 0, stream>>>(
      adb, style, ad2_b, ad2out, 1024, 512, 2048, 512, 512L * 2048, 1024L * 2048,
      nullptr, nullptr);
  adain_k<<<(8L * 512 * 2048 + 255) / 256, 256, 0, stream>>>(x2, ad2out, x2b);

  // ---- tail: t1 via MFMA (lrelu fused), t2/t3 f32 ----
  mfma_k<0, 0, 1, unsigned short, float><<<dim3(16, 2, 8), 256, 0, stream>>>(
      tw1b, x2b, tail_b1, t1, 256, 512, 2048, 512, 512L * 2048, 256L * 2048,
      nullptr, nullptr);
  gemm_k<1><<<dim3(32, 1, 8), 256, 0, stream>>>(
      tail_w2, t1, tail_b2, t2, 64, 256, 2048, 256L * 2048, 64L * 2048, 0.01f);
  gemm_k<2><<<dim3(32, 1, 8), 256, 0, stream>>>(
      tail_w3, t2, tail_b3, out, 3, 64, 2048, 64L * 2048, 3L * 2048, 0.f);
}

// Round 16
// 1621.728 us; speedup vs baseline: 3.2332x; 1.1693x over previous
//
#include <hip/hip_runtime.h>
#include <hip/hip_bf16.h>

// SP_DecoderLight forward, MI355X. Round 16.
// R15: 1896us. head f32 at 88% peak (hard floor, rank-exact). conv MFMA
// staging-instruction-bound (16 half-width loads + 8-way-conflict stores
// per 32k). Changes: (1) paired-uint B-stage (ushort); (2) kNN z=2;
// (3) w2-stats 2-batch z=2; (4) pass2 2-batch groups, conv z=batch*splitk4,
// halved P traffic. No numeric-path changes (absmax should hold ~1.5e-3).

using bf16 = __hip_bfloat16;
typedef short bf8_t __attribute__((ext_vector_type(8)));
typedef float f4_t __attribute__((ext_vector_type(4)));

#define DEV static __device__ __forceinline__
DEV void stf(float* p, float v) { *p = v; }
DEV void stf(bf16* p, float v) { *p = __float2bfloat16(v); }
DEV unsigned short f2b(float f) { bf16 h = __float2bfloat16(f); return *reinterpret_cast<unsigned short*>(&h); }
DEV unsigned short ldb(const float* p) { return f2b(*p); }
DEV unsigned short ldb(const unsigned short* p) { return *p; }

// ---------------- MFMA bf16 GEMM 128x128 ----------------
// OMODE: 0 store, 1 stats-only. SPLITK: 0 z=batch (X+=z*sXz);
// 1 z=splitk (kOff=z*kLen); 2 z=batch*4+split (kOff=(z&3)*kLen,
//   X+=(z>>2)*sXz, Out+=z*sOz).
template<int OMODE, int SPLITK, int ACT, typename TB, typename TO>
__global__ __launch_bounds__(256) void mfma_k(
    const unsigned short* __restrict__ Wb, const TB* __restrict__ X,
    const float* __restrict__ bias, TO* __restrict__ Out,
    int O, int K, int N, int kLen, long sXz, long sOz,
    double* __restrict__ gsum, double* __restrict__ gsq)
{
  int kOff = 0;
  if constexpr (SPLITK == 1) { kOff = blockIdx.z * kLen; }
  else if constexpr (SPLITK == 2) { kOff = (blockIdx.z & 3) * kLen; X += (long)(blockIdx.z >> 2) * sXz; }
  else { X += (long)blockIdx.z * sXz; }
  int n0 = blockIdx.x * 128, o0 = blockIdx.y * 128;
  __shared__ unsigned short As[128][40];
  __shared__ unsigned short Bs[128][40];
  __shared__ float ssum[128], ssq[128];
  int t = threadIdx.x;
  int w = t >> 6, l = t & 63;
  int lr = l & 15, lk = l >> 4;
  f4_t acc[2][8];
#pragma unroll
  for (int mi = 0; mi < 2; ++mi)
#pragma unroll
    for (int nj = 0; nj < 8; ++nj) acc[mi][nj] = (f4_t){0.f, 0.f, 0.f, 0.f};

  for (int k0 = kOff; k0 < kOff + kLen; k0 += 32) {
    {  // stage A (W): 4 bf16 per 8B load/store
      int ro = t >> 3, kq = (t & 7) * 4;
#pragma unroll
      for (int i = 0; i < 4; ++i) {
        int o = ro + i * 32;
        unsigned long long v = *reinterpret_cast<const unsigned long long*>(
            &Wb[(long)(o0 + o) * K + k0 + kq]);
        *reinterpret_cast<unsigned long long*>(&As[o][kq]) = v;
      }
    }
    if constexpr (sizeof(TB) == 2) {   // stage B: paired-n uint loads
      int nn = (t & 63) * 2, kg = (t >> 6) * 8;
#pragma unroll
      for (int i = 0; i < 8; ++i) {
        int kk = kg + i;
        unsigned v = *reinterpret_cast<const unsigned*>(
            &X[(long)(k0 + kk) * N + n0 + nn]);
        Bs[nn][kk] = (unsigned short)(v & 0xffffu);
        Bs[nn + 1][kk] = (unsigned short)(v >> 16);
      }
    } else {                           // float source (adain style)
      int nn = t & 127, kb = (t >> 7) * 2;
#pragma unroll
      for (int i = 0; i < 8; ++i) {
        int kk = kb + i * 4;
        unsigned short b0 = ldb(&X[(long)(k0 + kk) * N + n0 + nn]);
        unsigned short b1 = ldb(&X[(long)(k0 + kk + 1) * N + n0 + nn]);
        *reinterpret_cast<unsigned int*>(&Bs[nn][kk]) =
            (unsigned)b0 | ((unsigned)b1 << 16);
      }
    }
    __syncthreads();
    bf8_t a[2], b[8];
#pragma unroll
    for (int mi = 0; mi < 2; ++mi)
      a[mi] = *reinterpret_cast<const bf8_t*>(&As[w * 32 + mi * 16 + lr][lk * 8]);
#pragma unroll
    for (int nj = 0; nj < 8; ++nj)
      b[nj] = *reinterpret_cast<const bf8_t*>(&Bs[nj * 16 + lr][lk * 8]);
#pragma unroll
    for (int mi = 0; mi < 2; ++mi)
#pragma unroll
      for (int nj = 0; nj < 8; ++nj)
        acc[mi][nj] = __builtin_amdgcn_mfma_f32_16x16x32_bf16(
            a[mi], b[nj], acc[mi][nj], 0, 0, 0);
    __syncthreads();
  }
  if constexpr (OMODE == 1) {
    if (t < 128) { ssum[t] = 0.f; ssq[t] = 0.f; }
    __syncthreads();
#pragma unroll
    for (int mi = 0; mi < 2; ++mi)
#pragma unroll
      for (int jj = 0; jj < 4; ++jj) {
        float s = 0.f, s2 = 0.f;
#pragma unroll
        for (int nj = 0; nj < 8; ++nj) {
          float v = acc[mi][nj][jj];
          s += v; s2 = fmaf(v, v, s2);
        }
#pragma unroll
        for (int off = 1; off < 16; off <<= 1) {
          s += __shfl_xor(s, off);
          s2 += __shfl_xor(s2, off);
        }
        if (lr == 0) {
          int oi = w * 32 + mi * 16 + lk * 4 + jj;
          atomicAdd(&ssum[oi], s);
          atomicAdd(&ssq[oi], s2);
        }
      }
    __syncthreads();
    if (t < 128) {
      atomicAdd(&gsum[o0 + t], (double)ssum[t]);
      atomicAdd(&gsq[o0 + t], (double)ssq[t]);
    }
  } else {
    TO* Ob = Out + (long)blockIdx.z * sOz;
#pragma unroll
    for (int mi = 0; mi < 2; ++mi)
#pragma unroll
      for (int nj = 0; nj < 8; ++nj)
#pragma unroll
        for (int jj = 0; jj < 4; ++jj) {
          int o = o0 + w * 32 + mi * 16 + lk * 4 + jj;
          int n = n0 + nj * 16 + lr;
          float v = acc[mi][nj][jj] + (bias ? bias[o] : 0.f);
          if constexpr (ACT == 1) v = v >= 0.f ? v : 0.01f * v;
          stf(&Ob[(long)o * N + n], v);
        }
  }
}

// ---------------- f32 tiled GEMM 128x128 (np-exact chain; head) -----------
template<int ACT>
__global__ __launch_bounds__(256) void gemm2_k(
    const float* __restrict__ W, const float* __restrict__ X,
    const float* __restrict__ bias, float* __restrict__ Out,
    int O, int K, int N, int kLen, long sXz, long sOz)
{
  X += (long)blockIdx.z * sXz;
  int n0 = blockIdx.x * 128, o0 = blockIdx.y * 128;
  __shared__ float Ws[8][132];
  __shared__ float Xs[8][132];
  int t = threadIdx.x, tx = t & 15, ty = t >> 4;
  int cb = tx * 4;
  float acc[8][8] = {};
  for (int k0 = 0; k0 < kLen; k0 += 8) {
    {
      int kk = t & 7, oo0 = t >> 3;
#pragma unroll
      for (int i = 0; i < 4; ++i) {
        int oo = oo0 + i * 32;
        Ws[kk][oo] = W[(long)(o0 + oo) * K + k0 + kk];
      }
    }
    {
      int nn = t & 127, kk0 = t >> 7;
#pragma unroll
      for (int i = 0; i < 4; ++i) {
        int kk = kk0 + i * 2;
        Xs[kk][nn] = X[(long)(k0 + kk) * N + n0 + nn];
      }
    }
    __syncthreads();
#pragma unroll
    for (int kk = 0; kk < 8; ++kk) {
      float a[8], bx[8];
#pragma unroll
      for (int i = 0; i < 8; ++i) a[i] = Ws[kk][ty * 8 + i];
#pragma unroll
      for (int j = 0; j < 4; ++j) { bx[j] = Xs[kk][cb + j]; bx[4 + j] = Xs[kk][64 + cb + j]; }
#pragma unroll
      for (int i = 0; i < 8; ++i)
#pragma unroll
        for (int j = 0; j < 8; ++j)
          acc[i][j] = fmaf(a[i], bx[j], acc[i][j]);
    }
    __syncthreads();
  }
  float* Ob = Out + (long)blockIdx.z * sOz;
#pragma unroll
  for (int i = 0; i < 8; ++i) {
    int o = o0 + ty * 8 + i;
    float bv = bias ? bias[o] : 0.f;
#pragma unroll
    for (int j = 0; j < 8; ++j) {
      int col = (j < 4) ? (n0 + cb + j) : (n0 + 64 + cb + (j - 4));
      float v = acc[i][j] + bv;
      if constexpr (ACT == 1) v = v >= 0.f ? v : 0.01f * v;
      Ob[(long)o * N + col] = v;
    }
  }
}

// np-exact gram (z = batch pair offset)
__global__ __launch_bounds__(256) void gramg_k(const float* __restrict__ A,
                                               const float* __restrict__ sqb,
                                               float* __restrict__ D) {
  A += (long)blockIdx.z * 128 * 2048;
  sqb += (long)blockIdx.z * 2048;
  D += (long)blockIdx.z * 2048 * 2048;
  int m0 = blockIdx.x * 128, n0 = blockIdx.y * 128;
  __shared__ float Am[8][132];
  __shared__ float An[8][132];
  int t = threadIdx.x, tx = t & 15, ty = t >> 4;
  int cb = tx * 4;
  float g[8][8] = {};
  for (int c0 = 0; c0 < 128; c0 += 8) {
    {
      int nn = t & 127, kk0 = t >> 7;
#pragma unroll
      for (int i = 0; i < 4; ++i) {
        int kk = kk0 + i * 2;
        Am[kk][nn] = A[(long)(c0 + kk) * 2048 + m0 + nn];
        An[kk][nn] = A[(long)(c0 + kk) * 2048 + n0 + nn];
      }
    }
    __syncthreads();
#pragma unroll
    for (int kk = 0; kk < 8; ++kk) {
      float a[8], bm[8];
#pragma unroll
      for (int i = 0; i < 8; ++i) a[i] = An[kk][ty * 8 + i];
#pragma unroll
      for (int j = 0; j < 4; ++j) { bm[j] = Am[kk][cb + j]; bm[4 + j] = Am[kk][64 + cb + j]; }
#pragma unroll
      for (int i = 0; i < 8; ++i)
#pragma unroll
        for (int j = 0; j < 8; ++j)
          g[i][j] = fmaf(a[i], bm[j], g[i][j]);
    }
    __syncthreads();
  }
#pragma unroll
  for (int i = 0; i < 8; ++i) {
    int n = n0 + ty * 8 + i;
    float sn = sqb[n];
#pragma unroll
    for (int j = 0; j < 8; ++j) {
      int m = (j < 4) ? (m0 + cb + j) : (m0 + 64 + cb + (j - 4));
      float t1 = __fadd_rn(sn, sqb[m]);
      D[(long)n * 2048 + m] = __fsub_rn(t1, __fmul_rn(2.0f, g[i][j]));
    }
  }
}

// numpy npyv(AVX512) pairwise sum of squares
__global__ void sqnp_k(const float* __restrict__ x1, float* __restrict__ sq) {
  int n = blockIdx.x * 256 + threadIdx.x;
  int b = blockIdx.y;
  const float* p = x1 + (long)b * 128 * 2048 + n;
  float r[4][16];
#pragma unroll
  for (int v = 0; v < 4; ++v)
#pragma unroll
    for (int l = 0; l < 16; ++l) {
      float x = p[(long)(16 * v + l) * 2048];
      r[v][l] = __fmul_rn(x, x);
    }
#pragma unroll
  for (int v = 0; v < 4; ++v)
#pragma unroll
    for (int l = 0; l < 16; ++l) {
      float x = p[(long)(64 + 16 * v + l) * 2048];
      r[v][l] = __fadd_rn(r[v][l], __fmul_rn(x, x));
    }
  float u[16];
#pragma unroll
  for (int l = 0; l < 16; ++l)
    u[l] = __fadd_rn(__fadd_rn(r[0][l], r[1][l]), __fadd_rn(r[2][l], r[3][l]));
  float b8[8];
#pragma unroll
  for (int l = 0; l < 8; ++l) b8[l] = __fadd_rn(u[l], u[l + 8]);
  float c4[4];
#pragma unroll
  for (int l = 0; l < 4; ++l) c4[l] = __fadd_rn(b8[l], b8[l + 4]);
  float d0 = __fadd_rn(c4[0], c4[2]);
  float d1 = __fadd_rn(c4[1], c4[3]);
  sq[b * 2048 + n] = __fadd_rn(d0, d1);
}

// ---------------- f32 tiled GEMM 64x64 (Q / tail2 / tail3) ----------------
template<int ACT>
__global__ __launch_bounds__(256) void gemm_k(
    const float* __restrict__ W, const float* __restrict__ X,
    const float* __restrict__ bias, float* __restrict__ Out,
    int O, int K, int N, long sXb, long sOb, float slope)
{
  const float* Xb = X + (long)blockIdx.z * sXb;
  int n0 = blockIdx.x * 64, o0 = blockIdx.y * 64;
  __shared__ float Ws[16][68];
  __shared__ float Xs[16][68];
  int t = threadIdx.x, tx = t & 15, ty = t >> 4;
  float acc[16] = {};
  for (int k0 = 0; k0 < K; k0 += 16) {
#pragma unroll
    for (int i = 0; i < 4; ++i) {
      int l = t + i * 256, oo = l >> 4, kk = l & 15;
      int o = o0 + oo, k = k0 + kk;
      float v = 0.f;
      if (o < O && k < K) v = W[(long)o * K + k];
      Ws[kk][oo] = v;
    }
#pragma unroll
    for (int i = 0; i < 4; ++i) {
      int kk = (t >> 6) + i * 4, nn = t & 63;
      int k = k0 + kk;
      float v = 0.f;
      if (k < K) v = Xb[(long)k * N + n0 + nn];
      Xs[kk][nn] = v;
    }
    __syncthreads();
#pragma unroll
    for (int kk = 0; kk < 16; ++kk) {
      float a0 = Ws[kk][ty * 4 + 0], a1 = Ws[kk][ty * 4 + 1];
      float a2 = Ws[kk][ty * 4 + 2], a3 = Ws[kk][ty * 4 + 3];
      float b0 = Xs[kk][tx * 4 + 0], b1 = Xs[kk][tx * 4 + 1];
      float b2 = Xs[kk][tx * 4 + 2], b3 = Xs[kk][tx * 4 + 3];
      acc[0] = fmaf(a0, b0, acc[0]);   acc[1] = fmaf(a0, b1, acc[1]);
      acc[2] = fmaf(a0, b2, acc[2]);   acc[3] = fmaf(a0, b3, acc[3]);
      acc[4] = fmaf(a1, b0, acc[4]);   acc[5] = fmaf(a1, b1, acc[5]);
      acc[6] = fmaf(a1, b2, acc[6]);   acc[7] = fmaf(a1, b3, acc[7]);
      acc[8] = fmaf(a2, b0, acc[8]);   acc[9] = fmaf(a2, b1, acc[9]);
      acc[10] = fmaf(a2, b2, acc[10]); acc[11] = fmaf(a2, b3, acc[11]);
      acc[12] = fmaf(a3, b0, acc[12]); acc[13] = fmaf(a3, b1, acc[13]);
      acc[14] = fmaf(a3, b2, acc[14]); acc[15] = fmaf(a3, b3, acc[15]);
    }
    __syncthreads();
  }
#pragma unroll
  for (int i = 0; i < 4; ++i) {
    int o = o0 + ty * 4 + i;
    if (o < O) {
      float bv = bias ? bias[o] : 0.f;
#pragma unroll
      for (int j = 0; j < 4; ++j) {
        float v = acc[i * 4 + j] + bv;
        if constexpr (ACT == 1) v = v >= 0.f ? v : slope * v;
        if constexpr (ACT == 2) v = tanhf(v);
        Out[(long)blockIdx.z * sOb + (long)o * N + n0 + tx * 4 + j] = v;
      }
    }
  }
}

// ---------------- small kernels ----------------
__global__ void fill_k(float* __restrict__ out, float v, int n) {
  int id = blockIdx.x * 256 + threadIdx.x;
  if (id < n) out[id] = v;
}

__global__ void wcvt_k(const float* __restrict__ in, unsigned short* __restrict__ o, long n) {
  long id = (long)blockIdx.x * 256 + threadIdx.x;
  if (id < n) o[id] = f2b(in[id]);
}

__global__ void wpad_k(const float* __restrict__ w, float* __restrict__ wp) {
  int id = blockIdx.x * 256 + threadIdx.x;
  if (id >= 512 * 136) return;
  int o = id / 136, k = id % 136;
  wp[id] = (k < 131) ? w[o * 131 + k] : 0.f;
}

__global__ void xz_k(const float* __restrict__ x, const float* __restrict__ z,
                     float* __restrict__ xz) {
  long id = (long)blockIdx.x * 256 + threadIdx.x;
  const long TOT = 8L * 136 * 2048;
  if (id >= TOT) return;
  int n = (int)(id % 2048);
  int c = (int)((id / 2048) % 136);
  int b = (int)(id / (136L * 2048));
  float v = 0.f;
  if (c < 3) v = x[((long)b * 3 + c) * 2048 + n];
  else if (c < 131) v = z[((long)b * 128 + (c - 3)) * 2048 + n];
  xz[id] = v;
}

__global__ void xwsplit_k(const float* __restrict__ xw,
                          unsigned short* __restrict__ Ab,
                          unsigned short* __restrict__ Bb) {
  int id = blockIdx.x * 256 + threadIdx.x;
  if (id >= 512 * 128) return;
  int o = id / 128, c = id % 128;
  float a = xw[o * 256 + c];
  float b = xw[o * 256 + 128 + c];
  Ab[id] = f2b(a - b);
  Bb[id] = f2b(b);
}

// register-resident topk over (grid*4) rows of a contiguous dist region
__global__ __launch_bounds__(256) void topk_k(const float* __restrict__ dist,
                                              int* __restrict__ idx) {
  int row = blockIdx.x * 4 + (threadIdx.x >> 6);
  int lane = threadIdx.x & 63;
  const float* rp = dist + (long)row * 2048;
  float v[32];
#pragma unroll
  for (int i = 0; i < 32; ++i) v[i] = rp[i * 64 + lane];
  unsigned taken = 0;
  const float INF = __builtin_inff();
  for (int r = 0; r < 11; ++r) {
    float best = INF; int bi = 0x7fffffff;
#pragma unroll
    for (int i = 0; i < 32; ++i) {
      bool free = !((taken >> i) & 1u);
      if (free && v[i] < best) { best = v[i]; bi = i; }
    }
    int gi = (bi == 0x7fffffff) ? 0x7ffffffe : bi * 64 + lane;
#pragma unroll
    for (int off = 32; off; off >>= 1) {
      float ov = __shfl_xor(best, off);
      int og = __shfl_xor(gi, off);
      if (ov < best || (ov == best && og < gi)) { best = ov; gi = og; }
    }
    if (gi >= 0 && gi < 2048) {
      if (lane == 0 && r > 0) idx[row * 10 + (r - 1)] = gi;
      if ((gi & 63) == lane) taken |= 1u << (gi >> 6);
    } else if (lane == 0 && r > 0) {
      idx[row * 10 + (r - 1)] = row & 2047;
    }
  }
}

// G bf16 over nb batches: G[b][c][m] = lrelu01(sc1[c]*(Q[b][c][idx]-Q[b][c][n])+sh1[c])
__global__ void g2_k(const float* __restrict__ Q, const int* __restrict__ idx,
                     const float* __restrict__ sc, const float* __restrict__ sh,
                     unsigned short* __restrict__ G, int nb) {
  long id = (long)blockIdx.x * 256 + threadIdx.x;
  const long per = 256L * 20480;
  if (id >= (long)nb * per) return;
  int b = (int)(id / per);
  long r = id % per;
  int c = (int)(r / 20480);
  int m = (int)(r % 20480);
  int j = idx[(long)b * 20480 + m];
  int n = m / 10;
  const float* Qc = Q + (long)b * 256 * 2048 + (long)c * 2048;
  float v = fmaf(sc[c], Qc[j] - Qc[n], sh[c]);
  v = v >= 0.f ? v : 0.01f * v;
  G[id] = f2b(v);
}

// reduce 4 split-K partials for 2 batches; lrelu(0.2)
__global__ void redk2_k(const float* __restrict__ P, const float* __restrict__ bias,
                        float* __restrict__ xo) {
  int id = blockIdx.x * 256 + threadIdx.x;
  if (id >= 2 * 512 * 2048) return;
  int bi = id / (512 * 2048);
  int r = id % (512 * 2048);
  int o = r >> 11;
  float s = 0.f;
#pragma unroll
  for (int sp = 0; sp < 4; ++sp) s += P[(long)(bi * 4 + sp) * 512 * 2048 + r];
  s += bias[o];
  xo[(long)bi * 512 * 2048 + r] = s >= 0.f ? s : 0.2f * s;
}

// BN1 stats, Q row LDS-staged
__global__ __launch_bounds__(256) void stats_qd_k(const float* __restrict__ Q,
                                                  const int* __restrict__ idx,
                                                  double* __restrict__ sum,
                                                  double* __restrict__ sumsq) {
  int c = blockIdx.x, b = blockIdx.y;
  const float* Qp = Q + ((long)b * 256 + c) * 2048;
  const int* ip = idx + (long)b * 20480;
  __shared__ float Qs[2048];
  for (int i = threadIdx.x; i < 2048; i += 256) Qs[i] = Qp[i];
  __syncthreads();
  float s = 0.f, s2 = 0.f;
  for (int m = threadIdx.x; m < 20480; m += 256) {
    float v = Qs[ip[m]] - Qs[m / 10];
    s += v; s2 = fmaf(v, v, s2);
  }
  __shared__ float ls[256], ls2[256];
  ls[threadIdx.x] = s; ls2[threadIdx.x] = s2;
  __syncthreads();
  for (int st = 128; st > 0; st >>= 1) {
    if (threadIdx.x < st) { ls[threadIdx.x] += ls[threadIdx.x + st]; ls2[threadIdx.x] += ls2[threadIdx.x + st]; }
    __syncthreads();
  }
  if (threadIdx.x == 0) { atomicAdd(&sum[c], (double)ls[0]); atomicAdd(&sumsq[c], (double)ls2[0]); }
}

// BN3 stats, R+S rows LDS-staged
__global__ __launch_bounds__(256) void stats_cx_k(const float* __restrict__ R,
                                                  const float* __restrict__ S,
                                                  const int* __restrict__ idx,
                                                  double* __restrict__ sum,
                                                  double* __restrict__ sumsq) {
  int c = blockIdx.x, b = blockIdx.y;
  const float* Rp = R + ((long)b * 512 + c) * 2048;
  const float* Sp = S + ((long)b * 512 + c) * 2048;
  const int* ip = idx + (long)b * 20480;
  __shared__ float Rs[2048], Ss[2048];
  for (int i = threadIdx.x; i < 2048; i += 256) { Rs[i] = Rp[i]; Ss[i] = Sp[i]; }
  __syncthreads();
  float s = 0.f, s2 = 0.f;
  for (int m = threadIdx.x; m < 20480; m += 256) {
    float v = Rs[m / 10] + Ss[ip[m]];
    s += v; s2 = fmaf(v, v, s2);
  }
  __shared__ float ls[256], ls2[256];
  ls[threadIdx.x] = s; ls2[threadIdx.x] = s2;
  __syncthreads();
  for (int st = 128; st > 0; st >>= 1) {
    if (threadIdx.x < st) { ls[threadIdx.x] += ls[threadIdx.x + st]; ls2[threadIdx.x] += ls2[threadIdx.x + st]; }
    __syncthreads();
  }
  if (threadIdx.x == 0) { atomicAdd(&sum[c], (double)ls[0]); atomicAdd(&sumsq[c], (double)ls2[0]); }
}

__global__ void bnfin_k(const double* __restrict__ sum, const double* __restrict__ sumsq,
                        const float* __restrict__ g, const float* __restrict__ bb,
                        float* __restrict__ sc, float* __restrict__ sh, int C, double invcnt) {
  int c = blockIdx.x * 256 + threadIdx.x;
  if (c >= C) return;
  double mean = sum[c] * invcnt;
  double var = sumsq[c] * invcnt - mean * mean;
  float rstd = (float)(1.0 / sqrt(var + 1e-5));
  float scv = g[c] * rstd;
  sc[c] = scv;
  sh[c] = bb[c] - (float)mean * scv;
}

// fused softmax + Xe (per batch): block = channel c; S row LDS-staged.
__global__ __launch_bounds__(256) void smxe_k(
    const bf16* __restrict__ wl, const float* __restrict__ sc2,
    const float* __restrict__ sh2, const float* __restrict__ R,
    const float* __restrict__ S, const int* __restrict__ ip,
    const float* __restrict__ sc3, const float* __restrict__ sh3,
    unsigned short* __restrict__ Xe) {
  int c = blockIdx.x;
  __shared__ float Ss[2048];
  const float* Sp = S + (long)c * 2048;
  const float* Rp = R + (long)c * 2048;
  for (int i = threadIdx.x; i < 2048; i += 256) Ss[i] = Sp[i];
  __syncthreads();
  float a = sc2[c], bs = sh2[c], a3 = sc3[c], b3 = sh3[c];
  const bf16* wc = wl + (long)c * 20480;
  for (int n = threadIdx.x; n < 2048; n += 256) {
    float v[10], m = -1e30f;
#pragma unroll
    for (int k = 0; k < 10; ++k) {
      float x = fmaf(a, __bfloat162float(wc[n * 10 + k]), bs);
      x = x >= 0.f ? x : 0.01f * x;
      v[k] = x; m = fmaxf(m, x);
    }
    float s = 0.f;
#pragma unroll
    for (int k = 0; k < 10; ++k) { v[k] = __expf(v[k] - m); s += v[k]; }
    float inv = 1.f / s;
    float rn = Rp[n];
#pragma unroll
    for (int k = 0; k < 10; ++k) {
      int j = ip[n * 10 + k];
      float h = fmaf(a3, rn + Ss[j], b3);
      h = h >= 0.f ? h : 0.01f * h;
      Xe[(long)(c * 10 + k) * 2048 + n] = f2b(h * (v[k] * inv));
    }
  }
}

// AdaIN in place + bf16 copy for tail1 MFMA
__global__ void adain_k(float* __restrict__ x2, const float* __restrict__ ad2,
                        unsigned short* __restrict__ x2b) {
  long id = (long)blockIdx.x * 256 + threadIdx.x;
  const long TOT = 8L * 512 * 2048;
  if (id >= TOT) return;
  int n = (int)(id & 2047);
  long t = id >> 11;
  int c = (int)(t & 511);
  int b = (int)(t >> 9);
  const float* A = ad2 + (long)b * 1024 * 2048;
  float ga = A[(long)c * 2048 + n];
  float be = A[(long)(512 + c) * 2048 + n];
  float v = fmaf(ga, x2[id], be);
  x2[id] = v;
  x2b[id] = f2b(v);
}

// ---------------- host ----------------
extern "C" void kernel_launch(void* const* d_in, const int* in_sizes, int n_in,
                              void* d_out, int out_size, void* d_ws, size_t ws_size,
                              hipStream_t stream) {
  (void)in_sizes; (void)n_in;
  const float* xin     = (const float*)d_in[0];
  const float* zin     = (const float*)d_in[1];
  const float* head_w1 = (const float*)d_in[2];
  const float* head_b1 = (const float*)d_in[3];
  const float* head_w2 = (const float*)d_in[4];
  const float* head_b2 = (const float*)d_in[5];
  const float* lat_w   = (const float*)d_in[22];
  const float* lat_b   = (const float*)d_in[23];
  const float* e2_w1   = (const float*)d_in[24];
  const float* e2_g1   = (const float*)d_in[26];
  const float* e2_bb1  = (const float*)d_in[27];
  const float* e2_w2   = (const float*)d_in[28];
  const float* e2_g2   = (const float*)d_in[30];
  const float* e2_bb2  = (const float*)d_in[31];
  const float* e2_xw   = (const float*)d_in[32];
  const float* e2_xg   = (const float*)d_in[34];
  const float* e2_xbb  = (const float*)d_in[35];
  const float* e2_ow   = (const float*)d_in[36];
  const float* e2_ob   = (const float*)d_in[37];
  const float* ad2_w   = (const float*)d_in[38];
  const float* ad2_b   = (const float*)d_in[39];
  const float* tail_w1 = (const float*)d_in[40];
  const float* tail_b1 = (const float*)d_in[41];
  const float* tail_w2 = (const float*)d_in[42];
  const float* tail_b2 = (const float*)d_in[43];
  const float* tail_w3 = (const float*)d_in[44];
  const float* tail_b3 = (const float*)d_in[45];
  float* out = (float*)d_out;

  // ---- arena ----
  char* ws = (char*)d_ws;
  size_t off = 0;
  auto A = [&](size_t bytes) { size_t r = off; off += (bytes + 255) & ~(size_t)255; return r; };
  size_t oStats = A(20480);
  size_t oSc1 = A(1024), oSh1 = A(1024);
  size_t oSc2 = A(2048), oSh2 = A(2048);
  size_t oSc3 = A(2048), oSh3 = A(2048);
  size_t oXwAb = A(512 * 128 * 2), oXwBb = A(512 * 128 * 2);
  size_t oWp  = A(512 * 136 * 4);
  size_t oW2b = A(512 * 256 * 2);
  size_t oOwb = A(512L * 5120 * 2);
  size_t oAdb = A(1024 * 512 * 2);
  size_t oTw1b = A(256 * 512 * 2);
  size_t oSq  = A(8L * 2048 * 4);
  size_t oIdx = A(8L * 2048 * 10 * 4);
  size_t oX1  = A(8L * 128 * 2048 * 4);
  size_t oQ   = A(8L * 256 * 2048 * 4);
  size_t oR   = A(8L * 512 * 2048 * 4);
  size_t oS   = A(8L * 512 * 2048 * 4);
  size_t oStyle = A(8L * 512 * 2048 * 4);
  size_t oX2  = A(8L * 512 * 2048 * 4);
  size_t oSL  = A(83886080 + 512);
  size_t offBase = off;
  if (ws_size < offBase) {
    fill_k<<<(out_size + 255) / 256, 256, 0, stream>>>(out, (float)(ws_size >> 20), out_size);
    return;
  }

  double* sum1 = (double*)(ws + oStats);
  double* sumsq1 = sum1 + 256;
  double* sum2 = sumsq1 + 256;
  double* sumsq2 = sum2 + 512;
  double* sum3 = sumsq2 + 512;
  double* sumsq3 = sum3 + 512;
  float* sc1 = (float*)(ws + oSc1); float* sh1 = (float*)(ws + oSh1);
  float* sc2 = (float*)(ws + oSc2); float* sh2 = (float*)(ws + oSh2);
  float* sc3 = (float*)(ws + oSc3); float* sh3 = (float*)(ws + oSh3);
  unsigned short* xwAb = (unsigned short*)(ws + oXwAb);
  unsigned short* xwBb = (unsigned short*)(ws + oXwBb);
  float* Wp = (float*)(ws + oWp);
  unsigned short* w2b = (unsigned short*)(ws + oW2b);
  unsigned short* owb = (unsigned short*)(ws + oOwb);
  unsigned short* adb = (unsigned short*)(ws + oAdb);
  unsigned short* tw1b = (unsigned short*)(ws + oTw1b);
  float* sq = (float*)(ws + oSq);
  int* idx = (int*)(ws + oIdx);
  float* x1 = (float*)(ws + oX1);
  float* Q = (float*)(ws + oQ);
  float* R = (float*)(ws + oR);
  float* S = (float*)(ws + oS);
  float* style = (float*)(ws + oStyle);
  float* style1 = (float*)(ws + oX2);
  float* x2 = (float*)(ws + oX2);
  char* SL = ws + oSL;
  // SL (84MB) schedule:
  //  xzp[0,8.9) -> x1b[40,44.2) persists through R/S -> dist2[0,33.6) kNN ->
  //  G2[0,21) stats -> pass2 groups: Xe2[0,42), w2lb[44,65), G1[66,76.5),
  //    P[44,77.6) (after w2lb/G1 dead) ->
  //  ad2out[0,67.1) + x2b[70.25,87->83.8) -> t1[0,16.8)+t2[21,25.2)
  float* xzp = (float*)(SL);
  unsigned short* x1b = (unsigned short*)(SL + 41943040);
  float* dist2 = (float*)(SL);
  unsigned short* G2 = (unsigned short*)(SL);
  unsigned short* Xe2 = (unsigned short*)(SL);
  bf16* w2lb = (bf16*)(SL + 46137344);
  unsigned short* G1 = (unsigned short*)(SL + 69206016);
  float* P = (float*)(SL + 46137344);
  float* ad2out = (float*)(SL);
  unsigned short* x2b = (unsigned short*)(SL + 70254592);
  float* t1 = (float*)(SL);
  float* t2 = (float*)(SL + 20971520);

  hipMemsetAsync(ws + oStats, 0, 20480, stream);

  // weight conversions
  wcvt_k<<<(512 * 256 + 255) / 256, 256, 0, stream>>>(e2_w2, w2b, 512 * 256);
  wcvt_k<<<(int)((512L * 5120 + 255) / 256), 256, 0, stream>>>(e2_ow, owb, 512L * 5120);
  wcvt_k<<<(1024 * 512 + 255) / 256, 256, 0, stream>>>(ad2_w, adb, 1024 * 512);
  wcvt_k<<<(256 * 512 + 255) / 256, 256, 0, stream>>>(tail_w1, tw1b, 256 * 512);

  // ---- np-exact head (f32, bit-identical chain) ----
  wpad_k<<<(512 * 136 + 255) / 256, 256, 0, stream>>>(head_w1, Wp);
  xz_k<<<(8L * 136 * 2048 + 255) / 256, 256, 0, stream>>>(xin, zin, xzp);
  gemm2_k<1><<<dim3(16, 4, 8), 256, 0, stream>>>(
      Wp, xzp, head_b1, style1, 512, 136, 2048, 136, 136L * 2048, 512L * 2048);
  gemm2_k<1><<<dim3(16, 4, 8), 256, 0, stream>>>(
      head_w2, style1, head_b2, style, 512, 512, 2048, 512, 512L * 2048, 512L * 2048);
  gemm2_k<0><<<dim3(16, 1, 8), 256, 0, stream>>>(
      lat_w, style, lat_b, x1, 128, 512, 2048, 512, 512L * 2048, 128L * 2048);

  // bf16 copy of x1 for R/S MFMA (placed at SL+40M, clear of dist2's 33.6M)
  wcvt_k<<<(int)((8L * 128 * 2048 + 255) / 256), 256, 0, stream>>>(x1, x1b, 8L * 128 * 2048);

  // ---- np-exact kNN, 2 batches per dispatch ----
  sqnp_k<<<dim3(8, 8), 256, 0, stream>>>(x1, sq);
  for (int bp = 0; bp < 8; bp += 2) {
    gramg_k<<<dim3(16, 16, 2), 256, 0, stream>>>(
        x1 + (long)bp * 128 * 2048, sq + bp * 2048, dist2);
    topk_k<<<1024, 256, 0, stream>>>(dist2, idx + (long)bp * 20480);
  }

  // ---- Q (f32); BN1 stats ----
  gemm_k<0><<<dim3(32, 4, 8), 256, 0, stream>>>(
      e2_w1, x1, nullptr, Q, 256, 128, 2048, 128L * 2048, 256L * 2048, 0.f);
  stats_qd_k<<<dim3(256, 8), 256, 0, stream>>>(Q, idx, sum1, sumsq1);
  bnfin_k<<<1, 256, 0, stream>>>(sum1, sumsq1, e2_g1, e2_bb1, sc1, sh1, 256, 1.0 / 163840.0);

  // ---- conv_x via MFMA: R, S; BN3 stats ----
  xwsplit_k<<<(512 * 128 + 255) / 256, 256, 0, stream>>>(e2_xw, xwAb, xwBb);
  mfma_k<0, 0, 0, unsigned short, float><<<dim3(16, 4, 8), 256, 0, stream>>>(
      xwAb, x1b, nullptr, R, 512, 128, 2048, 128, 128L * 2048, 512L * 2048,
      nullptr, nullptr);
  mfma_k<0, 0, 0, unsigned short, float><<<dim3(16, 4, 8), 256, 0, stream>>>(
      xwBb, x1b, nullptr, S, 512, 128, 2048, 128, 128L * 2048, 512L * 2048,
      nullptr, nullptr);
  stats_cx_k<<<dim3(512, 8), 256, 0, stream>>>(R, S, idx, sum3, sumsq3);
  bnfin_k<<<2, 256, 0, stream>>>(sum3, sumsq3, e2_xg, e2_xbb, sc3, sh3, 512, 1.0 / 163840.0);

  // ---- BN2 stats: 2-batch G + z=2 stats GEMM ----
  for (int bp = 0; bp < 8; bp += 2) {
    g2_k<<<2 * 20480, 256, 0, stream>>>(Q + (long)bp * 256 * 2048,
                                        idx + (long)bp * 20480, sc1, sh1, G2, 2);
    mfma_k<1, 0, 0, unsigned short, float><<<dim3(160, 4, 2), 256, 0, stream>>>(
        w2b, G2, nullptr, nullptr, 512, 256, 20480, 256, 256L * 20480, 0,
        sum2, sumsq2);
  }
  bnfin_k<<<2, 256, 0, stream>>>(sum2, sumsq2, e2_g2, e2_bb2, sc2, sh2, 512, 1.0 / 163840.0);

  // ---- pass2: 2-batch groups ----
  for (int bp = 0; bp < 8; bp += 2) {
    for (int bi = 0; bi < 2; ++bi) {
      int b = bp + bi;
      g2_k<<<20480, 256, 0, stream>>>(Q + (long)b * 256 * 2048,
                                      idx + (long)b * 20480, sc1, sh1, G1, 1);
      mfma_k<0, 0, 0, unsigned short, bf16><<<dim3(160, 4, 1), 256, 0, stream>>>(
          w2b, G1, nullptr, w2lb, 512, 256, 20480, 256, 0, 0, nullptr, nullptr);
      smxe_k<<<512, 256, 0, stream>>>(
          w2lb, sc2, sh2, R + (long)b * 512 * 2048, S + (long)b * 512 * 2048,
          idx + (long)b * 20480, sc3, sh3, Xe2 + (long)bi * 5120 * 2048);
    }
    // conv_out: z = batch(2) x splitk(4); K=5120, kLen=1280
    mfma_k<0, 2, 0, unsigned short, float><<<dim3(16, 4, 8), 256, 0, stream>>>(
        owb, Xe2, nullptr, P, 512, 5120, 2048, 1280, 5120L * 2048, 512L * 2048,
        nullptr, nullptr);
    redk2_k<<<(2 * 512 * 2048 + 255) / 256, 256, 0, stream>>>(
        P, e2_ob, x2 + (long)bp * 512 * 2048);
  }

  // ---- AdaIN2 (MFMA, float B staging) + apply + bf16 copy ----
  mfma_k<0, 0, 0, float, float><<<dim3(16, 8, 8), 256, 0, stream>>>(
      adb, style, ad2_b, ad2out, 1024, 512, 2048, 512, 512L * 2048, 1024L * 2048,
      nullptr, nullptr);
  adain_k<<<(int)((8L * 512 * 2048 + 255) / 256), 256, 0, stream>>>(x2, ad2out, x2b);

  // ---- tail: t1 via MFMA (lrelu fused), t2/t3 f32 ----
  mfma_k<0, 0, 1, unsigned short, float><<<dim3(16, 2, 8), 256, 0, stream>>>(
      tw1b, x2b, tail_b1, t1, 256, 512, 2048, 512, 512L * 2048, 256L * 2048,
      nullptr, nullptr);
  gemm_k<1><<<dim3(32, 1, 8), 256, 0, stream>>>(
      tail_w2, t1, tail_b2, t2, 64, 256, 2048, 256L * 2048, 64L * 2048, 0.01f);
  gemm_k<2><<<dim3(32, 1, 8), 256, 0, stream>>>(
      tail_w3, t2, tail_b3, out, 3, 64, 2048, 64L * 2048, 3L * 2048, 0.f);
}

// Round 17
// 1587.228 us; speedup vs baseline: 3.3035x; 1.0217x over previous
//
#include <hip/hip_runtime.h>
#include <hip/hip_bf16.h>

// SP_DecoderLight forward, MI355X. Round 17 (consolidation).
// R16: 1622us; top-5 all = np-exact f32 head @88% vector peak (floor).
// Change: w2 VALUE pass 2-batch (g2 nb=2, mfma z=2 -> 40MiB bf16 logits,
// smxe x2, conv z=8). -8 dispatches, better w2 occupancy. No numeric change.

using bf16 = __hip_bfloat16;
typedef short bf8_t __attribute__((ext_vector_type(8)));
typedef float f4_t __attribute__((ext_vector_type(4)));

#define DEV static __device__ __forceinline__
DEV void stf(float* p, float v) { *p = v; }
DEV void stf(bf16* p, float v) { *p = __float2bfloat16(v); }
DEV unsigned short f2b(float f) { bf16 h = __float2bfloat16(f); return *reinterpret_cast<unsigned short*>(&h); }
DEV unsigned short ldb(const float* p) { return f2b(*p); }
DEV unsigned short ldb(const unsigned short* p) { return *p; }

// ---------------- MFMA bf16 GEMM 128x128 ----------------
// OMODE: 0 store, 1 stats-only. SPLITK: 0 z=batch (X+=z*sXz);
// 1 z=splitk (kOff=z*kLen); 2 z=batch*4+split.
template<int OMODE, int SPLITK, int ACT, typename TB, typename TO>
__global__ __launch_bounds__(256) void mfma_k(
    const unsigned short* __restrict__ Wb, const TB* __restrict__ X,
    const float* __restrict__ bias, TO* __restrict__ Out,
    int O, int K, int N, int kLen, long sXz, long sOz,
    double* __restrict__ gsum, double* __restrict__ gsq)
{
  int kOff = 0;
  if constexpr (SPLITK == 1) { kOff = blockIdx.z * kLen; }
  else if constexpr (SPLITK == 2) { kOff = (blockIdx.z & 3) * kLen; X += (long)(blockIdx.z >> 2) * sXz; }
  else { X += (long)blockIdx.z * sXz; }
  int n0 = blockIdx.x * 128, o0 = blockIdx.y * 128;
  __shared__ unsigned short As[128][40];
  __shared__ unsigned short Bs[128][40];
  __shared__ float ssum[128], ssq[128];
  int t = threadIdx.x;
  int w = t >> 6, l = t & 63;
  int lr = l & 15, lk = l >> 4;
  f4_t acc[2][8];
#pragma unroll
  for (int mi = 0; mi < 2; ++mi)
#pragma unroll
    for (int nj = 0; nj < 8; ++nj) acc[mi][nj] = (f4_t){0.f, 0.f, 0.f, 0.f};

  for (int k0 = kOff; k0 < kOff + kLen; k0 += 32) {
    {
      int ro = t >> 3, kq = (t & 7) * 4;
#pragma unroll
      for (int i = 0; i < 4; ++i) {
        int o = ro + i * 32;
        unsigned long long v = *reinterpret_cast<const unsigned long long*>(
            &Wb[(long)(o0 + o) * K + k0 + kq]);
        *reinterpret_cast<unsigned long long*>(&As[o][kq]) = v;
      }
    }
    if constexpr (sizeof(TB) == 2) {
      int nn = (t & 63) * 2, kg = (t >> 6) * 8;
#pragma unroll
      for (int i = 0; i < 8; ++i) {
        int kk = kg + i;
        unsigned v = *reinterpret_cast<const unsigned*>(
            &X[(long)(k0 + kk) * N + n0 + nn]);
        Bs[nn][kk] = (unsigned short)(v & 0xffffu);
        Bs[nn + 1][kk] = (unsigned short)(v >> 16);
      }
    } else {
      int nn = t & 127, kb = (t >> 7) * 2;
#pragma unroll
      for (int i = 0; i < 8; ++i) {
        int kk = kb + i * 4;
        unsigned short b0 = ldb(&X[(long)(k0 + kk) * N + n0 + nn]);
        unsigned short b1 = ldb(&X[(long)(k0 + kk + 1) * N + n0 + nn]);
        *reinterpret_cast<unsigned int*>(&Bs[nn][kk]) =
            (unsigned)b0 | ((unsigned)b1 << 16);
      }
    }
    __syncthreads();
    bf8_t a[2], b[8];
#pragma unroll
    for (int mi = 0; mi < 2; ++mi)
      a[mi] = *reinterpret_cast<const bf8_t*>(&As[w * 32 + mi * 16 + lr][lk * 8]);
#pragma unroll
    for (int nj = 0; nj < 8; ++nj)
      b[nj] = *reinterpret_cast<const bf8_t*>(&Bs[nj * 16 + lr][lk * 8]);
#pragma unroll
    for (int mi = 0; mi < 2; ++mi)
#pragma unroll
      for (int nj = 0; nj < 8; ++nj)
        acc[mi][nj] = __builtin_amdgcn_mfma_f32_16x16x32_bf16(
            a[mi], b[nj], acc[mi][nj], 0, 0, 0);
    __syncthreads();
  }
  if constexpr (OMODE == 1) {
    if (t < 128) { ssum[t] = 0.f; ssq[t] = 0.f; }
    __syncthreads();
#pragma unroll
    for (int mi = 0; mi < 2; ++mi)
#pragma unroll
      for (int jj = 0; jj < 4; ++jj) {
        float s = 0.f, s2 = 0.f;
#pragma unroll
        for (int nj = 0; nj < 8; ++nj) {
          float v = acc[mi][nj][jj];
          s += v; s2 = fmaf(v, v, s2);
        }
#pragma unroll
        for (int off = 1; off < 16; off <<= 1) {
          s += __shfl_xor(s, off);
          s2 += __shfl_xor(s2, off);
        }
        if (lr == 0) {
          int oi = w * 32 + mi * 16 + lk * 4 + jj;
          atomicAdd(&ssum[oi], s);
          atomicAdd(&ssq[oi], s2);
        }
      }
    __syncthreads();
    if (t < 128) {
      atomicAdd(&gsum[o0 + t], (double)ssum[t]);
      atomicAdd(&gsq[o0 + t], (double)ssq[t]);
    }
  } else {
    TO* Ob = Out + (long)blockIdx.z * sOz;
#pragma unroll
    for (int mi = 0; mi < 2; ++mi)
#pragma unroll
      for (int nj = 0; nj < 8; ++nj)
#pragma unroll
        for (int jj = 0; jj < 4; ++jj) {
          int o = o0 + w * 32 + mi * 16 + lk * 4 + jj;
          int n = n0 + nj * 16 + lr;
          float v = acc[mi][nj][jj] + (bias ? bias[o] : 0.f);
          if constexpr (ACT == 1) v = v >= 0.f ? v : 0.01f * v;
          stf(&Ob[(long)o * N + n], v);
        }
  }
}

// ---------------- f32 tiled GEMM 128x128 (np-exact chain; head) -----------
template<int ACT>
__global__ __launch_bounds__(256) void gemm2_k(
    const float* __restrict__ W, const float* __restrict__ X,
    const float* __restrict__ bias, float* __restrict__ Out,
    int O, int K, int N, int kLen, long sXz, long sOz)
{
  X += (long)blockIdx.z * sXz;
  int n0 = blockIdx.x * 128, o0 = blockIdx.y * 128;
  __shared__ float Ws[8][132];
  __shared__ float Xs[8][132];
  int t = threadIdx.x, tx = t & 15, ty = t >> 4;
  int cb = tx * 4;
  float acc[8][8] = {};
  for (int k0 = 0; k0 < kLen; k0 += 8) {
    {
      int kk = t & 7, oo0 = t >> 3;
#pragma unroll
      for (int i = 0; i < 4; ++i) {
        int oo = oo0 + i * 32;
        Ws[kk][oo] = W[(long)(o0 + oo) * K + k0 + kk];
      }
    }
    {
      int nn = t & 127, kk0 = t >> 7;
#pragma unroll
      for (int i = 0; i < 4; ++i) {
        int kk = kk0 + i * 2;
        Xs[kk][nn] = X[(long)(k0 + kk) * N + n0 + nn];
      }
    }
    __syncthreads();
#pragma unroll
    for (int kk = 0; kk < 8; ++kk) {
      float a[8], bx[8];
#pragma unroll
      for (int i = 0; i < 8; ++i) a[i] = Ws[kk][ty * 8 + i];
#pragma unroll
      for (int j = 0; j < 4; ++j) { bx[j] = Xs[kk][cb + j]; bx[4 + j] = Xs[kk][64 + cb + j]; }
#pragma unroll
      for (int i = 0; i < 8; ++i)
#pragma unroll
        for (int j = 0; j < 8; ++j)
          acc[i][j] = fmaf(a[i], bx[j], acc[i][j]);
    }
    __syncthreads();
  }
  float* Ob = Out + (long)blockIdx.z * sOz;
#pragma unroll
  for (int i = 0; i < 8; ++i) {
    int o = o0 + ty * 8 + i;
    float bv = bias ? bias[o] : 0.f;
#pragma unroll
    for (int j = 0; j < 8; ++j) {
      int col = (j < 4) ? (n0 + cb + j) : (n0 + 64 + cb + (j - 4));
      float v = acc[i][j] + bv;
      if constexpr (ACT == 1) v = v >= 0.f ? v : 0.01f * v;
      Ob[(long)o * N + col] = v;
    }
  }
}

// np-exact gram (z = batch offset within pair)
__global__ __launch_bounds__(256) void gramg_k(const float* __restrict__ A,
                                               const float* __restrict__ sqb,
                                               float* __restrict__ D) {
  A += (long)blockIdx.z * 128 * 2048;
  sqb += (long)blockIdx.z * 2048;
  D += (long)blockIdx.z * 2048 * 2048;
  int m0 = blockIdx.x * 128, n0 = blockIdx.y * 128;
  __shared__ float Am[8][132];
  __shared__ float An[8][132];
  int t = threadIdx.x, tx = t & 15, ty = t >> 4;
  int cb = tx * 4;
  float g[8][8] = {};
  for (int c0 = 0; c0 < 128; c0 += 8) {
    {
      int nn = t & 127, kk0 = t >> 7;
#pragma unroll
      for (int i = 0; i < 4; ++i) {
        int kk = kk0 + i * 2;
        Am[kk][nn] = A[(long)(c0 + kk) * 2048 + m0 + nn];
        An[kk][nn] = A[(long)(c0 + kk) * 2048 + n0 + nn];
      }
    }
    __syncthreads();
#pragma unroll
    for (int kk = 0; kk < 8; ++kk) {
      float a[8], bm[8];
#pragma unroll
      for (int i = 0; i < 8; ++i) a[i] = An[kk][ty * 8 + i];
#pragma unroll
      for (int j = 0; j < 4; ++j) { bm[j] = Am[kk][cb + j]; bm[4 + j] = Am[kk][64 + cb + j]; }
#pragma unroll
      for (int i = 0; i < 8; ++i)
#pragma unroll
        for (int j = 0; j < 8; ++j)
          g[i][j] = fmaf(a[i], bm[j], g[i][j]);
    }
    __syncthreads();
  }
#pragma unroll
  for (int i = 0; i < 8; ++i) {
    int n = n0 + ty * 8 + i;
    float sn = sqb[n];
#pragma unroll
    for (int j = 0; j < 8; ++j) {
      int m = (j < 4) ? (m0 + cb + j) : (m0 + 64 + cb + (j - 4));
      float t1 = __fadd_rn(sn, sqb[m]);
      D[(long)n * 2048 + m] = __fsub_rn(t1, __fmul_rn(2.0f, g[i][j]));
    }
  }
}

// numpy npyv(AVX512) pairwise sum of squares
__global__ void sqnp_k(const float* __restrict__ x1, float* __restrict__ sq) {
  int n = blockIdx.x * 256 + threadIdx.x;
  int b = blockIdx.y;
  const float* p = x1 + (long)b * 128 * 2048 + n;
  float r[4][16];
#pragma unroll
  for (int v = 0; v < 4; ++v)
#pragma unroll
    for (int l = 0; l < 16; ++l) {
      float x = p[(long)(16 * v + l) * 2048];
      r[v][l] = __fmul_rn(x, x);
    }
#pragma unroll
  for (int v = 0; v < 4; ++v)
#pragma unroll
    for (int l = 0; l < 16; ++l) {
      float x = p[(long)(64 + 16 * v + l) * 2048];
      r[v][l] = __fadd_rn(r[v][l], __fmul_rn(x, x));
    }
  float u[16];
#pragma unroll
  for (int l = 0; l < 16; ++l)
    u[l] = __fadd_rn(__fadd_rn(r[0][l], r[1][l]), __fadd_rn(r[2][l], r[3][l]));
  float b8[8];
#pragma unroll
  for (int l = 0; l < 8; ++l) b8[l] = __fadd_rn(u[l], u[l + 8]);
  float c4[4];
#pragma unroll
  for (int l = 0; l < 4; ++l) c4[l] = __fadd_rn(b8[l], b8[l + 4]);
  float d0 = __fadd_rn(c4[0], c4[2]);
  float d1 = __fadd_rn(c4[1], c4[3]);
  sq[b * 2048 + n] = __fadd_rn(d0, d1);
}

// ---------------- f32 tiled GEMM 64x64 (Q / tail2 / tail3) ----------------
template<int ACT>
__global__ __launch_bounds__(256) void gemm_k(
    const float* __restrict__ W, const float* __restrict__ X,
    const float* __restrict__ bias, float* __restrict__ Out,
    int O, int K, int N, long sXb, long sOb, float slope)
{
  const float* Xb = X + (long)blockIdx.z * sXb;
  int n0 = blockIdx.x * 64, o0 = blockIdx.y * 64;
  __shared__ float Ws[16][68];
  __shared__ float Xs[16][68];
  int t = threadIdx.x, tx = t & 15, ty = t >> 4;
  float acc[16] = {};
  for (int k0 = 0; k0 < K; k0 += 16) {
#pragma unroll
    for (int i = 0; i < 4; ++i) {
      int l = t + i * 256, oo = l >> 4, kk = l & 15;
      int o = o0 + oo, k = k0 + kk;
      float v = 0.f;
      if (o < O && k < K) v = W[(long)o * K + k];
      Ws[kk][oo] = v;
    }
#pragma unroll
    for (int i = 0; i < 4; ++i) {
      int kk = (t >> 6) + i * 4, nn = t & 63;
      int k = k0 + kk;
      float v = 0.f;
      if (k < K) v = Xb[(long)k * N + n0 + nn];
      Xs[kk][nn] = v;
    }
    __syncthreads();
#pragma unroll
    for (int kk = 0; kk < 16; ++kk) {
      float a0 = Ws[kk][ty * 4 + 0], a1 = Ws[kk][ty * 4 + 1];
      float a2 = Ws[kk][ty * 4 + 2], a3 = Ws[kk][ty * 4 + 3];
      float b0 = Xs[kk][tx * 4 + 0], b1 = Xs[kk][tx * 4 + 1];
      float b2 = Xs[kk][tx * 4 + 2], b3 = Xs[kk][tx * 4 + 3];
      acc[0] = fmaf(a0, b0, acc[0]);   acc[1] = fmaf(a0, b1, acc[1]);
      acc[2] = fmaf(a0, b2, acc[2]);   acc[3] = fmaf(a0, b3, acc[3]);
      acc[4] = fmaf(a1, b0, acc[4]);   acc[5] = fmaf(a1, b1, acc[5]);
      acc[6] = fmaf(a1, b2, acc[6]);   acc[7] = fmaf(a1, b3, acc[7]);
      acc[8] = fmaf(a2, b0, acc[8]);   acc[9] = fmaf(a2, b1, acc[9]);
      acc[10] = fmaf(a2, b2, acc[10]); acc[11] = fmaf(a2, b3, acc[11]);
      acc[12] = fmaf(a3, b0, acc[12]); acc[13] = fmaf(a3, b1, acc[13]);
      acc[14] = fmaf(a3, b2, acc[14]); acc[15] = fmaf(a3, b3, acc[15]);
    }
    __syncthreads();
  }
#pragma unroll
  for (int i = 0; i < 4; ++i) {
    int o = o0 + ty * 4 + i;
    if (o < O) {
      float bv = bias ? bias[o] : 0.f;
#pragma unroll
      for (int j = 0; j < 4; ++j) {
        float v = acc[i * 4 + j] + bv;
        if constexpr (ACT == 1) v = v >= 0.f ? v : slope * v;
        if constexpr (ACT == 2) v = tanhf(v);
        Out[(long)blockIdx.z * sOb + (long)o * N + n0 + tx * 4 + j] = v;
      }
    }
  }
}

// ---------------- small kernels ----------------
__global__ void fill_k(float* __restrict__ out, float v, int n) {
  int id = blockIdx.x * 256 + threadIdx.x;
  if (id < n) out[id] = v;
}

__global__ void wcvt_k(const float* __restrict__ in, unsigned short* __restrict__ o, long n) {
  long id = (long)blockIdx.x * 256 + threadIdx.x;
  if (id < n) o[id] = f2b(in[id]);
}

__global__ void wpad_k(const float* __restrict__ w, float* __restrict__ wp) {
  int id = blockIdx.x * 256 + threadIdx.x;
  if (id >= 512 * 136) return;
  int o = id / 136, k = id % 136;
  wp[id] = (k < 131) ? w[o * 131 + k] : 0.f;
}

__global__ void xz_k(const float* __restrict__ x, const float* __restrict__ z,
                     float* __restrict__ xz) {
  long id = (long)blockIdx.x * 256 + threadIdx.x;
  const long TOT = 8L * 136 * 2048;
  if (id >= TOT) return;
  int n = (int)(id % 2048);
  int c = (int)((id / 2048) % 136);
  int b = (int)(id / (136L * 2048));
  float v = 0.f;
  if (c < 3) v = x[((long)b * 3 + c) * 2048 + n];
  else if (c < 131) v = z[((long)b * 128 + (c - 3)) * 2048 + n];
  xz[id] = v;
}

__global__ void xwsplit_k(const float* __restrict__ xw,
                          unsigned short* __restrict__ Ab,
                          unsigned short* __restrict__ Bb) {
  int id = blockIdx.x * 256 + threadIdx.x;
  if (id >= 512 * 128) return;
  int o = id / 128, c = id % 128;
  float a = xw[o * 256 + c];
  float b = xw[o * 256 + 128 + c];
  Ab[id] = f2b(a - b);
  Bb[id] = f2b(b);
}

// register-resident topk over (grid*4) rows of a contiguous dist region
__global__ __launch_bounds__(256) void topk_k(const float* __restrict__ dist,
                                              int* __restrict__ idx) {
  int row = blockIdx.x * 4 + (threadIdx.x >> 6);
  int lane = threadIdx.x & 63;
  const float* rp = dist + (long)row * 2048;
  float v[32];
#pragma unroll
  for (int i = 0; i < 32; ++i) v[i] = rp[i * 64 + lane];
  unsigned taken = 0;
  const float INF = __builtin_inff();
  for (int r = 0; r < 11; ++r) {
    float best = INF; int bi = 0x7fffffff;
#pragma unroll
    for (int i = 0; i < 32; ++i) {
      bool free = !((taken >> i) & 1u);
      if (free && v[i] < best) { best = v[i]; bi = i; }
    }
    int gi = (bi == 0x7fffffff) ? 0x7ffffffe : bi * 64 + lane;
#pragma unroll
    for (int off = 32; off; off >>= 1) {
      float ov = __shfl_xor(best, off);
      int og = __shfl_xor(gi, off);
      if (ov < best || (ov == best && og < gi)) { best = ov; gi = og; }
    }
    if (gi >= 0 && gi < 2048) {
      if (lane == 0 && r > 0) idx[row * 10 + (r - 1)] = gi;
      if ((gi & 63) == lane) taken |= 1u << (gi >> 6);
    } else if (lane == 0 && r > 0) {
      idx[row * 10 + (r - 1)] = row & 2047;
    }
  }
}

// G bf16 over nb batches
__global__ void g2_k(const float* __restrict__ Q, const int* __restrict__ idx,
                     const float* __restrict__ sc, const float* __restrict__ sh,
                     unsigned short* __restrict__ G, int nb) {
  long id = (long)blockIdx.x * 256 + threadIdx.x;
  const long per = 256L * 20480;
  if (id >= (long)nb * per) return;
  int b = (int)(id / per);
  long r = id % per;
  int c = (int)(r / 20480);
  int m = (int)(r % 20480);
  int j = idx[(long)b * 20480 + m];
  int n = m / 10;
  const float* Qc = Q + (long)b * 256 * 2048 + (long)c * 2048;
  float v = fmaf(sc[c], Qc[j] - Qc[n], sh[c]);
  v = v >= 0.f ? v : 0.01f * v;
  G[id] = f2b(v);
}

// reduce 4 split-K partials for 2 batches; lrelu(0.2)
__global__ void redk2_k(const float* __restrict__ P, const float* __restrict__ bias,
                        float* __restrict__ xo) {
  int id = blockIdx.x * 256 + threadIdx.x;
  if (id >= 2 * 512 * 2048) return;
  int bi = id / (512 * 2048);
  int r = id % (512 * 2048);
  int o = r >> 11;
  float s = 0.f;
#pragma unroll
  for (int sp = 0; sp < 4; ++sp) s += P[(long)(bi * 4 + sp) * 512 * 2048 + r];
  s += bias[o];
  xo[(long)bi * 512 * 2048 + r] = s >= 0.f ? s : 0.2f * s;
}

// BN1 stats, Q row LDS-staged
__global__ __launch_bounds__(256) void stats_qd_k(const float* __restrict__ Q,
                                                  const int* __restrict__ idx,
                                                  double* __restrict__ sum,
                                                  double* __restrict__ sumsq) {
  int c = blockIdx.x, b = blockIdx.y;
  const float* Qp = Q + ((long)b * 256 + c) * 2048;
  const int* ip = idx + (long)b * 20480;
  __shared__ float Qs[2048];
  for (int i = threadIdx.x; i < 2048; i += 256) Qs[i] = Qp[i];
  __syncthreads();
  float s = 0.f, s2 = 0.f;
  for (int m = threadIdx.x; m < 20480; m += 256) {
    float v = Qs[ip[m]] - Qs[m / 10];
    s += v; s2 = fmaf(v, v, s2);
  }
  __shared__ float ls[256], ls2[256];
  ls[threadIdx.x] = s; ls2[threadIdx.x] = s2;
  __syncthreads();
  for (int st = 128; st > 0; st >>= 1) {
    if (threadIdx.x < st) { ls[threadIdx.x] += ls[threadIdx.x + st]; ls2[threadIdx.x] += ls2[threadIdx.x + st]; }
    __syncthreads();
  }
  if (threadIdx.x == 0) { atomicAdd(&sum[c], (double)ls[0]); atomicAdd(&sumsq[c], (double)ls2[0]); }
}

// BN3 stats, R+S rows LDS-staged
__global__ __launch_bounds__(256) void stats_cx_k(const float* __restrict__ R,
                                                  const float* __restrict__ S,
                                                  const int* __restrict__ idx,
                                                  double* __restrict__ sum,
                                                  double* __restrict__ sumsq) {
  int c = blockIdx.x, b = blockIdx.y;
  const float* Rp = R + ((long)b * 512 + c) * 2048;
  const float* Sp = S + ((long)b * 512 + c) * 2048;
  const int* ip = idx + (long)b * 20480;
  __shared__ float Rs[2048], Ss[2048];
  for (int i = threadIdx.x; i < 2048; i += 256) { Rs[i] = Rp[i]; Ss[i] = Sp[i]; }
  __syncthreads();
  float s = 0.f, s2 = 0.f;
  for (int m = threadIdx.x; m < 20480; m += 256) {
    float v = Rs[m / 10] + Ss[ip[m]];
    s += v; s2 = fmaf(v, v, s2);
  }
  __shared__ float ls[256], ls2[256];
  ls[threadIdx.x] = s; ls2[threadIdx.x] = s2;
  __syncthreads();
  for (int st = 128; st > 0; st >>= 1) {
    if (threadIdx.x < st) { ls[threadIdx.x] += ls[threadIdx.x + st]; ls2[threadIdx.x] += ls2[threadIdx.x + st]; }
    __syncthreads();
  }
  if (threadIdx.x == 0) { atomicAdd(&sum[c], (double)ls[0]); atomicAdd(&sumsq[c], (double)ls2[0]); }
}

__global__ void bnfin_k(const double* __restrict__ sum, const double* __restrict__ sumsq,
                        const float* __restrict__ g, const float* __restrict__ bb,
                        float* __restrict__ sc, float* __restrict__ sh, int C, double invcnt) {
  int c = blockIdx.x * 256 + threadIdx.x;
  if (c >= C) return;
  double mean = sum[c] * invcnt;
  double var = sumsq[c] * invcnt - mean * mean;
  float rstd = (float)(1.0 / sqrt(var + 1e-5));
  float scv = g[c] * rstd;
  sc[c] = scv;
  sh[c] = bb[c] - (float)mean * scv;
}

// fused softmax + Xe (per batch)
__global__ __launch_bounds__(256) void smxe_k(
    const bf16* __restrict__ wl, const float* __restrict__ sc2,
    const float* __restrict__ sh2, const float* __restrict__ R,
    const float* __restrict__ S, const int* __restrict__ ip,
    const float* __restrict__ sc3, const float* __restrict__ sh3,
    unsigned short* __restrict__ Xe) {
  int c = blockIdx.x;
  __shared__ float Ss[2048];
  const float* Sp = S + (long)c * 2048;
  const float* Rp = R + (long)c * 2048;
  for (int i = threadIdx.x; i < 2048; i += 256) Ss[i] = Sp[i];
  __syncthreads();
  float a = sc2[c], bs = sh2[c], a3 = sc3[c], b3 = sh3[c];
  const bf16* wc = wl + (long)c * 20480;
  for (int n = threadIdx.x; n < 2048; n += 256) {
    float v[10], m = -1e30f;
#pragma unroll
    for (int k = 0; k < 10; ++k) {
      float x = fmaf(a, __bfloat162float(wc[n * 10 + k]), bs);
      x = x >= 0.f ? x : 0.01f * x;
      v[k] = x; m = fmaxf(m, x);
    }
    float s = 0.f;
#pragma unroll
    for (int k = 0; k < 10; ++k) { v[k] = __expf(v[k] - m); s += v[k]; }
    float inv = 1.f / s;
    float rn = Rp[n];
#pragma unroll
    for (int k = 0; k < 10; ++k) {
      int j = ip[n * 10 + k];
      float h = fmaf(a3, rn + Ss[j], b3);
      h = h >= 0.f ? h : 0.01f * h;
      Xe[(long)(c * 10 + k) * 2048 + n] = f2b(h * (v[k] * inv));
    }
  }
}

// AdaIN in place + bf16 copy for tail1 MFMA
__global__ void adain_k(float* __restrict__ x2, const float* __restrict__ ad2,
                        unsigned short* __restrict__ x2b) {
  long id = (long)blockIdx.x * 256 + threadIdx.x;
  const long TOT = 8L * 512 * 2048;
  if (id >= TOT) return;
  int n = (int)(id & 2047);
  long t = id >> 11;
  int c = (int)(t & 511);
  int b = (int)(t >> 9);
  const float* A = ad2 + (long)b * 1024 * 2048;
  float ga = A[(long)c * 2048 + n];
  float be = A[(long)(512 + c) * 2048 + n];
  float v = fmaf(ga, x2[id], be);
  x2[id] = v;
  x2b[id] = f2b(v);
}

// ---------------- host ----------------
extern "C" void kernel_launch(void* const* d_in, const int* in_sizes, int n_in,
                              void* d_out, int out_size, void* d_ws, size_t ws_size,
                              hipStream_t stream) {
  (void)in_sizes; (void)n_in;
  const float* xin     = (const float*)d_in[0];
  const float* zin     = (const float*)d_in[1];
  const float* head_w1 = (const float*)d_in[2];
  const float* head_b1 = (const float*)d_in[3];
  const float* head_w2 = (const float*)d_in[4];
  const float* head_b2 = (const float*)d_in[5];
  const float* lat_w   = (const float*)d_in[22];
  const float* lat_b   = (const float*)d_in[23];
  const float* e2_w1   = (const float*)d_in[24];
  const float* e2_g1   = (const float*)d_in[26];
  const float* e2_bb1  = (const float*)d_in[27];
  const float* e2_w2   = (const float*)d_in[28];
  const float* e2_g2   = (const float*)d_in[30];
  const float* e2_bb2  = (const float*)d_in[31];
  const float* e2_xw   = (const float*)d_in[32];
  const float* e2_xg   = (const float*)d_in[34];
  const float* e2_xbb  = (const float*)d_in[35];
  const float* e2_ow   = (const float*)d_in[36];
  const float* e2_ob   = (const float*)d_in[37];
  const float* ad2_w   = (const float*)d_in[38];
  const float* ad2_b   = (const float*)d_in[39];
  const float* tail_w1 = (const float*)d_in[40];
  const float* tail_b1 = (const float*)d_in[41];
  const float* tail_w2 = (const float*)d_in[42];
  const float* tail_b2 = (const float*)d_in[43];
  const float* tail_w3 = (const float*)d_in[44];
  const float* tail_b3 = (const float*)d_in[45];
  float* out = (float*)d_out;

  // ---- arena ----
  char* ws = (char*)d_ws;
  size_t off = 0;
  auto A = [&](size_t bytes) { size_t r = off; off += (bytes + 255) & ~(size_t)255; return r; };
  size_t oStats = A(20480);
  size_t oSc1 = A(1024), oSh1 = A(1024);
  size_t oSc2 = A(2048), oSh2 = A(2048);
  size_t oSc3 = A(2048), oSh3 = A(2048);
  size_t oXwAb = A(512 * 128 * 2), oXwBb = A(512 * 128 * 2);
  size_t oWp  = A(512 * 136 * 4);
  size_t oW2b = A(512 * 256 * 2);
  size_t oOwb = A(512L * 5120 * 2);
  size_t oAdb = A(1024 * 512 * 2);
  size_t oTw1b = A(256 * 512 * 2);
  size_t oSq  = A(8L * 2048 * 4);
  size_t oIdx = A(8L * 2048 * 10 * 4);
  size_t oX1  = A(8L * 128 * 2048 * 4);
  size_t oQ   = A(8L * 256 * 2048 * 4);
  size_t oR   = A(8L * 512 * 2048 * 4);
  size_t oS   = A(8L * 512 * 2048 * 4);
  size_t oStyle = A(8L * 512 * 2048 * 4);
  size_t oX2  = A(8L * 512 * 2048 * 4);
  size_t oSL  = A(83886080 + 512);
  size_t offBase = off;
  if (ws_size < offBase) {
    fill_k<<<(out_size + 255) / 256, 256, 0, stream>>>(out, (float)(ws_size >> 20), out_size);
    return;
  }

  double* sum1 = (double*)(ws + oStats);
  double* sumsq1 = sum1 + 256;
  double* sum2 = sumsq1 + 256;
  double* sumsq2 = sum2 + 512;
  double* sum3 = sumsq2 + 512;
  double* sumsq3 = sum3 + 512;
  float* sc1 = (float*)(ws + oSc1); float* sh1 = (float*)(ws + oSh1);
  float* sc2 = (float*)(ws + oSc2); float* sh2 = (float*)(ws + oSh2);
  float* sc3 = (float*)(ws + oSc3); float* sh3 = (float*)(ws + oSh3);
  unsigned short* xwAb = (unsigned short*)(ws + oXwAb);
  unsigned short* xwBb = (unsigned short*)(ws + oXwBb);
  float* Wp = (float*)(ws + oWp);
  unsigned short* w2b = (unsigned short*)(ws + oW2b);
  unsigned short* owb = (unsigned short*)(ws + oOwb);
  unsigned short* adb = (unsigned short*)(ws + oAdb);
  unsigned short* tw1b = (unsigned short*)(ws + oTw1b);
  float* sq = (float*)(ws + oSq);
  int* idx = (int*)(ws + oIdx);
  float* x1 = (float*)(ws + oX1);
  float* Q = (float*)(ws + oQ);
  float* R = (float*)(ws + oR);
  float* S = (float*)(ws + oS);
  float* style = (float*)(ws + oStyle);
  float* style1 = (float*)(ws + oX2);
  float* x2 = (float*)(ws + oX2);
  char* SL = ws + oSL;
  // SL (80MiB) schedule:
  //  xzp[0,8.9M) -> x1b[40Mi,44.2Mi) (persists through R/S) ->
  //  dist2[0,33.6M) kNN -> G2[0,21M) stats ->
  //  pass2 per 2-batch group: G2v[0,21M) -> w2lb2[40Mi,80Mi) ->
  //    Xe2[0,42M) (over G2v) -> P[40Mi,73.5Mi) (over w2lb2) -> redk2 ->
  //  ad2out[0,67.1M) + x2b[70Mi,74.2Mi)... x2b placed at 70254592 (67MiB)
  //  -> t1[0,16.8M)+t2[21M,25.2M)
  float* xzp = (float*)(SL);
  unsigned short* x1b = (unsigned short*)(SL + 41943040);
  float* dist2 = (float*)(SL);
  unsigned short* G2 = (unsigned short*)(SL);
  bf16* w2lb2 = (bf16*)(SL + 41943040);
  unsigned short* Xe2 = (unsigned short*)(SL);
  float* P = (float*)(SL + 41943040);
  float* ad2out = (float*)(SL);
  unsigned short* x2b = (unsigned short*)(SL + 70254592);
  float* t1 = (float*)(SL);
  float* t2 = (float*)(SL + 20971520);

  hipMemsetAsync(ws + oStats, 0, 20480, stream);

  // weight conversions
  wcvt_k<<<(512 * 256 + 255) / 256, 256, 0, stream>>>(e2_w2, w2b, 512 * 256);
  wcvt_k<<<(int)((512L * 5120 + 255) / 256), 256, 0, stream>>>(e2_ow, owb, 512L * 5120);
  wcvt_k<<<(1024 * 512 + 255) / 256, 256, 0, stream>>>(ad2_w, adb, 1024 * 512);
  wcvt_k<<<(256 * 512 + 255) / 256, 256, 0, stream>>>(tail_w1, tw1b, 256 * 512);

  // ---- np-exact head (f32, bit-identical chain) ----
  wpad_k<<<(512 * 136 + 255) / 256, 256, 0, stream>>>(head_w1, Wp);
  xz_k<<<(8L * 136 * 2048 + 255) / 256, 256, 0, stream>>>(xin, zin, xzp);
  gemm2_k<1><<<dim3(16, 4, 8), 256, 0, stream>>>(
      Wp, xzp, head_b1, style1, 512, 136, 2048, 136, 136L * 2048, 512L * 2048);
  gemm2_k<1><<<dim3(16, 4, 8), 256, 0, stream>>>(
      head_w2, style1, head_b2, style, 512, 512, 2048, 512, 512L * 2048, 512L * 2048);
  gemm2_k<0><<<dim3(16, 1, 8), 256, 0, stream>>>(
      lat_w, style, lat_b, x1, 128, 512, 2048, 512, 512L * 2048, 128L * 2048);

  // bf16 copy of x1 for R/S MFMA
  wcvt_k<<<(int)((8L * 128 * 2048 + 255) / 256), 256, 0, stream>>>(x1, x1b, 8L * 128 * 2048);

  // ---- np-exact kNN, 2 batches per dispatch ----
  sqnp_k<<<dim3(8, 8), 256, 0, stream>>>(x1, sq);
  for (int bp = 0; bp < 8; bp += 2) {
    gramg_k<<<dim3(16, 16, 2), 256, 0, stream>>>(
        x1 + (long)bp * 128 * 2048, sq + bp * 2048, dist2);
    topk_k<<<1024, 256, 0, stream>>>(dist2, idx + (long)bp * 20480);
  }

  // ---- Q (f32); BN1 stats ----
  gemm_k<0><<<dim3(32, 4, 8), 256, 0, stream>>>(
      e2_w1, x1, nullptr, Q, 256, 128, 2048, 128L * 2048, 256L * 2048, 0.f);
  stats_qd_k<<<dim3(256, 8), 256, 0, stream>>>(Q, idx, sum1, sumsq1);
  bnfin_k<<<1, 256, 0, stream>>>(sum1, sumsq1, e2_g1, e2_bb1, sc1, sh1, 256, 1.0 / 163840.0);

  // ---- conv_x via MFMA: R, S; BN3 stats ----
  xwsplit_k<<<(512 * 128 + 255) / 256, 256, 0, stream>>>(e2_xw, xwAb, xwBb);
  mfma_k<0, 0, 0, unsigned short, float><<<dim3(16, 4, 8), 256, 0, stream>>>(
      xwAb, x1b, nullptr, R, 512, 128, 2048, 128, 128L * 2048, 512L * 2048,
      nullptr, nullptr);
  mfma_k<0, 0, 0, unsigned short, float><<<dim3(16, 4, 8), 256, 0, stream>>>(
      xwBb, x1b, nullptr, S, 512, 128, 2048, 128, 128L * 2048, 512L * 2048,
      nullptr, nullptr);
  stats_cx_k<<<dim3(512, 8), 256, 0, stream>>>(R, S, idx, sum3, sumsq3);
  bnfin_k<<<2, 256, 0, stream>>>(sum3, sumsq3, e2_xg, e2_xbb, sc3, sh3, 512, 1.0 / 163840.0);

  // ---- BN2 stats: 2-batch G + z=2 stats GEMM ----
  for (int bp = 0; bp < 8; bp += 2) {
    g2_k<<<2 * 20480, 256, 0, stream>>>(Q + (long)bp * 256 * 2048,
                                        idx + (long)bp * 20480, sc1, sh1, G2, 2);
    mfma_k<1, 0, 0, unsigned short, float><<<dim3(160, 4, 2), 256, 0, stream>>>(
        w2b, G2, nullptr, nullptr, 512, 256, 20480, 256, 256L * 20480, 0,
        sum2, sumsq2);
  }
  bnfin_k<<<2, 256, 0, stream>>>(sum2, sumsq2, e2_g2, e2_bb2, sc2, sh2, 512, 1.0 / 163840.0);

  // ---- pass2: 2-batch groups, single w2-value GEMM per group ----
  for (int bp = 0; bp < 8; bp += 2) {
    g2_k<<<2 * 20480, 256, 0, stream>>>(Q + (long)bp * 256 * 2048,
                                        idx + (long)bp * 20480, sc1, sh1, G2, 2);
    mfma_k<0, 0, 0, unsigned short, bf16><<<dim3(160, 4, 2), 256, 0, stream>>>(
        w2b, G2, nullptr, w2lb2, 512, 256, 20480, 256, 256L * 20480,
        512L * 20480, nullptr, nullptr);
    for (int bi = 0; bi < 2; ++bi) {
      int b = bp + bi;
      smxe_k<<<512, 256, 0, stream>>>(
          w2lb2 + (long)bi * 512 * 20480, sc2, sh2,
          R + (long)b * 512 * 2048, S + (long)b * 512 * 2048,
          idx + (long)b * 20480, sc3, sh3, Xe2 + (long)bi * 5120 * 2048);
    }
    // conv_out: z = batch(2) x splitk(4); K=5120, kLen=1280
    mfma_k<0, 2, 0, unsigned short, float><<<dim3(16, 4, 8), 256, 0, stream>>>(
        owb, Xe2, nullptr, P, 512, 5120, 2048, 1280, 5120L * 2048, 512L * 2048,
        nullptr, nullptr);
    redk2_k<<<(2 * 512 * 2048 + 255) / 256, 256, 0, stream>>>(
        P, e2_ob, x2 + (long)bp * 512 * 2048);
  }

  // ---- AdaIN2 (MFMA, float B staging) + apply + bf16 copy ----
  mfma_k<0, 0, 0, float, float><<<dim3(16, 8, 8), 256, 0, stream>>>(
      adb, style, ad2_b, ad2out, 1024, 512, 2048, 512, 512L * 2048, 1024L * 2048,
      nullptr, nullptr);
  adain_k<<<(int)((8L * 512 * 2048 + 255) / 256), 256, 0, stream>>>(x2, ad2out, x2b);

  // ---- tail: t1 via MFMA (lrelu fused), t2/t3 f32 ----
  mfma_k<0, 0, 1, unsigned short, float><<<dim3(16, 2, 8), 256, 0, stream>>>(
      tw1b, x2b, tail_b1, t1, 256, 512, 2048, 512, 512L * 2048, 256L * 2048,
      nullptr, nullptr);
  gemm_k<1><<<dim3(32, 1, 8), 256, 0, stream>>>(
      tail_w2, t1, tail_b2, t2, 64, 256, 2048, 256L * 2048, 64L * 2048, 0.01f);
  gemm_k<2><<<dim3(32, 1, 8), 256, 0, stream>>>(
      tail_w3, t2, tail_b3, out, 3, 64, 2048, 64L * 2048, 3L * 2048, 0.f);
}